// Round 7
// baseline (239.052 us; speedup 1.0000x reference)
//
#include <hip/hip_runtime.h>
#include <cstddef>

// ---------------------------------------------------------------------------
// B=16, N=512, D=256, H=8, DH=16, INNER=128, SCALE=0.25
// R5 structure (best: 215.6us) + non-temporal stores on streaming outputs.
// bf16 MFMA everywhere; global_load_lds staging; fused GEGLU via weight-col
// permutation (128x128 tile); thin GEMMs on 64x64 tiles. 17 launches.
// ---------------------------------------------------------------------------

typedef __attribute__((ext_vector_type(8))) short short8;
typedef __attribute__((ext_vector_type(4))) short bf16x4;
typedef __attribute__((ext_vector_type(4))) float f32x4;
typedef unsigned short u16t;

__device__ __forceinline__ u16t f2b(float f) {           // fp32 -> bf16 (RNE)
  union { float f; unsigned u; } x; x.f = f;
  unsigned r = (x.u + 0x7fffu + ((x.u >> 16) & 1u)) >> 16;
  return (u16t)r;
}

__device__ __forceinline__ void gload16(const void* g, void* l) {
  __builtin_amdgcn_global_load_lds(
      (const __attribute__((address_space(1))) void*)g,
      (__attribute__((address_space(3))) void*)l, 16, 0, 0);
}

// exact-GELU via Abramowitz-Stegun 7.1.26 erf (max abs err 1.5e-7)
__device__ __forceinline__ float gelu_f(float g) {
  const float x = g * 0.70710678118654752f;
  const float ax = fabsf(x);
  const float t = 1.f / (1.f + 0.3275911f * ax);
  const float p = t * (0.254829592f + t * (-0.284496736f +
                  t * (1.421413741f + t * (-1.453152027f + t * 1.061405429f))));
  const float er = 1.f - p * __expf(-x * x);
  return 0.5f * g * (1.f + copysignf(er, x));
}

// GEGLU weight-column permutation: n_new -> n_orig.
__device__ __forceinline__ int origcol(int n, int halfN) {
  const int nb = n >> 7, s = (n >> 4) & 7, r = n & 15;
  return ((s & 1) ? halfN : 0) + (nb << 6) + ((s >> 1) << 4) + r;
}

// ---------------- 128x128 MFMA GEMM (EPI 2 = fused GEGLU) ------------------
template<int EPI>
__global__ __launch_bounds__(256) void mgemm(
    const u16t* __restrict__ A, const u16t* __restrict__ BT,
    const float* __restrict__ bias, const float* __restrict__ res,
    void* __restrict__ C, int M, int N, int K) {
  __shared__ u16t Al[128 * 32];
  __shared__ u16t Bl[128 * 32];
  const int t = threadIdx.x, lane = t & 63, wid = t >> 6;
  const int wr = wid >> 1, wc = wid & 1;
  const int lr = lane & 15, lq = lane >> 4;
  const int bm = blockIdx.y << 7, bn = blockIdx.x << 7;

  const int ao0 = wid * 2048 + lane * 16;
  const int ar0 = ao0 >> 6,          ac0 = (ao0 & 63) >> 1;
  const int ar1 = (ao0 + 1024) >> 6, ac1 = ((ao0 + 1024) & 63) >> 1;

  const u16t* Ab = A + (size_t)bm * K;
  const u16t* Bb = BT + (size_t)bn * K;

  f32x4 acc[4][4];
#pragma unroll
  for (int m = 0; m < 4; ++m)
#pragma unroll
    for (int n = 0; n < 4; ++n) acc[m][n] = (f32x4){0.f, 0.f, 0.f, 0.f};

  for (int k0 = 0; k0 < K; k0 += 32) {
    gload16(Ab + (size_t)ar0 * K + k0 + ac0, (char*)Al + wid * 2048);
    gload16(Ab + (size_t)ar1 * K + k0 + ac1, (char*)Al + wid * 2048 + 1024);
    gload16(Bb + (size_t)ar0 * K + k0 + ac0, (char*)Bl + wid * 2048);
    gload16(Bb + (size_t)ar1 * K + k0 + ac1, (char*)Bl + wid * 2048 + 1024);
    __syncthreads();
    short8 af[4], bf[4];
#pragma unroll
    for (int m = 0; m < 4; ++m)
      af[m] = *(const short8*)&Al[(wr * 64 + m * 16 + lr) * 32 + lq * 8];
#pragma unroll
    for (int n = 0; n < 4; ++n)
      bf[n] = *(const short8*)&Bl[(wc * 64 + n * 16 + lr) * 32 + lq * 8];
#pragma unroll
    for (int m = 0; m < 4; ++m)
#pragma unroll
      for (int n = 0; n < 4; ++n)
        acc[m][n] = __builtin_amdgcn_mfma_f32_16x16x32_bf16(af[m], bf[n], acc[m][n], 0, 0, 0);
    __syncthreads();
  }

  if (EPI == 2) {                    // fused bias + GEGLU -> NT store (ubuf)
    const int Nh = N >> 1;
#pragma unroll
    for (int np = 0; np < 2; ++np) {
      const int ca = bn + wc * 64 + np * 32 + lr;
      const float ba = bias[ca], bg = bias[ca + 16];
      const int uc = (bn >> 1) + wc * 32 + np * 16 + lr;
#pragma unroll
      for (int m = 0; m < 4; ++m) {
#pragma unroll
        for (int i = 0; i < 4; ++i) {
          const int row = bm + wr * 64 + m * 16 + lq * 4 + i;
          const float a = acc[m][2 * np][i] + ba;
          const float g = acc[m][2 * np + 1][i] + bg;
          __builtin_nontemporal_store(
              (short)f2b(a * gelu_f(g)),
              (short*)C + (size_t)row * Nh + uc);
        }
      }
    }
  } else {
#pragma unroll
    for (int n = 0; n < 4; ++n) {
      const int col = bn + wc * 64 + n * 16 + lr;
      const float bv = bias ? bias[col] : 0.f;
#pragma unroll
      for (int m = 0; m < 4; ++m) {
#pragma unroll
        for (int i = 0; i < 4; ++i) {
          const int row = bm + wr * 64 + m * 16 + lq * 4 + i;
          float v = acc[m][n][i] + bv;
          if (EPI == 1) {
            v += res[(size_t)row * N + col];
            __builtin_nontemporal_store(v, (float*)C + (size_t)row * N + col);
          } else {
            ((u16t*)C)[(size_t)row * N + col] = f2b(v);
          }
        }
      }
    }
  }
}

// ---------------- 64x64 MFMA GEMM for thin shapes (occupancy) --------------
template<int EPI>
__global__ __launch_bounds__(256) void mgemm64(
    const u16t* __restrict__ A, const u16t* __restrict__ BT,
    const float* __restrict__ bias, const float* __restrict__ res,
    void* __restrict__ C, int M, int N, int K) {
  __shared__ u16t Al[64 * 32];       // 4 KB
  __shared__ u16t Bl[64 * 32];
  const int t = threadIdx.x, lane = t & 63, wid = t >> 6;
  const int wr = wid >> 1, wc = wid & 1;
  const int lr = lane & 15, lq = lane >> 4;
  const int bm = blockIdx.y << 6, bn = blockIdx.x << 6;
  const int ch = wid * 64 + lane;
  const int crow = ch >> 2, ccol = (ch & 3) << 3;

  const u16t* Ab = A + (size_t)bm * K;
  const u16t* Bb = BT + (size_t)bn * K;

  f32x4 acc[2][2];
#pragma unroll
  for (int m = 0; m < 2; ++m)
#pragma unroll
    for (int n = 0; n < 2; ++n) acc[m][n] = (f32x4){0.f, 0.f, 0.f, 0.f};

  for (int k0 = 0; k0 < K; k0 += 32) {
    gload16(Ab + (size_t)crow * K + k0 + ccol, (char*)Al + wid * 1024);
    gload16(Bb + (size_t)crow * K + k0 + ccol, (char*)Bl + wid * 1024);
    __syncthreads();
    short8 af[2], bf[2];
#pragma unroll
    for (int m = 0; m < 2; ++m)
      af[m] = *(const short8*)&Al[(wr * 32 + m * 16 + lr) * 32 + lq * 8];
#pragma unroll
    for (int n = 0; n < 2; ++n)
      bf[n] = *(const short8*)&Bl[(wc * 32 + n * 16 + lr) * 32 + lq * 8];
#pragma unroll
    for (int m = 0; m < 2; ++m)
#pragma unroll
      for (int n = 0; n < 2; ++n)
        acc[m][n] = __builtin_amdgcn_mfma_f32_16x16x32_bf16(af[m], bf[n], acc[m][n], 0, 0, 0);
    __syncthreads();
  }

#pragma unroll
  for (int n = 0; n < 2; ++n) {
    const int col = bn + wc * 32 + n * 16 + lr;
    const float bv = bias ? bias[col] : 0.f;
#pragma unroll
    for (int m = 0; m < 2; ++m) {
#pragma unroll
      for (int i = 0; i < 4; ++i) {
        const int row = bm + wr * 32 + m * 16 + lq * 4 + i;
        float v = acc[m][n][i] + bv;
        if (EPI == 1) {
          v += res[(size_t)row * N + col];
          __builtin_nontemporal_store(v, (float*)C + (size_t)row * N + col);
        } else {
          ((u16t*)C)[(size_t)row * N + col] = f2b(v);
        }
      }
    }
  }
}

// ---------------- MFMA attention (share via NT stores) ---------------------
template<int NTOK>
__global__ __launch_bounds__(256) void attn_mfma(
    const u16t* __restrict__ qkv, float* __restrict__ share,
    u16t* __restrict__ outb) {
  __shared__ u16t VT[16][NTOK + 40];
  __shared__ u16t PB[4][16][40];
  const int t = threadIdx.x, lane = t & 63, wv = t >> 6;
  const int lr = lane & 15, lq = lane >> 4;
  const int bpb = NTOK / 64;
  const int bh = blockIdx.x / bpb, rg = blockIdx.x % bpb;
  const int b = bh >> 3, h = bh & 7;
  const u16t* qkvb = qkv + (size_t)b * NTOK * 384;

  for (int tok = t; tok < NTOK; tok += 256) {
    const u16t* vp = qkvb + (size_t)tok * 384 + 256 + h * 16;
    short8 v0 = *(const short8*)vp;
    short8 v1 = *(const short8*)(vp + 8);
#pragma unroll
    for (int d = 0; d < 8; ++d) {
      VT[d][tok]     = (u16t)v0[d];
      VT[d + 8][tok] = (u16t)v1[d];
    }
  }
  __syncthreads();

  const int i0 = rg * 64 + wv * 16;
  short8 qf = {0, 0, 0, 0, 0, 0, 0, 0};
  if (lq < 2)
    qf = *(const short8*)(qkvb + (size_t)(i0 + lr) * 384 + h * 16 + lq * 8);

  f32x4 oacc = {0.f, 0.f, 0.f, 0.f};
  f32x4 sacc = {0.f, 0.f, 0.f, 0.f};
  const f32x4 zero = {0.f, 0.f, 0.f, 0.f};
  float* shb = share + (size_t)bh * NTOK * NTOK;

  for (int t0 = 0; t0 < NTOK; t0 += 32) {
#pragma unroll
    for (int s2 = 0; s2 < 2; ++s2) {
      short8 kf = {0, 0, 0, 0, 0, 0, 0, 0};
      if (lq < 2)
        kf = *(const short8*)(qkvb + (size_t)(t0 + s2 * 16 + lr) * 384 + 128 + h * 16 + lq * 8);
      f32x4 e = __builtin_amdgcn_mfma_f32_16x16x32_bf16(qf, kf, zero, 0, 0, 0);
#pragma unroll
      for (int i = 0; i < 4; ++i) {
        const float ev = e[i] * 0.25f;
        __builtin_nontemporal_store(
            ev, shb + (size_t)(i0 + lq * 4 + i) * NTOK + t0 + s2 * 16 + lr);
        const float p = __expf(ev);
        sacc[i] += p;
        PB[wv][lq * 4 + i][s2 * 16 + lr] = f2b(p);
      }
    }
    asm volatile("s_waitcnt lgkmcnt(0)" ::: "memory");
    __builtin_amdgcn_sched_barrier(0);
    short8 pa = *(const short8*)&PB[wv][lr][lq * 8];
    short8 vf = *(const short8*)&VT[lr][t0 + lq * 8];
    oacc = __builtin_amdgcn_mfma_f32_16x16x32_bf16(pa, vf, oacc, 0, 0, 0);
    __builtin_amdgcn_sched_barrier(0);
  }
#pragma unroll
  for (int i = 0; i < 4; ++i) {
    float s = sacc[i];
    s += __shfl_xor(s, 1); s += __shfl_xor(s, 2);
    s += __shfl_xor(s, 4); s += __shfl_xor(s, 8);
    sacc[i] = s;
  }
#pragma unroll
  for (int i = 0; i < 4; ++i) {
    const float o = oacc[i] / sacc[i];
    outb[((size_t)(b * NTOK) + i0 + lq * 4 + i) * 128 + h * 16 + lr] = f2b(o);
  }
}

// ---------------- LayerNorm (input pre-summed), float4 vectorized ----------
template<int NT, bool B16>
__global__ __launch_bounds__(NT) void ln_vec(
    const float* __restrict__ xin, const float* __restrict__ g,
    const float* __restrict__ be, float* __restrict__ y32,
    u16t* __restrict__ y16, int D) {
  const int row = blockIdx.x, t = threadIdx.x;
  const int lane = t & 63;
  const float4 x = ((const float4*)xin)[(size_t)row * (D >> 2) + t];
  float s = x.x + x.y + x.z + x.w;
  float s2 = x.x * x.x + x.y * x.y + x.z * x.z + x.w * x.w;
#pragma unroll
  for (int off = 32; off; off >>= 1) {
    s  += __shfl_xor(s, off);
    s2 += __shfl_xor(s2, off);
  }
  if (NT == 128) {
    __shared__ float a1[2], a2[2];
    const int wv = t >> 6;
    if (lane == 0) { a1[wv] = s; a2[wv] = s2; }
    __syncthreads();
    s = a1[0] + a1[1]; s2 = a2[0] + a2[1];
  }
  const float mean = s / D;
  const float var  = s2 / D - mean * mean;
  const float rstd = rsqrtf(var + 1e-5f);
  const float4 gv = ((const float4*)g)[t];
  const float4 bv = ((const float4*)be)[t];
  float4 y;
  y.x = (x.x - mean) * rstd * gv.x + bv.x;
  y.y = (x.y - mean) * rstd * gv.y + bv.y;
  y.z = (x.z - mean) * rstd * gv.z + bv.z;
  y.w = (x.w - mean) * rstd * gv.w + bv.w;
  ((float4*)y32)[(size_t)row * (D >> 2) + t] = y;
  if (B16) {
    bf16x4 p;
    p[0] = (short)f2b(y.x); p[1] = (short)f2b(y.y);
    p[2] = (short)f2b(y.z); p[3] = (short)f2b(y.w);
    *(bf16x4*)&y16[(size_t)row * D + t * 4] = p;
  }
}

// ---------------- batched transpose [B][R][C]->[B][C][R], opt bf16 twin ----
template<bool BF16OUT, bool NTOUT>
__global__ void transp(const float* __restrict__ in, float* __restrict__ out32,
                       u16t* __restrict__ out16, int R, int C) {
  __shared__ float tile[32][33];
  const int b = blockIdx.z;
  const int r0 = blockIdx.y << 5, c0 = blockIdx.x << 5;
  const float* inb = in + (size_t)b * R * C;
  const int tx = threadIdx.x, ty = threadIdx.y;
#pragma unroll
  for (int dy = 0; dy < 32; dy += 8)
    tile[ty + dy][tx] = inb[(size_t)(r0 + ty + dy) * C + c0 + tx];
  __syncthreads();
#pragma unroll
  for (int dy = 0; dy < 32; dy += 8) {
    const float v = tile[tx][ty + dy];
    const size_t idx = (size_t)b * R * C + (size_t)(c0 + ty + dy) * R + r0 + tx;
    if (NTOUT) __builtin_nontemporal_store(v, out32 + idx);
    else       out32[idx] = v;
    if (BF16OUT) out16[idx] = f2b(v);
  }
}

// ---------------- one-shot prep -------------------------------------------
__global__ __launch_bounds__(256) void prep_all(
    const float* __restrict__ x0, u16t* __restrict__ x16,
    const float* __restrict__ wqkv1, u16t* __restrict__ tqkv1,
    const float* __restrict__ wo1,   u16t* __restrict__ two1,
    const float* __restrict__ ff1w1, u16t* __restrict__ tff1a,
    const float* __restrict__ ff1w2, u16t* __restrict__ tff1b,
    const float* __restrict__ wqkv2, u16t* __restrict__ tqkv2,
    const float* __restrict__ wo2,   u16t* __restrict__ two2,
    const float* __restrict__ ff2w1, u16t* __restrict__ tff2a,
    const float* __restrict__ ff2w2, u16t* __restrict__ tff2b,
    const float* __restrict__ ff1b1, float* __restrict__ bp1,
    const float* __restrict__ ff2b1, float* __restrict__ bp2) {
  __shared__ float tile[32][33];
  const int b = blockIdx.x, t = threadIdx.x;
  const int tx = t & 31, ty = t >> 5;
  const float* src; u16t* dst;
  int K, N, bxd, blk, halfN = 0; bool perm = false;
  if (b < 1024) {
    const float* p = x0 + (size_t)(b * 256 + t) * 8;
    short8 v;
#pragma unroll
    for (int j = 0; j < 8; ++j) v[j] = (short)f2b(p[j]);
    *(short8*)(x16 + (size_t)(b * 256 + t) * 8) = v;
    return;
  } else if (b < 1120) { src = wqkv1; dst = tqkv1; K = 256;  N = 384;  bxd = 12;  blk = b - 1024; }
  else if (b < 1152)   { src = wo1;   dst = two1;  K = 128;  N = 256;  bxd = 8;   blk = b - 1120; }
  else if (b < 1664)   { src = ff1w1; dst = tff1a; K = 256;  N = 2048; bxd = 64;  blk = b - 1152; perm = true; halfN = 1024; }
  else if (b < 1920)   { src = ff1w2; dst = tff1b; K = 1024; N = 256;  bxd = 8;   blk = b - 1664; }
  else if (b < 2112)   { src = wqkv2; dst = tqkv2; K = 512;  N = 384;  bxd = 12;  blk = b - 1920; }
  else if (b < 2176)   { src = wo2;   dst = two2;  K = 128;  N = 512;  bxd = 16;  blk = b - 2112; }
  else if (b < 4224)   { src = ff2w1; dst = tff2a; K = 512;  N = 4096; bxd = 128; blk = b - 2176; perm = true; halfN = 2048; }
  else if (b < 5248)   { src = ff2w2; dst = tff2b; K = 2048; N = 512;  bxd = 16;  blk = b - 4224; }
  else if (b < 5256) { const int n = (b - 5248) * 256 + t; bp1[n] = ff1b1[origcol(n, 1024)]; return; }
  else               { const int n = (b - 5256) * 256 + t; bp2[n] = ff2b1[origcol(n, 2048)]; return; }

  const int bx = blk % bxd, by = blk / bxd;
  const int n0 = bx * 32, k0 = by * 32;
  const int nn = n0 + tx;
  const int no = perm ? origcol(nn, halfN) : nn;
#pragma unroll
  for (int dy = 0; dy < 32; dy += 8)
    tile[ty + dy][tx] = src[(size_t)(k0 + ty + dy) * N + no];
  __syncthreads();
#pragma unroll
  for (int dy = 0; dy < 32; dy += 8)
    dst[(size_t)(n0 + ty + dy) * K + k0 + tx] = f2b(tile[tx][ty + dy]);
}

// ---------------------------------------------------------------------------
extern "C" void kernel_launch(void* const* d_in, const int* in_sizes, int n_in,
                              void* d_out, int out_size, void* d_ws, size_t ws_size,
                              hipStream_t stream) {
  (void)in_sizes; (void)n_in; (void)out_size; (void)ws_size;
  const float* x0    = (const float*)d_in[0];
  const float* wqkv1 = (const float*)d_in[1];
  const float* wo1   = (const float*)d_in[2];
  const float* bo1   = (const float*)d_in[3];
  const float* ff1w1 = (const float*)d_in[4];
  const float* ff1b1 = (const float*)d_in[5];
  const float* ff1w2 = (const float*)d_in[6];
  const float* ff1b2 = (const float*)d_in[7];
  const float* wqkv2 = (const float*)d_in[8];
  const float* wo2   = (const float*)d_in[9];
  const float* bo2   = (const float*)d_in[10];
  const float* ff2w1 = (const float*)d_in[11];
  const float* ff2b1 = (const float*)d_in[12];
  const float* ff2w2 = (const float*)d_in[13];
  const float* ff2b2 = (const float*)d_in[14];
  const float* ln1g  = (const float*)d_in[15];
  const float* ln1b  = (const float*)d_in[16];
  const float* ln2g  = (const float*)d_in[17];
  const float* ln2b  = (const float*)d_in[18];
  const float* ln3g  = (const float*)d_in[19];
  const float* ln3b  = (const float*)d_in[20];
  const float* ln4g  = (const float*)d_in[21];
  const float* ln4b  = (const float*)d_in[22];

  float* out_x  = (float*)d_out;
  float* share1 = out_x + (size_t)2097152;
  float* share2 = share1 + (size_t)33554432;

  size_t off = 0;
  auto carve = [&](size_t bytes) -> void* {
    void* p = (char*)d_ws + off;
    off += (bytes + 255) & ~(size_t)255;
    return p;
  };
  u16t*  x16    = (u16t*)carve((size_t)8192 * 256 * 2);
  u16t*  qkv16  = (u16t*)carve((size_t)8192 * 384 * 2);
  u16t*  attn16 = (u16t*)carve((size_t)8192 * 128 * 2);
  float* sumb   = (float*)carve((size_t)8192 * 256 * 4);
  float* xa32   = (float*)carve((size_t)8192 * 256 * 4);
  u16t*  xa16   = (u16t*)carve((size_t)8192 * 256 * 2);
  float* xb32   = (float*)carve((size_t)8192 * 256 * 4);
  float* xt32   = (float*)carve((size_t)8192 * 256 * 4);
  u16t*  xt16   = (u16t*)carve((size_t)8192 * 256 * 2);
  float* xc32   = (float*)carve((size_t)8192 * 256 * 4);
  u16t*  xc16   = (u16t*)carve((size_t)8192 * 256 * 2);
  float* xd32   = (float*)carve((size_t)8192 * 256 * 4);
  u16t*  ubuf   = (u16t*)carve((size_t)8192 * 1024 * 2);
  u16t*  tqkv1  = (u16t*)carve((size_t)384 * 256 * 2);
  u16t*  two1   = (u16t*)carve((size_t)256 * 128 * 2);
  u16t*  tff1a  = (u16t*)carve((size_t)2048 * 256 * 2);
  u16t*  tff1b  = (u16t*)carve((size_t)256 * 1024 * 2);
  u16t*  tqkv2  = (u16t*)carve((size_t)384 * 512 * 2);
  u16t*  two2   = (u16t*)carve((size_t)512 * 128 * 2);
  u16t*  tff2a  = (u16t*)carve((size_t)4096 * 512 * 2);
  u16t*  tff2b  = (u16t*)carve((size_t)512 * 2048 * 2);
  float* bp1    = (float*)carve((size_t)2048 * 4);
  float* bp2    = (float*)carve((size_t)4096 * 4);

  prep_all<<<5272, 256, 0, stream>>>(x0, x16, wqkv1, tqkv1, wo1, two1,
      ff1w1, tff1a, ff1w2, tff1b, wqkv2, tqkv2, wo2, two2,
      ff2w1, tff2a, ff2w2, tff2b, ff1b1, bp1, ff2b1, bp2);

  // ---- stage 1 (tokens=512, feat=256) ----
  mgemm64<0><<<dim3(6, 128), 256, 0, stream>>>(x16, tqkv1, nullptr, nullptr, qkv16, 8192, 384, 256);
  attn_mfma<512><<<1024, 256, 0, stream>>>(qkv16, share1, attn16);
  mgemm64<1><<<dim3(4, 128), 256, 0, stream>>>(attn16, two1, bo1, x0, sumb, 8192, 256, 128);
  ln_vec<64, true><<<8192, 64, 0, stream>>>(sumb, ln1g, ln1b, xa32, xa16, 256);
  mgemm<2><<<dim3(16, 64), 256, 0, stream>>>(xa16, tff1a, bp1, nullptr, ubuf, 8192, 2048, 256);
  mgemm64<1><<<dim3(4, 128), 256, 0, stream>>>(ubuf, tff1b, ff1b2, xa32, sumb, 8192, 256, 1024);
  ln_vec<64, false><<<8192, 64, 0, stream>>>(sumb, ln2g, ln2b, xb32, nullptr, 256);

  // ---- transpose to [B,256,512] ----
  transp<true, false><<<dim3(8, 16, 16), dim3(32, 8), 0, stream>>>(xb32, xt32, xt16, 512, 256);

  // ---- stage 2 (tokens=256, feat=512) ----
  mgemm64<0><<<dim3(6, 64), 256, 0, stream>>>(xt16, tqkv2, nullptr, nullptr, qkv16, 4096, 384, 512);
  attn_mfma<256><<<512, 256, 0, stream>>>(qkv16, share2, attn16);
  mgemm64<1><<<dim3(8, 64), 256, 0, stream>>>(attn16, two2, bo2, xt32, sumb, 4096, 512, 128);
  ln_vec<128, true><<<4096, 128, 0, stream>>>(sumb, ln3g, ln3b, xc32, xc16, 512);
  mgemm<2><<<dim3(32, 32), 256, 0, stream>>>(xc16, tff2a, bp2, nullptr, ubuf, 4096, 4096, 512);
  mgemm64<1><<<dim3(8, 64), 256, 0, stream>>>(ubuf, tff2b, ff2b2, xc32, sumb, 4096, 512, 2048);
  ln_vec<128, false><<<4096, 128, 0, stream>>>(sumb, ln4g, ln4b, xd32, nullptr, 512);

  // ---- transpose back -> out ----
  transp<false, true><<<dim3(16, 8, 16), dim3(32, 8), 0, stream>>>(xd32, out_x, nullptr, 256, 512);
}

// Round 8
// 227.412 us; speedup vs baseline: 1.0512x; 1.0512x over previous
//
#include <hip/hip_runtime.h>
#include <cstddef>

// ---------------------------------------------------------------------------
// B=16, N=512, D=256, H=8, DH=16, INNER=128, SCALE=0.25
// R5 structure (best: 215.6us). One isolated change vs R5: non-temporal
// stores on share1/share2 energy writes ONLY (never re-read; keeps L2 for
// the qkv K/V panels attn actively re-reads). 17 launches.
// ---------------------------------------------------------------------------

typedef __attribute__((ext_vector_type(8))) short short8;
typedef __attribute__((ext_vector_type(4))) short bf16x4;
typedef __attribute__((ext_vector_type(4))) float f32x4;
typedef unsigned short u16t;

__device__ __forceinline__ u16t f2b(float f) {           // fp32 -> bf16 (RNE)
  union { float f; unsigned u; } x; x.f = f;
  unsigned r = (x.u + 0x7fffu + ((x.u >> 16) & 1u)) >> 16;
  return (u16t)r;
}

__device__ __forceinline__ void gload16(const void* g, void* l) {
  __builtin_amdgcn_global_load_lds(
      (const __attribute__((address_space(1))) void*)g,
      (__attribute__((address_space(3))) void*)l, 16, 0, 0);
}

// exact-GELU via Abramowitz-Stegun 7.1.26 erf (max abs err 1.5e-7)
__device__ __forceinline__ float gelu_f(float g) {
  const float x = g * 0.70710678118654752f;
  const float ax = fabsf(x);
  const float t = 1.f / (1.f + 0.3275911f * ax);
  const float p = t * (0.254829592f + t * (-0.284496736f +
                  t * (1.421413741f + t * (-1.453152027f + t * 1.061405429f))));
  const float er = 1.f - p * __expf(-x * x);
  return 0.5f * g * (1.f + copysignf(er, x));
}

// GEGLU weight-column permutation: n_new -> n_orig.
__device__ __forceinline__ int origcol(int n, int halfN) {
  const int nb = n >> 7, s = (n >> 4) & 7, r = n & 15;
  return ((s & 1) ? halfN : 0) + (nb << 6) + ((s >> 1) << 4) + r;
}

// ---------------- 128x128 MFMA GEMM (EPI 2 = fused GEGLU) ------------------
template<int EPI>
__global__ __launch_bounds__(256) void mgemm(
    const u16t* __restrict__ A, const u16t* __restrict__ BT,
    const float* __restrict__ bias, const float* __restrict__ res,
    void* __restrict__ C, int M, int N, int K) {
  __shared__ u16t Al[128 * 32];
  __shared__ u16t Bl[128 * 32];
  const int t = threadIdx.x, lane = t & 63, wid = t >> 6;
  const int wr = wid >> 1, wc = wid & 1;
  const int lr = lane & 15, lq = lane >> 4;
  const int bm = blockIdx.y << 7, bn = blockIdx.x << 7;

  const int ao0 = wid * 2048 + lane * 16;
  const int ar0 = ao0 >> 6,          ac0 = (ao0 & 63) >> 1;
  const int ar1 = (ao0 + 1024) >> 6, ac1 = ((ao0 + 1024) & 63) >> 1;

  const u16t* Ab = A + (size_t)bm * K;
  const u16t* Bb = BT + (size_t)bn * K;

  f32x4 acc[4][4];
#pragma unroll
  for (int m = 0; m < 4; ++m)
#pragma unroll
    for (int n = 0; n < 4; ++n) acc[m][n] = (f32x4){0.f, 0.f, 0.f, 0.f};

  for (int k0 = 0; k0 < K; k0 += 32) {
    gload16(Ab + (size_t)ar0 * K + k0 + ac0, (char*)Al + wid * 2048);
    gload16(Ab + (size_t)ar1 * K + k0 + ac1, (char*)Al + wid * 2048 + 1024);
    gload16(Bb + (size_t)ar0 * K + k0 + ac0, (char*)Bl + wid * 2048);
    gload16(Bb + (size_t)ar1 * K + k0 + ac1, (char*)Bl + wid * 2048 + 1024);
    __syncthreads();
    short8 af[4], bf[4];
#pragma unroll
    for (int m = 0; m < 4; ++m)
      af[m] = *(const short8*)&Al[(wr * 64 + m * 16 + lr) * 32 + lq * 8];
#pragma unroll
    for (int n = 0; n < 4; ++n)
      bf[n] = *(const short8*)&Bl[(wc * 64 + n * 16 + lr) * 32 + lq * 8];
#pragma unroll
    for (int m = 0; m < 4; ++m)
#pragma unroll
      for (int n = 0; n < 4; ++n)
        acc[m][n] = __builtin_amdgcn_mfma_f32_16x16x32_bf16(af[m], bf[n], acc[m][n], 0, 0, 0);
    __syncthreads();
  }

  if (EPI == 2) {                    // fused bias + GEGLU (permuted cols)
    const int Nh = N >> 1;
#pragma unroll
    for (int np = 0; np < 2; ++np) {
      const int ca = bn + wc * 64 + np * 32 + lr;
      const float ba = bias[ca], bg = bias[ca + 16];
      const int uc = (bn >> 1) + wc * 32 + np * 16 + lr;
#pragma unroll
      for (int m = 0; m < 4; ++m) {
#pragma unroll
        for (int i = 0; i < 4; ++i) {
          const int row = bm + wr * 64 + m * 16 + lq * 4 + i;
          const float a = acc[m][2 * np][i] + ba;
          const float g = acc[m][2 * np + 1][i] + bg;
          ((u16t*)C)[(size_t)row * Nh + uc] = f2b(a * gelu_f(g));
        }
      }
    }
  } else {
#pragma unroll
    for (int n = 0; n < 4; ++n) {
      const int col = bn + wc * 64 + n * 16 + lr;
      const float bv = bias ? bias[col] : 0.f;
#pragma unroll
      for (int m = 0; m < 4; ++m) {
#pragma unroll
        for (int i = 0; i < 4; ++i) {
          const int row = bm + wr * 64 + m * 16 + lq * 4 + i;
          float v = acc[m][n][i] + bv;
          if (EPI == 1) {
            v += res[(size_t)row * N + col];
            ((float*)C)[(size_t)row * N + col] = v;
          } else {
            ((u16t*)C)[(size_t)row * N + col] = f2b(v);
          }
        }
      }
    }
  }
}

// ---------------- 64x64 MFMA GEMM for thin shapes (occupancy) --------------
template<int EPI>
__global__ __launch_bounds__(256) void mgemm64(
    const u16t* __restrict__ A, const u16t* __restrict__ BT,
    const float* __restrict__ bias, const float* __restrict__ res,
    void* __restrict__ C, int M, int N, int K) {
  __shared__ u16t Al[64 * 32];       // 4 KB
  __shared__ u16t Bl[64 * 32];
  const int t = threadIdx.x, lane = t & 63, wid = t >> 6;
  const int wr = wid >> 1, wc = wid & 1;
  const int lr = lane & 15, lq = lane >> 4;
  const int bm = blockIdx.y << 6, bn = blockIdx.x << 6;
  const int ch = wid * 64 + lane;
  const int crow = ch >> 2, ccol = (ch & 3) << 3;

  const u16t* Ab = A + (size_t)bm * K;
  const u16t* Bb = BT + (size_t)bn * K;

  f32x4 acc[2][2];
#pragma unroll
  for (int m = 0; m < 2; ++m)
#pragma unroll
    for (int n = 0; n < 2; ++n) acc[m][n] = (f32x4){0.f, 0.f, 0.f, 0.f};

  for (int k0 = 0; k0 < K; k0 += 32) {
    gload16(Ab + (size_t)crow * K + k0 + ccol, (char*)Al + wid * 1024);
    gload16(Bb + (size_t)crow * K + k0 + ccol, (char*)Bl + wid * 1024);
    __syncthreads();
    short8 af[2], bf[2];
#pragma unroll
    for (int m = 0; m < 2; ++m)
      af[m] = *(const short8*)&Al[(wr * 32 + m * 16 + lr) * 32 + lq * 8];
#pragma unroll
    for (int n = 0; n < 2; ++n)
      bf[n] = *(const short8*)&Bl[(wc * 32 + n * 16 + lr) * 32 + lq * 8];
#pragma unroll
    for (int m = 0; m < 2; ++m)
#pragma unroll
      for (int n = 0; n < 2; ++n)
        acc[m][n] = __builtin_amdgcn_mfma_f32_16x16x32_bf16(af[m], bf[n], acc[m][n], 0, 0, 0);
    __syncthreads();
  }

#pragma unroll
  for (int n = 0; n < 2; ++n) {
    const int col = bn + wc * 32 + n * 16 + lr;
    const float bv = bias ? bias[col] : 0.f;
#pragma unroll
    for (int m = 0; m < 2; ++m) {
#pragma unroll
      for (int i = 0; i < 4; ++i) {
        const int row = bm + wr * 32 + m * 16 + lq * 4 + i;
        float v = acc[m][n][i] + bv;
        if (EPI == 1) {
          v += res[(size_t)row * N + col];
          ((float*)C)[(size_t)row * N + col] = v;
        } else {
          ((u16t*)C)[(size_t)row * N + col] = f2b(v);
        }
      }
    }
  }
}

// ---------------- MFMA attention (share via NT stores — never re-read) -----
template<int NTOK>
__global__ __launch_bounds__(256) void attn_mfma(
    const u16t* __restrict__ qkv, float* __restrict__ share,
    u16t* __restrict__ outb) {
  __shared__ u16t VT[16][NTOK + 40];
  __shared__ u16t PB[4][16][40];
  const int t = threadIdx.x, lane = t & 63, wv = t >> 6;
  const int lr = lane & 15, lq = lane >> 4;
  const int bpb = NTOK / 64;
  const int bh = blockIdx.x / bpb, rg = blockIdx.x % bpb;
  const int b = bh >> 3, h = bh & 7;
  const u16t* qkvb = qkv + (size_t)b * NTOK * 384;

  for (int tok = t; tok < NTOK; tok += 256) {
    const u16t* vp = qkvb + (size_t)tok * 384 + 256 + h * 16;
    short8 v0 = *(const short8*)vp;
    short8 v1 = *(const short8*)(vp + 8);
#pragma unroll
    for (int d = 0; d < 8; ++d) {
      VT[d][tok]     = (u16t)v0[d];
      VT[d + 8][tok] = (u16t)v1[d];
    }
  }
  __syncthreads();

  const int i0 = rg * 64 + wv * 16;
  short8 qf = {0, 0, 0, 0, 0, 0, 0, 0};
  if (lq < 2)
    qf = *(const short8*)(qkvb + (size_t)(i0 + lr) * 384 + h * 16 + lq * 8);

  f32x4 oacc = {0.f, 0.f, 0.f, 0.f};
  f32x4 sacc = {0.f, 0.f, 0.f, 0.f};
  const f32x4 zero = {0.f, 0.f, 0.f, 0.f};
  float* shb = share + (size_t)bh * NTOK * NTOK;

  for (int t0 = 0; t0 < NTOK; t0 += 32) {
#pragma unroll
    for (int s2 = 0; s2 < 2; ++s2) {
      short8 kf = {0, 0, 0, 0, 0, 0, 0, 0};
      if (lq < 2)
        kf = *(const short8*)(qkvb + (size_t)(t0 + s2 * 16 + lr) * 384 + 128 + h * 16 + lq * 8);
      f32x4 e = __builtin_amdgcn_mfma_f32_16x16x32_bf16(qf, kf, zero, 0, 0, 0);
#pragma unroll
      for (int i = 0; i < 4; ++i) {
        const float ev = e[i] * 0.25f;
        __builtin_nontemporal_store(
            ev, shb + (size_t)(i0 + lq * 4 + i) * NTOK + t0 + s2 * 16 + lr);
        const float p = __expf(ev);
        sacc[i] += p;
        PB[wv][lq * 4 + i][s2 * 16 + lr] = f2b(p);
      }
    }
    asm volatile("s_waitcnt lgkmcnt(0)" ::: "memory");
    __builtin_amdgcn_sched_barrier(0);
    short8 pa = *(const short8*)&PB[wv][lr][lq * 8];
    short8 vf = *(const short8*)&VT[lr][t0 + lq * 8];
    oacc = __builtin_amdgcn_mfma_f32_16x16x32_bf16(pa, vf, oacc, 0, 0, 0);
    __builtin_amdgcn_sched_barrier(0);
  }
#pragma unroll
  for (int i = 0; i < 4; ++i) {
    float s = sacc[i];
    s += __shfl_xor(s, 1); s += __shfl_xor(s, 2);
    s += __shfl_xor(s, 4); s += __shfl_xor(s, 8);
    sacc[i] = s;
  }
#pragma unroll
  for (int i = 0; i < 4; ++i) {
    const float o = oacc[i] / sacc[i];
    outb[((size_t)(b * NTOK) + i0 + lq * 4 + i) * 128 + h * 16 + lr] = f2b(o);
  }
}

// ---------------- LayerNorm (input pre-summed), float4 vectorized ----------
template<int NT, bool B16>
__global__ __launch_bounds__(NT) void ln_vec(
    const float* __restrict__ xin, const float* __restrict__ g,
    const float* __restrict__ be, float* __restrict__ y32,
    u16t* __restrict__ y16, int D) {
  const int row = blockIdx.x, t = threadIdx.x;
  const int lane = t & 63;
  const float4 x = ((const float4*)xin)[(size_t)row * (D >> 2) + t];
  float s = x.x + x.y + x.z + x.w;
  float s2 = x.x * x.x + x.y * x.y + x.z * x.z + x.w * x.w;
#pragma unroll
  for (int off = 32; off; off >>= 1) {
    s  += __shfl_xor(s, off);
    s2 += __shfl_xor(s2, off);
  }
  if (NT == 128) {
    __shared__ float a1[2], a2[2];
    const int wv = t >> 6;
    if (lane == 0) { a1[wv] = s; a2[wv] = s2; }
    __syncthreads();
    s = a1[0] + a1[1]; s2 = a2[0] + a2[1];
  }
  const float mean = s / D;
  const float var  = s2 / D - mean * mean;
  const float rstd = rsqrtf(var + 1e-5f);
  const float4 gv = ((const float4*)g)[t];
  const float4 bv = ((const float4*)be)[t];
  float4 y;
  y.x = (x.x - mean) * rstd * gv.x + bv.x;
  y.y = (x.y - mean) * rstd * gv.y + bv.y;
  y.z = (x.z - mean) * rstd * gv.z + bv.z;
  y.w = (x.w - mean) * rstd * gv.w + bv.w;
  ((float4*)y32)[(size_t)row * (D >> 2) + t] = y;
  if (B16) {
    bf16x4 p;
    p[0] = (short)f2b(y.x); p[1] = (short)f2b(y.y);
    p[2] = (short)f2b(y.z); p[3] = (short)f2b(y.w);
    *(bf16x4*)&y16[(size_t)row * D + t * 4] = p;
  }
}

// ---------------- batched transpose [B][R][C]->[B][C][R], opt bf16 twin ----
template<bool BF16OUT>
__global__ void transp(const float* __restrict__ in, float* __restrict__ out32,
                       u16t* __restrict__ out16, int R, int C) {
  __shared__ float tile[32][33];
  const int b = blockIdx.z;
  const int r0 = blockIdx.y << 5, c0 = blockIdx.x << 5;
  const float* inb = in + (size_t)b * R * C;
  const int tx = threadIdx.x, ty = threadIdx.y;
#pragma unroll
  for (int dy = 0; dy < 32; dy += 8)
    tile[ty + dy][tx] = inb[(size_t)(r0 + ty + dy) * C + c0 + tx];
  __syncthreads();
#pragma unroll
  for (int dy = 0; dy < 32; dy += 8) {
    const float v = tile[tx][ty + dy];
    const size_t idx = (size_t)b * R * C + (size_t)(c0 + ty + dy) * R + r0 + tx;
    out32[idx] = v;
    if (BF16OUT) out16[idx] = f2b(v);
  }
}

// ---------------- one-shot prep -------------------------------------------
__global__ __launch_bounds__(256) void prep_all(
    const float* __restrict__ x0, u16t* __restrict__ x16,
    const float* __restrict__ wqkv1, u16t* __restrict__ tqkv1,
    const float* __restrict__ wo1,   u16t* __restrict__ two1,
    const float* __restrict__ ff1w1, u16t* __restrict__ tff1a,
    const float* __restrict__ ff1w2, u16t* __restrict__ tff1b,
    const float* __restrict__ wqkv2, u16t* __restrict__ tqkv2,
    const float* __restrict__ wo2,   u16t* __restrict__ two2,
    const float* __restrict__ ff2w1, u16t* __restrict__ tff2a,
    const float* __restrict__ ff2w2, u16t* __restrict__ tff2b,
    const float* __restrict__ ff1b1, float* __restrict__ bp1,
    const float* __restrict__ ff2b1, float* __restrict__ bp2) {
  __shared__ float tile[32][33];
  const int b = blockIdx.x, t = threadIdx.x;
  const int tx = t & 31, ty = t >> 5;
  const float* src; u16t* dst;
  int K, N, bxd, blk, halfN = 0; bool perm = false;
  if (b < 1024) {
    const float* p = x0 + (size_t)(b * 256 + t) * 8;
    short8 v;
#pragma unroll
    for (int j = 0; j < 8; ++j) v[j] = (short)f2b(p[j]);
    *(short8*)(x16 + (size_t)(b * 256 + t) * 8) = v;
    return;
  } else if (b < 1120) { src = wqkv1; dst = tqkv1; K = 256;  N = 384;  bxd = 12;  blk = b - 1024; }
  else if (b < 1152)   { src = wo1;   dst = two1;  K = 128;  N = 256;  bxd = 8;   blk = b - 1120; }
  else if (b < 1664)   { src = ff1w1; dst = tff1a; K = 256;  N = 2048; bxd = 64;  blk = b - 1152; perm = true; halfN = 1024; }
  else if (b < 1920)   { src = ff1w2; dst = tff1b; K = 1024; N = 256;  bxd = 8;   blk = b - 1664; }
  else if (b < 2112)   { src = wqkv2; dst = tqkv2; K = 512;  N = 384;  bxd = 12;  blk = b - 1920; }
  else if (b < 2176)   { src = wo2;   dst = two2;  K = 128;  N = 512;  bxd = 16;  blk = b - 2112; }
  else if (b < 4224)   { src = ff2w1; dst = tff2a; K = 512;  N = 4096; bxd = 128; blk = b - 2176; perm = true; halfN = 2048; }
  else if (b < 5248)   { src = ff2w2; dst = tff2b; K = 2048; N = 512;  bxd = 16;  blk = b - 4224; }
  else if (b < 5256) { const int n = (b - 5248) * 256 + t; bp1[n] = ff1b1[origcol(n, 1024)]; return; }
  else               { const int n = (b - 5256) * 256 + t; bp2[n] = ff2b1[origcol(n, 2048)]; return; }

  const int bx = blk % bxd, by = blk / bxd;
  const int n0 = bx * 32, k0 = by * 32;
  const int nn = n0 + tx;
  const int no = perm ? origcol(nn, halfN) : nn;
#pragma unroll
  for (int dy = 0; dy < 32; dy += 8)
    tile[ty + dy][tx] = src[(size_t)(k0 + ty + dy) * N + no];
  __syncthreads();
#pragma unroll
  for (int dy = 0; dy < 32; dy += 8)
    dst[(size_t)(n0 + ty + dy) * K + k0 + tx] = f2b(tile[tx][ty + dy]);
}

// ---------------------------------------------------------------------------
extern "C" void kernel_launch(void* const* d_in, const int* in_sizes, int n_in,
                              void* d_out, int out_size, void* d_ws, size_t ws_size,
                              hipStream_t stream) {
  (void)in_sizes; (void)n_in; (void)out_size; (void)ws_size;
  const float* x0    = (const float*)d_in[0];
  const float* wqkv1 = (const float*)d_in[1];
  const float* wo1   = (const float*)d_in[2];
  const float* bo1   = (const float*)d_in[3];
  const float* ff1w1 = (const float*)d_in[4];
  const float* ff1b1 = (const float*)d_in[5];
  const float* ff1w2 = (const float*)d_in[6];
  const float* ff1b2 = (const float*)d_in[7];
  const float* wqkv2 = (const float*)d_in[8];
  const float* wo2   = (const float*)d_in[9];
  const float* bo2   = (const float*)d_in[10];
  const float* ff2w1 = (const float*)d_in[11];
  const float* ff2b1 = (const float*)d_in[12];
  const float* ff2w2 = (const float*)d_in[13];
  const float* ff2b2 = (const float*)d_in[14];
  const float* ln1g  = (const float*)d_in[15];
  const float* ln1b  = (const float*)d_in[16];
  const float* ln2g  = (const float*)d_in[17];
  const float* ln2b  = (const float*)d_in[18];
  const float* ln3g  = (const float*)d_in[19];
  const float* ln3b  = (const float*)d_in[20];
  const float* ln4g  = (const float*)d_in[21];
  const float* ln4b  = (const float*)d_in[22];

  float* out_x  = (float*)d_out;
  float* share1 = out_x + (size_t)2097152;
  float* share2 = share1 + (size_t)33554432;

  size_t off = 0;
  auto carve = [&](size_t bytes) -> void* {
    void* p = (char*)d_ws + off;
    off += (bytes + 255) & ~(size_t)255;
    return p;
  };
  u16t*  x16    = (u16t*)carve((size_t)8192 * 256 * 2);
  u16t*  qkv16  = (u16t*)carve((size_t)8192 * 384 * 2);
  u16t*  attn16 = (u16t*)carve((size_t)8192 * 128 * 2);
  float* sumb   = (float*)carve((size_t)8192 * 256 * 4);
  float* xa32   = (float*)carve((size_t)8192 * 256 * 4);
  u16t*  xa16   = (u16t*)carve((size_t)8192 * 256 * 2);
  float* xb32   = (float*)carve((size_t)8192 * 256 * 4);
  float* xt32   = (float*)carve((size_t)8192 * 256 * 4);
  u16t*  xt16   = (u16t*)carve((size_t)8192 * 256 * 2);
  float* xc32   = (float*)carve((size_t)8192 * 256 * 4);
  u16t*  xc16   = (u16t*)carve((size_t)8192 * 256 * 2);
  float* xd32   = (float*)carve((size_t)8192 * 256 * 4);
  u16t*  ubuf   = (u16t*)carve((size_t)8192 * 1024 * 2);
  u16t*  tqkv1  = (u16t*)carve((size_t)384 * 256 * 2);
  u16t*  two1   = (u16t*)carve((size_t)256 * 128 * 2);
  u16t*  tff1a  = (u16t*)carve((size_t)2048 * 256 * 2);
  u16t*  tff1b  = (u16t*)carve((size_t)256 * 1024 * 2);
  u16t*  tqkv2  = (u16t*)carve((size_t)384 * 512 * 2);
  u16t*  two2   = (u16t*)carve((size_t)512 * 128 * 2);
  u16t*  tff2a  = (u16t*)carve((size_t)4096 * 512 * 2);
  u16t*  tff2b  = (u16t*)carve((size_t)512 * 2048 * 2);
  float* bp1    = (float*)carve((size_t)2048 * 4);
  float* bp2    = (float*)carve((size_t)4096 * 4);

  prep_all<<<5272, 256, 0, stream>>>(x0, x16, wqkv1, tqkv1, wo1, two1,
      ff1w1, tff1a, ff1w2, tff1b, wqkv2, tqkv2, wo2, two2,
      ff2w1, tff2a, ff2w2, tff2b, ff1b1, bp1, ff2b1, bp2);

  // ---- stage 1 (tokens=512, feat=256) ----
  mgemm64<0><<<dim3(6, 128), 256, 0, stream>>>(x16, tqkv1, nullptr, nullptr, qkv16, 8192, 384, 256);
  attn_mfma<512><<<1024, 256, 0, stream>>>(qkv16, share1, attn16);
  mgemm64<1><<<dim3(4, 128), 256, 0, stream>>>(attn16, two1, bo1, x0, sumb, 8192, 256, 128);
  ln_vec<64, true><<<8192, 64, 0, stream>>>(sumb, ln1g, ln1b, xa32, xa16, 256);
  mgemm<2><<<dim3(16, 64), 256, 0, stream>>>(xa16, tff1a, bp1, nullptr, ubuf, 8192, 2048, 256);
  mgemm64<1><<<dim3(4, 128), 256, 0, stream>>>(ubuf, tff1b, ff1b2, xa32, sumb, 8192, 256, 1024);
  ln_vec<64, false><<<8192, 64, 0, stream>>>(sumb, ln2g, ln2b, xb32, nullptr, 256);

  // ---- transpose to [B,256,512] ----
  transp<true><<<dim3(8, 16, 16), dim3(32, 8), 0, stream>>>(xb32, xt32, xt16, 512, 256);

  // ---- stage 2 (tokens=256, feat=512) ----
  mgemm64<0><<<dim3(6, 64), 256, 0, stream>>>(xt16, tqkv2, nullptr, nullptr, qkv16, 4096, 384, 512);
  attn_mfma<256><<<512, 256, 0, stream>>>(qkv16, share2, attn16);
  mgemm64<1><<<dim3(8, 64), 256, 0, stream>>>(attn16, two2, bo2, xt32, sumb, 4096, 512, 128);
  ln_vec<128, true><<<4096, 128, 0, stream>>>(sumb, ln3g, ln3b, xc32, xc16, 512);
  mgemm<2><<<dim3(32, 32), 256, 0, stream>>>(xc16, tff2a, bp2, nullptr, ubuf, 4096, 4096, 512);
  mgemm64<1><<<dim3(8, 64), 256, 0, stream>>>(ubuf, tff2b, ff2b2, xc32, sumb, 4096, 512, 2048);
  ln_vec<128, false><<<4096, 128, 0, stream>>>(sumb, ln4g, ln4b, xd32, nullptr, 512);

  // ---- transpose back -> out ----
  transp<false><<<dim3(16, 8, 16), dim3(32, 8), 0, stream>>>(xd32, out_x, nullptr, 256, 512);
}

// Round 9
// 215.674 us; speedup vs baseline: 1.1084x; 1.0544x over previous
//
#include <hip/hip_runtime.h>
#include <cstddef>

// ---------------------------------------------------------------------------
// B=16, N=512, D=256, H=8, DH=16, INNER=128, SCALE=0.25
// R5 base (best: 215.6us, no NT stores) + wo-projection+LayerNorm fusion
// via stage-once full-B-in-LDS GEMM (K=128, no K-loop restaging).
// 16 launches.
// ---------------------------------------------------------------------------

typedef __attribute__((ext_vector_type(8))) short short8;
typedef __attribute__((ext_vector_type(4))) short bf16x4;
typedef __attribute__((ext_vector_type(4))) float f32x4;
typedef unsigned short u16t;

__device__ __forceinline__ u16t f2b(float f) {           // fp32 -> bf16 (RNE)
  union { float f; unsigned u; } x; x.f = f;
  unsigned r = (x.u + 0x7fffu + ((x.u >> 16) & 1u)) >> 16;
  return (u16t)r;
}

__device__ __forceinline__ void gload16(const void* g, void* l) {
  __builtin_amdgcn_global_load_lds(
      (const __attribute__((address_space(1))) void*)g,
      (__attribute__((address_space(3))) void*)l, 16, 0, 0);
}

// exact-GELU via Abramowitz-Stegun 7.1.26 erf (max abs err 1.5e-7)
__device__ __forceinline__ float gelu_f(float g) {
  const float x = g * 0.70710678118654752f;
  const float ax = fabsf(x);
  const float t = 1.f / (1.f + 0.3275911f * ax);
  const float p = t * (0.254829592f + t * (-0.284496736f +
                  t * (1.421413741f + t * (-1.453152027f + t * 1.061405429f))));
  const float er = 1.f - p * __expf(-x * x);
  return 0.5f * g * (1.f + copysignf(er, x));
}

// GEGLU weight-column permutation: n_new -> n_orig.
__device__ __forceinline__ int origcol(int n, int halfN) {
  const int nb = n >> 7, s = (n >> 4) & 7, r = n & 15;
  return ((s & 1) ? halfN : 0) + (nb << 6) + ((s >> 1) << 4) + r;
}

// ---------------- 128x128 MFMA GEMM (EPI 2 = fused GEGLU) ------------------
template<int EPI>
__global__ __launch_bounds__(256) void mgemm(
    const u16t* __restrict__ A, const u16t* __restrict__ BT,
    const float* __restrict__ bias, const float* __restrict__ res,
    void* __restrict__ C, int M, int N, int K) {
  __shared__ u16t Al[128 * 32];
  __shared__ u16t Bl[128 * 32];
  const int t = threadIdx.x, lane = t & 63, wid = t >> 6;
  const int wr = wid >> 1, wc = wid & 1;
  const int lr = lane & 15, lq = lane >> 4;
  const int bm = blockIdx.y << 7, bn = blockIdx.x << 7;

  const int ao0 = wid * 2048 + lane * 16;
  const int ar0 = ao0 >> 6,          ac0 = (ao0 & 63) >> 1;
  const int ar1 = (ao0 + 1024) >> 6, ac1 = ((ao0 + 1024) & 63) >> 1;

  const u16t* Ab = A + (size_t)bm * K;
  const u16t* Bb = BT + (size_t)bn * K;

  f32x4 acc[4][4];
#pragma unroll
  for (int m = 0; m < 4; ++m)
#pragma unroll
    for (int n = 0; n < 4; ++n) acc[m][n] = (f32x4){0.f, 0.f, 0.f, 0.f};

  for (int k0 = 0; k0 < K; k0 += 32) {
    gload16(Ab + (size_t)ar0 * K + k0 + ac0, (char*)Al + wid * 2048);
    gload16(Ab + (size_t)ar1 * K + k0 + ac1, (char*)Al + wid * 2048 + 1024);
    gload16(Bb + (size_t)ar0 * K + k0 + ac0, (char*)Bl + wid * 2048);
    gload16(Bb + (size_t)ar1 * K + k0 + ac1, (char*)Bl + wid * 2048 + 1024);
    __syncthreads();
    short8 af[4], bf[4];
#pragma unroll
    for (int m = 0; m < 4; ++m)
      af[m] = *(const short8*)&Al[(wr * 64 + m * 16 + lr) * 32 + lq * 8];
#pragma unroll
    for (int n = 0; n < 4; ++n)
      bf[n] = *(const short8*)&Bl[(wc * 64 + n * 16 + lr) * 32 + lq * 8];
#pragma unroll
    for (int m = 0; m < 4; ++m)
#pragma unroll
      for (int n = 0; n < 4; ++n)
        acc[m][n] = __builtin_amdgcn_mfma_f32_16x16x32_bf16(af[m], bf[n], acc[m][n], 0, 0, 0);
    __syncthreads();
  }

  if (EPI == 2) {                    // fused bias + GEGLU (permuted cols)
    const int Nh = N >> 1;
#pragma unroll
    for (int np = 0; np < 2; ++np) {
      const int ca = bn + wc * 64 + np * 32 + lr;
      const float ba = bias[ca], bg = bias[ca + 16];
      const int uc = (bn >> 1) + wc * 32 + np * 16 + lr;
#pragma unroll
      for (int m = 0; m < 4; ++m) {
#pragma unroll
        for (int i = 0; i < 4; ++i) {
          const int row = bm + wr * 64 + m * 16 + lq * 4 + i;
          const float a = acc[m][2 * np][i] + ba;
          const float g = acc[m][2 * np + 1][i] + bg;
          ((u16t*)C)[(size_t)row * Nh + uc] = f2b(a * gelu_f(g));
        }
      }
    }
  } else {
#pragma unroll
    for (int n = 0; n < 4; ++n) {
      const int col = bn + wc * 64 + n * 16 + lr;
      const float bv = bias ? bias[col] : 0.f;
#pragma unroll
      for (int m = 0; m < 4; ++m) {
#pragma unroll
        for (int i = 0; i < 4; ++i) {
          const int row = bm + wr * 64 + m * 16 + lq * 4 + i;
          float v = acc[m][n][i] + bv;
          if (EPI == 1) {
            v += res[(size_t)row * N + col];
            ((float*)C)[(size_t)row * N + col] = v;
          } else {
            ((u16t*)C)[(size_t)row * N + col] = f2b(v);
          }
        }
      }
    }
  }
}

// ---------------- 64x64 MFMA GEMM for thin shapes (occupancy) --------------
template<int EPI>
__global__ __launch_bounds__(256) void mgemm64(
    const u16t* __restrict__ A, const u16t* __restrict__ BT,
    const float* __restrict__ bias, const float* __restrict__ res,
    void* __restrict__ C, int M, int N, int K) {
  __shared__ u16t Al[64 * 32];       // 4 KB
  __shared__ u16t Bl[64 * 32];
  const int t = threadIdx.x, lane = t & 63, wid = t >> 6;
  const int wr = wid >> 1, wc = wid & 1;
  const int lr = lane & 15, lq = lane >> 4;
  const int bm = blockIdx.y << 6, bn = blockIdx.x << 6;
  const int ch = wid * 64 + lane;
  const int crow = ch >> 2, ccol = (ch & 3) << 3;

  const u16t* Ab = A + (size_t)bm * K;
  const u16t* Bb = BT + (size_t)bn * K;

  f32x4 acc[2][2];
#pragma unroll
  for (int m = 0; m < 2; ++m)
#pragma unroll
    for (int n = 0; n < 2; ++n) acc[m][n] = (f32x4){0.f, 0.f, 0.f, 0.f};

  for (int k0 = 0; k0 < K; k0 += 32) {
    gload16(Ab + (size_t)crow * K + k0 + ccol, (char*)Al + wid * 1024);
    gload16(Bb + (size_t)crow * K + k0 + ccol, (char*)Bl + wid * 1024);
    __syncthreads();
    short8 af[2], bf[2];
#pragma unroll
    for (int m = 0; m < 2; ++m)
      af[m] = *(const short8*)&Al[(wr * 32 + m * 16 + lr) * 32 + lq * 8];
#pragma unroll
    for (int n = 0; n < 2; ++n)
      bf[n] = *(const short8*)&Bl[(wc * 32 + n * 16 + lr) * 32 + lq * 8];
#pragma unroll
    for (int m = 0; m < 2; ++m)
#pragma unroll
      for (int n = 0; n < 2; ++n)
        acc[m][n] = __builtin_amdgcn_mfma_f32_16x16x32_bf16(af[m], bf[n], acc[m][n], 0, 0, 0);
    __syncthreads();
  }

#pragma unroll
  for (int n = 0; n < 2; ++n) {
    const int col = bn + wc * 32 + n * 16 + lr;
    const float bv = bias ? bias[col] : 0.f;
#pragma unroll
    for (int m = 0; m < 2; ++m) {
#pragma unroll
      for (int i = 0; i < 4; ++i) {
        const int row = bm + wr * 32 + m * 16 + lq * 4 + i;
        float v = acc[m][n][i] + bv;
        if (EPI == 1) {
          v += res[(size_t)row * N + col];
          ((float*)C)[(size_t)row * N + col] = v;
        } else {
          ((u16t*)C)[(size_t)row * N + col] = f2b(v);
        }
      }
    }
  }
}

// ---------------- wo-projection + bias + residual + LayerNorm, fused -------
// C = LN(A[M,128] @ BT[NW,128]^T + bias + res). Whole B staged in LDS ONCE
// (K=128 fits), then 4 register K-steps of MFMA — no K-loop, no restaging.
// Block: 256 thr = 4 waves, BM=32 rows, each wave NW/4 cols.
template<int NW>
__global__ __launch_bounds__(256) void gemmlnF(
    const u16t* __restrict__ A, const u16t* __restrict__ BT,
    const float* __restrict__ bias, const float* __restrict__ res,
    const float* __restrict__ g, const float* __restrict__ be,
    float* __restrict__ y32, u16t* __restrict__ y16) {
  constexpr int NR = NW / 64;        // col frags per wave
  extern __shared__ u16t lds[];
  u16t* Al = lds;                    // [32][128] row-major
  u16t* Bl = lds + 32 * 128;         // [NW][128] row-major
  __shared__ float psum[4][32], psq[4][32];
  const int t = threadIdx.x, lane = t & 63, wid = t >> 6;
  const int lr = lane & 15, lq = lane >> 4;
  const int bm = blockIdx.x << 5;
  const int wofs = wid * (NW / 4);

  // stage A (512 16B-chunks) + full B (NW*16 chunks); chunk c -> row c>>4,
  // 8-elem col (c&15). LDS linear == global row-major.
  const int c0 = wid * 64 + lane;
#pragma unroll
  for (int j = 0; j < 2; ++j) {
    const int c = j * 256 + c0;
    gload16(A + (size_t)(bm + (c >> 4)) * 128 + ((c & 15) << 3),
            (char*)Al + (size_t)(j * 256 + wid * 64) * 16);
  }
#pragma unroll
  for (int j = 0; j < NW / 16; ++j) {
    const int c = j * 256 + c0;
    gload16(BT + (size_t)(c >> 4) * 128 + ((c & 15) << 3),
            (char*)Bl + (size_t)(j * 256 + wid * 64) * 16);
  }
  __syncthreads();

  f32x4 acc[2][NR];
#pragma unroll
  for (int m = 0; m < 2; ++m)
#pragma unroll
    for (int n = 0; n < NR; ++n) acc[m][n] = (f32x4){0.f, 0.f, 0.f, 0.f};

#pragma unroll
  for (int kk = 0; kk < 4; ++kk) {
    short8 af[2], bf[NR];
#pragma unroll
    for (int m = 0; m < 2; ++m)
      af[m] = *(const short8*)&Al[(m * 16 + lr) * 128 + kk * 32 + lq * 8];
#pragma unroll
    for (int n = 0; n < NR; ++n)
      bf[n] = *(const short8*)&Bl[(wofs + n * 16 + lr) * 128 + kk * 32 + lq * 8];
#pragma unroll
    for (int m = 0; m < 2; ++m)
#pragma unroll
      for (int n = 0; n < NR; ++n)
        acc[m][n] = __builtin_amdgcn_mfma_f32_16x16x32_bf16(af[m], bf[n], acc[m][n], 0, 0, 0);
  }

  // fold bias + residual; per-row partial stats (epilogue verified in R4)
  float ps[2][4], ps2[2][4];
#pragma unroll
  for (int m = 0; m < 2; ++m)
#pragma unroll
    for (int i = 0; i < 4; ++i) { ps[m][i] = 0.f; ps2[m][i] = 0.f; }
#pragma unroll
  for (int m = 0; m < 2; ++m)
#pragma unroll
    for (int n = 0; n < NR; ++n) {
      const int col = wofs + n * 16 + lr;
      const float bv = bias[col];
#pragma unroll
      for (int i = 0; i < 4; ++i) {
        const int row = bm + m * 16 + lq * 4 + i;
        const float v = acc[m][n][i] + bv + res[(size_t)row * NW + col];
        acc[m][n][i] = v;
        ps[m][i] += v; ps2[m][i] += v * v;
      }
    }
#pragma unroll
  for (int m = 0; m < 2; ++m)
#pragma unroll
    for (int i = 0; i < 4; ++i) {
      float s = ps[m][i], s2 = ps2[m][i];
      s  += __shfl_xor(s, 1);  s  += __shfl_xor(s, 2);
      s  += __shfl_xor(s, 4);  s  += __shfl_xor(s, 8);
      s2 += __shfl_xor(s2, 1); s2 += __shfl_xor(s2, 2);
      s2 += __shfl_xor(s2, 4); s2 += __shfl_xor(s2, 8);
      if (lr == 0) {
        psum[wid][m * 16 + lq * 4 + i] = s;
        psq[wid][m * 16 + lq * 4 + i]  = s2;
      }
    }
  __syncthreads();
#pragma unroll
  for (int m = 0; m < 2; ++m)
#pragma unroll
    for (int i = 0; i < 4; ++i) {
      const int r = m * 16 + lq * 4 + i;
      const float tot = psum[0][r] + psum[1][r] + psum[2][r] + psum[3][r];
      const float tq  = psq[0][r]  + psq[1][r]  + psq[2][r]  + psq[3][r];
      const float mean = tot / NW;
      const float rstd = rsqrtf(tq / NW - mean * mean + 1e-5f);
      const int row = bm + r;
#pragma unroll
      for (int n = 0; n < NR; ++n) {
        const int col = wofs + n * 16 + lr;
        const float y = (acc[m][n][i] - mean) * rstd * g[col] + be[col];
        y32[(size_t)row * NW + col] = y;
        y16[(size_t)row * NW + col] = f2b(y);
      }
    }
}

// ---------------- MFMA attention ------------------------------------------
template<int NTOK>
__global__ __launch_bounds__(256) void attn_mfma(
    const u16t* __restrict__ qkv, float* __restrict__ share,
    u16t* __restrict__ outb) {
  __shared__ u16t VT[16][NTOK + 40];
  __shared__ u16t PB[4][16][40];
  const int t = threadIdx.x, lane = t & 63, wv = t >> 6;
  const int lr = lane & 15, lq = lane >> 4;
  const int bpb = NTOK / 64;
  const int bh = blockIdx.x / bpb, rg = blockIdx.x % bpb;
  const int b = bh >> 3, h = bh & 7;
  const u16t* qkvb = qkv + (size_t)b * NTOK * 384;

  for (int tok = t; tok < NTOK; tok += 256) {
    const u16t* vp = qkvb + (size_t)tok * 384 + 256 + h * 16;
    short8 v0 = *(const short8*)vp;
    short8 v1 = *(const short8*)(vp + 8);
#pragma unroll
    for (int d = 0; d < 8; ++d) {
      VT[d][tok]     = (u16t)v0[d];
      VT[d + 8][tok] = (u16t)v1[d];
    }
  }
  __syncthreads();

  const int i0 = rg * 64 + wv * 16;
  short8 qf = {0, 0, 0, 0, 0, 0, 0, 0};
  if (lq < 2)
    qf = *(const short8*)(qkvb + (size_t)(i0 + lr) * 384 + h * 16 + lq * 8);

  f32x4 oacc = {0.f, 0.f, 0.f, 0.f};
  f32x4 sacc = {0.f, 0.f, 0.f, 0.f};
  const f32x4 zero = {0.f, 0.f, 0.f, 0.f};
  float* shb = share + (size_t)bh * NTOK * NTOK;

  for (int t0 = 0; t0 < NTOK; t0 += 32) {
#pragma unroll
    for (int s2 = 0; s2 < 2; ++s2) {
      short8 kf = {0, 0, 0, 0, 0, 0, 0, 0};
      if (lq < 2)
        kf = *(const short8*)(qkvb + (size_t)(t0 + s2 * 16 + lr) * 384 + 128 + h * 16 + lq * 8);
      f32x4 e = __builtin_amdgcn_mfma_f32_16x16x32_bf16(qf, kf, zero, 0, 0, 0);
#pragma unroll
      for (int i = 0; i < 4; ++i) {
        const float ev = e[i] * 0.25f;
        shb[(size_t)(i0 + lq * 4 + i) * NTOK + t0 + s2 * 16 + lr] = ev;
        const float p = __expf(ev);
        sacc[i] += p;
        PB[wv][lq * 4 + i][s2 * 16 + lr] = f2b(p);
      }
    }
    asm volatile("s_waitcnt lgkmcnt(0)" ::: "memory");
    __builtin_amdgcn_sched_barrier(0);
    short8 pa = *(const short8*)&PB[wv][lr][lq * 8];
    short8 vf = *(const short8*)&VT[lr][t0 + lq * 8];
    oacc = __builtin_amdgcn_mfma_f32_16x16x32_bf16(pa, vf, oacc, 0, 0, 0);
    __builtin_amdgcn_sched_barrier(0);
  }
#pragma unroll
  for (int i = 0; i < 4; ++i) {
    float s = sacc[i];
    s += __shfl_xor(s, 1); s += __shfl_xor(s, 2);
    s += __shfl_xor(s, 4); s += __shfl_xor(s, 8);
    sacc[i] = s;
  }
#pragma unroll
  for (int i = 0; i < 4; ++i) {
    const float o = oacc[i] / sacc[i];
    outb[((size_t)(b * NTOK) + i0 + lq * 4 + i) * 128 + h * 16 + lr] = f2b(o);
  }
}

// ---------------- LayerNorm (input pre-summed), float4 vectorized ----------
template<int NT, bool B16>
__global__ __launch_bounds__(NT) void ln_vec(
    const float* __restrict__ xin, const float* __restrict__ g,
    const float* __restrict__ be, float* __restrict__ y32,
    u16t* __restrict__ y16, int D) {
  const int row = blockIdx.x, t = threadIdx.x;
  const int lane = t & 63;
  const float4 x = ((const float4*)xin)[(size_t)row * (D >> 2) + t];
  float s = x.x + x.y + x.z + x.w;
  float s2 = x.x * x.x + x.y * x.y + x.z * x.z + x.w * x.w;
#pragma unroll
  for (int off = 32; off; off >>= 1) {
    s  += __shfl_xor(s, off);
    s2 += __shfl_xor(s2, off);
  }
  if (NT == 128) {
    __shared__ float a1[2], a2[2];
    const int wv = t >> 6;
    if (lane == 0) { a1[wv] = s; a2[wv] = s2; }
    __syncthreads();
    s = a1[0] + a1[1]; s2 = a2[0] + a2[1];
  }
  const float mean = s / D;
  const float var  = s2 / D - mean * mean;
  const float rstd = rsqrtf(var + 1e-5f);
  const float4 gv = ((const float4*)g)[t];
  const float4 bv = ((const float4*)be)[t];
  float4 y;
  y.x = (x.x - mean) * rstd * gv.x + bv.x;
  y.y = (x.y - mean) * rstd * gv.y + bv.y;
  y.z = (x.z - mean) * rstd * gv.z + bv.z;
  y.w = (x.w - mean) * rstd * gv.w + bv.w;
  ((float4*)y32)[(size_t)row * (D >> 2) + t] = y;
  if (B16) {
    bf16x4 p;
    p[0] = (short)f2b(y.x); p[1] = (short)f2b(y.y);
    p[2] = (short)f2b(y.z); p[3] = (short)f2b(y.w);
    *(bf16x4*)&y16[(size_t)row * D + t * 4] = p;
  }
}

// ---------------- batched transpose [B][R][C]->[B][C][R], opt bf16 twin ----
template<bool BF16OUT>
__global__ void transp(const float* __restrict__ in, float* __restrict__ out32,
                       u16t* __restrict__ out16, int R, int C) {
  __shared__ float tile[32][33];
  const int b = blockIdx.z;
  const int r0 = blockIdx.y << 5, c0 = blockIdx.x << 5;
  const float* inb = in + (size_t)b * R * C;
  const int tx = threadIdx.x, ty = threadIdx.y;
#pragma unroll
  for (int dy = 0; dy < 32; dy += 8)
    tile[ty + dy][tx] = inb[(size_t)(r0 + ty + dy) * C + c0 + tx];
  __syncthreads();
#pragma unroll
  for (int dy = 0; dy < 32; dy += 8) {
    const float v = tile[tx][ty + dy];
    const size_t idx = (size_t)b * R * C + (size_t)(c0 + ty + dy) * R + r0 + tx;
    out32[idx] = v;
    if (BF16OUT) out16[idx] = f2b(v);
  }
}

// ---------------- one-shot prep -------------------------------------------
__global__ __launch_bounds__(256) void prep_all(
    const float* __restrict__ x0, u16t* __restrict__ x16,
    const float* __restrict__ wqkv1, u16t* __restrict__ tqkv1,
    const float* __restrict__ wo1,   u16t* __restrict__ two1,
    const float* __restrict__ ff1w1, u16t* __restrict__ tff1a,
    const float* __restrict__ ff1w2, u16t* __restrict__ tff1b,
    const float* __restrict__ wqkv2, u16t* __restrict__ tqkv2,
    const float* __restrict__ wo2,   u16t* __restrict__ two2,
    const float* __restrict__ ff2w1, u16t* __restrict__ tff2a,
    const float* __restrict__ ff2w2, u16t* __restrict__ tff2b,
    const float* __restrict__ ff1b1, float* __restrict__ bp1,
    const float* __restrict__ ff2b1, float* __restrict__ bp2) {
  __shared__ float tile[32][33];
  const int b = blockIdx.x, t = threadIdx.x;
  const int tx = t & 31, ty = t >> 5;
  const float* src; u16t* dst;
  int K, N, bxd, blk, halfN = 0; bool perm = false;
  if (b < 1024) {
    const float* p = x0 + (size_t)(b * 256 + t) * 8;
    short8 v;
#pragma unroll
    for (int j = 0; j < 8; ++j) v[j] = (short)f2b(p[j]);
    *(short8*)(x16 + (size_t)(b * 256 + t) * 8) = v;
    return;
  } else if (b < 1120) { src = wqkv1; dst = tqkv1; K = 256;  N = 384;  bxd = 12;  blk = b - 1024; }
  else if (b < 1152)   { src = wo1;   dst = two1;  K = 128;  N = 256;  bxd = 8;   blk = b - 1120; }
  else if (b < 1664)   { src = ff1w1; dst = tff1a; K = 256;  N = 2048; bxd = 64;  blk = b - 1152; perm = true; halfN = 1024; }
  else if (b < 1920)   { src = ff1w2; dst = tff1b; K = 1024; N = 256;  bxd = 8;   blk = b - 1664; }
  else if (b < 2112)   { src = wqkv2; dst = tqkv2; K = 512;  N = 384;  bxd = 12;  blk = b - 1920; }
  else if (b < 2176)   { src = wo2;   dst = two2;  K = 128;  N = 512;  bxd = 16;  blk = b - 2112; }
  else if (b < 4224)   { src = ff2w1; dst = tff2a; K = 512;  N = 4096; bxd = 128; blk = b - 2176; perm = true; halfN = 2048; }
  else if (b < 5248)   { src = ff2w2; dst = tff2b; K = 2048; N = 512;  bxd = 16;  blk = b - 4224; }
  else if (b < 5256) { const int n = (b - 5248) * 256 + t; bp1[n] = ff1b1[origcol(n, 1024)]; return; }
  else               { const int n = (b - 5256) * 256 + t; bp2[n] = ff2b1[origcol(n, 2048)]; return; }

  const int bx = blk % bxd, by = blk / bxd;
  const int n0 = bx * 32, k0 = by * 32;
  const int nn = n0 + tx;
  const int no = perm ? origcol(nn, halfN) : nn;
#pragma unroll
  for (int dy = 0; dy < 32; dy += 8)
    tile[ty + dy][tx] = src[(size_t)(k0 + ty + dy) * N + no];
  __syncthreads();
#pragma unroll
  for (int dy = 0; dy < 32; dy += 8)
    dst[(size_t)(n0 + ty + dy) * K + k0 + tx] = f2b(tile[tx][ty + dy]);
}

// ---------------------------------------------------------------------------
extern "C" void kernel_launch(void* const* d_in, const int* in_sizes, int n_in,
                              void* d_out, int out_size, void* d_ws, size_t ws_size,
                              hipStream_t stream) {
  (void)in_sizes; (void)n_in; (void)out_size; (void)ws_size;
  const float* x0    = (const float*)d_in[0];
  const float* wqkv1 = (const float*)d_in[1];
  const float* wo1   = (const float*)d_in[2];
  const float* bo1   = (const float*)d_in[3];
  const float* ff1w1 = (const float*)d_in[4];
  const float* ff1b1 = (const float*)d_in[5];
  const float* ff1w2 = (const float*)d_in[6];
  const float* ff1b2 = (const float*)d_in[7];
  const float* wqkv2 = (const float*)d_in[8];
  const float* wo2   = (const float*)d_in[9];
  const float* bo2   = (const float*)d_in[10];
  const float* ff2w1 = (const float*)d_in[11];
  const float* ff2b1 = (const float*)d_in[12];
  const float* ff2w2 = (const float*)d_in[13];
  const float* ff2b2 = (const float*)d_in[14];
  const float* ln1g  = (const float*)d_in[15];
  const float* ln1b  = (const float*)d_in[16];
  const float* ln2g  = (const float*)d_in[17];
  const float* ln2b  = (const float*)d_in[18];
  const float* ln3g  = (const float*)d_in[19];
  const float* ln3b  = (const float*)d_in[20];
  const float* ln4g  = (const float*)d_in[21];
  const float* ln4b  = (const float*)d_in[22];

  float* out_x  = (float*)d_out;
  float* share1 = out_x + (size_t)2097152;
  float* share2 = share1 + (size_t)33554432;

  size_t off = 0;
  auto carve = [&](size_t bytes) -> void* {
    void* p = (char*)d_ws + off;
    off += (bytes + 255) & ~(size_t)255;
    return p;
  };
  u16t*  x16    = (u16t*)carve((size_t)8192 * 256 * 2);
  u16t*  qkv16  = (u16t*)carve((size_t)8192 * 384 * 2);
  u16t*  attn16 = (u16t*)carve((size_t)8192 * 128 * 2);
  float* sumb   = (float*)carve((size_t)8192 * 256 * 4);
  float* xa32   = (float*)carve((size_t)8192 * 256 * 4);
  u16t*  xa16   = (u16t*)carve((size_t)8192 * 256 * 2);
  float* xb32   = (float*)carve((size_t)8192 * 256 * 4);
  float* xt32   = (float*)carve((size_t)8192 * 256 * 4);
  u16t*  xt16   = (u16t*)carve((size_t)8192 * 256 * 2);
  float* xc32   = (float*)carve((size_t)8192 * 256 * 4);
  u16t*  xc16   = (u16t*)carve((size_t)8192 * 256 * 2);
  float* xd32   = (float*)carve((size_t)8192 * 256 * 4);
  u16t*  ubuf   = (u16t*)carve((size_t)8192 * 1024 * 2);
  u16t*  tqkv1  = (u16t*)carve((size_t)384 * 256 * 2);
  u16t*  two1   = (u16t*)carve((size_t)256 * 128 * 2);
  u16t*  tff1a  = (u16t*)carve((size_t)2048 * 256 * 2);
  u16t*  tff1b  = (u16t*)carve((size_t)256 * 1024 * 2);
  u16t*  tqkv2  = (u16t*)carve((size_t)384 * 512 * 2);
  u16t*  two2   = (u16t*)carve((size_t)512 * 128 * 2);
  u16t*  tff2a  = (u16t*)carve((size_t)4096 * 512 * 2);
  u16t*  tff2b  = (u16t*)carve((size_t)512 * 2048 * 2);
  float* bp1    = (float*)carve((size_t)2048 * 4);
  float* bp2    = (float*)carve((size_t)4096 * 4);

  // dynamic-LDS opt-in for the fused wo+LN kernels (72 KB / 136 KB)
  (void)hipFuncSetAttribute(reinterpret_cast<const void*>(&gemmlnF<256>),
                            hipFuncAttributeMaxDynamicSharedMemorySize, 73728);
  (void)hipFuncSetAttribute(reinterpret_cast<const void*>(&gemmlnF<512>),
                            hipFuncAttributeMaxDynamicSharedMemorySize, 139264);

  prep_all<<<5272, 256, 0, stream>>>(x0, x16, wqkv1, tqkv1, wo1, two1,
      ff1w1, tff1a, ff1w2, tff1b, wqkv2, tqkv2, wo2, two2,
      ff2w1, tff2a, ff2w2, tff2b, ff1b1, bp1, ff2b1, bp2);

  // ---- stage 1 (tokens=512, feat=256) ----
  mgemm64<0><<<dim3(6, 128), 256, 0, stream>>>(x16, tqkv1, nullptr, nullptr, qkv16, 8192, 384, 256);
  attn_mfma<512><<<1024, 256, 0, stream>>>(qkv16, share1, attn16);
  // fused wo1 + bias + residual(x0) + LN1 -> xa32, xa16
  gemmlnF<256><<<256, 256, 73728, stream>>>(attn16, two1, bo1, x0, ln1g, ln1b, xa32, xa16);
  mgemm<2><<<dim3(16, 64), 256, 0, stream>>>(xa16, tff1a, bp1, nullptr, ubuf, 8192, 2048, 256);
  mgemm64<1><<<dim3(4, 128), 256, 0, stream>>>(ubuf, tff1b, ff1b2, xa32, sumb, 8192, 256, 1024);
  ln_vec<64, false><<<8192, 64, 0, stream>>>(sumb, ln2g, ln2b, xb32, nullptr, 256);

  // ---- transpose to [B,256,512] ----
  transp<true><<<dim3(8, 16, 16), dim3(32, 8), 0, stream>>>(xb32, xt32, xt16, 512, 256);

  // ---- stage 2 (tokens=256, feat=512) ----
  mgemm64<0><<<dim3(6, 64), 256, 0, stream>>>(xt16, tqkv2, nullptr, nullptr, qkv16, 4096, 384, 512);
  attn_mfma<256><<<512, 256, 0, stream>>>(qkv16, share2, attn16);
  // fused wo2 + bias + residual(xt32) + LN3 -> xc32, xc16
  gemmlnF<512><<<128, 256, 139264, stream>>>(attn16, two2, bo2, xt32, ln3g, ln3b, xc32, xc16);
  mgemm<2><<<dim3(32, 32), 256, 0, stream>>>(xc16, tff2a, bp2, nullptr, ubuf, 4096, 4096, 512);
  mgemm64<1><<<dim3(8, 64), 256, 0, stream>>>(ubuf, tff2b, ff2b2, xc32, sumb, 4096, 512, 2048);
  ln_vec<128, false><<<4096, 128, 0, stream>>>(sumb, ln4g, ln4b, xd32, nullptr, 512);

  // ---- transpose back -> out ----
  transp<false><<<dim3(16, 8, 16), dim3(32, 8), 0, stream>>>(xd32, out_x, nullptr, 256, 512);
}

// Round 10
// 206.802 us; speedup vs baseline: 1.1560x; 1.0429x over previous
//
#include <hip/hip_runtime.h>
#include <cstddef>

// ---------------------------------------------------------------------------
// B=16, N=512, D=256, H=8, DH=16, INNER=128, SCALE=0.25
// R9 base + BK=64 (two 32-col LDS sub-tiles per operand) in both GEMM
// kernels: same staged bytes / MFMA count, HALF the barrier drains.
// 16 launches.
// ---------------------------------------------------------------------------

typedef __attribute__((ext_vector_type(8))) short short8;
typedef __attribute__((ext_vector_type(4))) short bf16x4;
typedef __attribute__((ext_vector_type(4))) float f32x4;
typedef unsigned short u16t;

__device__ __forceinline__ u16t f2b(float f) {           // fp32 -> bf16 (RNE)
  union { float f; unsigned u; } x; x.f = f;
  unsigned r = (x.u + 0x7fffu + ((x.u >> 16) & 1u)) >> 16;
  return (u16t)r;
}

__device__ __forceinline__ void gload16(const void* g, void* l) {
  __builtin_amdgcn_global_load_lds(
      (const __attribute__((address_space(1))) void*)g,
      (__attribute__((address_space(3))) void*)l, 16, 0, 0);
}

// exact-GELU via Abramowitz-Stegun 7.1.26 erf (max abs err 1.5e-7)
__device__ __forceinline__ float gelu_f(float g) {
  const float x = g * 0.70710678118654752f;
  const float ax = fabsf(x);
  const float t = 1.f / (1.f + 0.3275911f * ax);
  const float p = t * (0.254829592f + t * (-0.284496736f +
                  t * (1.421413741f + t * (-1.453152027f + t * 1.061405429f))));
  const float er = 1.f - p * __expf(-x * x);
  return 0.5f * g * (1.f + copysignf(er, x));
}

// GEGLU weight-column permutation: n_new -> n_orig.
__device__ __forceinline__ int origcol(int n, int halfN) {
  const int nb = n >> 7, s = (n >> 4) & 7, r = n & 15;
  return ((s & 1) ? halfN : 0) + (nb << 6) + ((s >> 1) << 4) + r;
}

// ---------------- 128x128 MFMA GEMM, BK=64 (EPI 2 = fused GEGLU) -----------
template<int EPI>
__global__ __launch_bounds__(256) void mgemm(
    const u16t* __restrict__ A, const u16t* __restrict__ BT,
    const float* __restrict__ bias, const float* __restrict__ res,
    void* __restrict__ C, int M, int N, int K) {
  __shared__ u16t Al[2][128 * 32];   // two 32-col halves, 8 KB each
  __shared__ u16t Bl[2][128 * 32];
  const int t = threadIdx.x, lane = t & 63, wid = t >> 6;
  const int wr = wid >> 1, wc = wid & 1;
  const int lr = lane & 15, lq = lane >> 4;
  const int bm = blockIdx.y << 7, bn = blockIdx.x << 7;

  const int ao0 = wid * 2048 + lane * 16;
  const int ar0 = ao0 >> 6,          ac0 = (ao0 & 63) >> 1;
  const int ar1 = (ao0 + 1024) >> 6, ac1 = ((ao0 + 1024) & 63) >> 1;

  const u16t* Ab = A + (size_t)bm * K;
  const u16t* Bb = BT + (size_t)bn * K;

  f32x4 acc[4][4];
#pragma unroll
  for (int m = 0; m < 4; ++m)
#pragma unroll
    for (int n = 0; n < 4; ++n) acc[m][n] = (f32x4){0.f, 0.f, 0.f, 0.f};

  for (int k0 = 0; k0 < K; k0 += 64) {
#pragma unroll
    for (int h = 0; h < 2; ++h) {
      const int kh = k0 + h * 32;
      gload16(Ab + (size_t)ar0 * K + kh + ac0, (char*)Al[h] + wid * 2048);
      gload16(Ab + (size_t)ar1 * K + kh + ac1, (char*)Al[h] + wid * 2048 + 1024);
      gload16(Bb + (size_t)ar0 * K + kh + ac0, (char*)Bl[h] + wid * 2048);
      gload16(Bb + (size_t)ar1 * K + kh + ac1, (char*)Bl[h] + wid * 2048 + 1024);
    }
    __syncthreads();
#pragma unroll
    for (int h = 0; h < 2; ++h) {
      short8 af[4], bf[4];
#pragma unroll
      for (int m = 0; m < 4; ++m)
        af[m] = *(const short8*)&Al[h][(wr * 64 + m * 16 + lr) * 32 + lq * 8];
#pragma unroll
      for (int n = 0; n < 4; ++n)
        bf[n] = *(const short8*)&Bl[h][(wc * 64 + n * 16 + lr) * 32 + lq * 8];
#pragma unroll
      for (int m = 0; m < 4; ++m)
#pragma unroll
        for (int n = 0; n < 4; ++n)
          acc[m][n] = __builtin_amdgcn_mfma_f32_16x16x32_bf16(af[m], bf[n], acc[m][n], 0, 0, 0);
    }
    __syncthreads();
  }

  if (EPI == 2) {                    // fused bias + GEGLU (permuted cols)
    const int Nh = N >> 1;
#pragma unroll
    for (int np = 0; np < 2; ++np) {
      const int ca = bn + wc * 64 + np * 32 + lr;
      const float ba = bias[ca], bg = bias[ca + 16];
      const int uc = (bn >> 1) + wc * 32 + np * 16 + lr;
#pragma unroll
      for (int m = 0; m < 4; ++m) {
#pragma unroll
        for (int i = 0; i < 4; ++i) {
          const int row = bm + wr * 64 + m * 16 + lq * 4 + i;
          const float a = acc[m][2 * np][i] + ba;
          const float g = acc[m][2 * np + 1][i] + bg;
          ((u16t*)C)[(size_t)row * Nh + uc] = f2b(a * gelu_f(g));
        }
      }
    }
  } else {
#pragma unroll
    for (int n = 0; n < 4; ++n) {
      const int col = bn + wc * 64 + n * 16 + lr;
      const float bv = bias ? bias[col] : 0.f;
#pragma unroll
      for (int m = 0; m < 4; ++m) {
#pragma unroll
        for (int i = 0; i < 4; ++i) {
          const int row = bm + wr * 64 + m * 16 + lq * 4 + i;
          float v = acc[m][n][i] + bv;
          if (EPI == 1) {
            v += res[(size_t)row * N + col];
            ((float*)C)[(size_t)row * N + col] = v;
          } else {
            ((u16t*)C)[(size_t)row * N + col] = f2b(v);
          }
        }
      }
    }
  }
}

// ---------------- 64x64 MFMA GEMM, BK=64, for thin shapes ------------------
template<int EPI>
__global__ __launch_bounds__(256) void mgemm64(
    const u16t* __restrict__ A, const u16t* __restrict__ BT,
    const float* __restrict__ bias, const float* __restrict__ res,
    void* __restrict__ C, int M, int N, int K) {
  __shared__ u16t Al[2][64 * 32];    // two 32-col halves, 4 KB each
  __shared__ u16t Bl[2][64 * 32];
  const int t = threadIdx.x, lane = t & 63, wid = t >> 6;
  const int wr = wid >> 1, wc = wid & 1;
  const int lr = lane & 15, lq = lane >> 4;
  const int bm = blockIdx.y << 6, bn = blockIdx.x << 6;
  const int ch = wid * 64 + lane;
  const int crow = ch >> 2, ccol = (ch & 3) << 3;

  const u16t* Ab = A + (size_t)bm * K;
  const u16t* Bb = BT + (size_t)bn * K;

  f32x4 acc[2][2];
#pragma unroll
  for (int m = 0; m < 2; ++m)
#pragma unroll
    for (int n = 0; n < 2; ++n) acc[m][n] = (f32x4){0.f, 0.f, 0.f, 0.f};

  for (int k0 = 0; k0 < K; k0 += 64) {
#pragma unroll
    for (int h = 0; h < 2; ++h) {
      const int kh = k0 + h * 32;
      gload16(Ab + (size_t)crow * K + kh + ccol, (char*)Al[h] + wid * 1024);
      gload16(Bb + (size_t)crow * K + kh + ccol, (char*)Bl[h] + wid * 1024);
    }
    __syncthreads();
#pragma unroll
    for (int h = 0; h < 2; ++h) {
      short8 af[2], bf[2];
#pragma unroll
      for (int m = 0; m < 2; ++m)
        af[m] = *(const short8*)&Al[h][(wr * 32 + m * 16 + lr) * 32 + lq * 8];
#pragma unroll
      for (int n = 0; n < 2; ++n)
        bf[n] = *(const short8*)&Bl[h][(wc * 32 + n * 16 + lr) * 32 + lq * 8];
#pragma unroll
      for (int m = 0; m < 2; ++m)
#pragma unroll
        for (int n = 0; n < 2; ++n)
          acc[m][n] = __builtin_amdgcn_mfma_f32_16x16x32_bf16(af[m], bf[n], acc[m][n], 0, 0, 0);
    }
    __syncthreads();
  }

#pragma unroll
  for (int n = 0; n < 2; ++n) {
    const int col = bn + wc * 32 + n * 16 + lr;
    const float bv = bias ? bias[col] : 0.f;
#pragma unroll
    for (int m = 0; m < 2; ++m) {
#pragma unroll
      for (int i = 0; i < 4; ++i) {
        const int row = bm + wr * 32 + m * 16 + lq * 4 + i;
        float v = acc[m][n][i] + bv;
        if (EPI == 1) {
          v += res[(size_t)row * N + col];
          ((float*)C)[(size_t)row * N + col] = v;
        } else {
          ((u16t*)C)[(size_t)row * N + col] = f2b(v);
        }
      }
    }
  }
}

// ---------------- wo-projection + bias + residual + LayerNorm, fused -------
template<int NW>
__global__ __launch_bounds__(256) void gemmlnF(
    const u16t* __restrict__ A, const u16t* __restrict__ BT,
    const float* __restrict__ bias, const float* __restrict__ res,
    const float* __restrict__ g, const float* __restrict__ be,
    float* __restrict__ y32, u16t* __restrict__ y16) {
  constexpr int NR = NW / 64;        // col frags per wave
  extern __shared__ u16t lds[];
  u16t* Al = lds;                    // [32][128] row-major
  u16t* Bl = lds + 32 * 128;         // [NW][128] row-major
  __shared__ float psum[4][32], psq[4][32];
  const int t = threadIdx.x, lane = t & 63, wid = t >> 6;
  const int lr = lane & 15, lq = lane >> 4;
  const int bm = blockIdx.x << 5;
  const int wofs = wid * (NW / 4);

  const int c0 = wid * 64 + lane;
#pragma unroll
  for (int j = 0; j < 2; ++j) {
    const int c = j * 256 + c0;
    gload16(A + (size_t)(bm + (c >> 4)) * 128 + ((c & 15) << 3),
            (char*)Al + (size_t)(j * 256 + wid * 64) * 16);
  }
#pragma unroll
  for (int j = 0; j < NW / 16; ++j) {
    const int c = j * 256 + c0;
    gload16(BT + (size_t)(c >> 4) * 128 + ((c & 15) << 3),
            (char*)Bl + (size_t)(j * 256 + wid * 64) * 16);
  }
  __syncthreads();

  f32x4 acc[2][NR];
#pragma unroll
  for (int m = 0; m < 2; ++m)
#pragma unroll
    for (int n = 0; n < NR; ++n) acc[m][n] = (f32x4){0.f, 0.f, 0.f, 0.f};

#pragma unroll
  for (int kk = 0; kk < 4; ++kk) {
    short8 af[2], bf[NR];
#pragma unroll
    for (int m = 0; m < 2; ++m)
      af[m] = *(const short8*)&Al[(m * 16 + lr) * 128 + kk * 32 + lq * 8];
#pragma unroll
    for (int n = 0; n < NR; ++n)
      bf[n] = *(const short8*)&Bl[(wofs + n * 16 + lr) * 128 + kk * 32 + lq * 8];
#pragma unroll
    for (int m = 0; m < 2; ++m)
#pragma unroll
      for (int n = 0; n < NR; ++n)
        acc[m][n] = __builtin_amdgcn_mfma_f32_16x16x32_bf16(af[m], bf[n], acc[m][n], 0, 0, 0);
  }

  float ps[2][4], ps2[2][4];
#pragma unroll
  for (int m = 0; m < 2; ++m)
#pragma unroll
    for (int i = 0; i < 4; ++i) { ps[m][i] = 0.f; ps2[m][i] = 0.f; }
#pragma unroll
  for (int m = 0; m < 2; ++m)
#pragma unroll
    for (int n = 0; n < NR; ++n) {
      const int col = wofs + n * 16 + lr;
      const float bv = bias[col];
#pragma unroll
      for (int i = 0; i < 4; ++i) {
        const int row = bm + m * 16 + lq * 4 + i;
        const float v = acc[m][n][i] + bv + res[(size_t)row * NW + col];
        acc[m][n][i] = v;
        ps[m][i] += v; ps2[m][i] += v * v;
      }
    }
#pragma unroll
  for (int m = 0; m < 2; ++m)
#pragma unroll
    for (int i = 0; i < 4; ++i) {
      float s = ps[m][i], s2 = ps2[m][i];
      s  += __shfl_xor(s, 1);  s  += __shfl_xor(s, 2);
      s  += __shfl_xor(s, 4);  s  += __shfl_xor(s, 8);
      s2 += __shfl_xor(s2, 1); s2 += __shfl_xor(s2, 2);
      s2 += __shfl_xor(s2, 4); s2 += __shfl_xor(s2, 8);
      if (lr == 0) {
        psum[wid][m * 16 + lq * 4 + i] = s;
        psq[wid][m * 16 + lq * 4 + i]  = s2;
      }
    }
  __syncthreads();
#pragma unroll
  for (int m = 0; m < 2; ++m)
#pragma unroll
    for (int i = 0; i < 4; ++i) {
      const int r = m * 16 + lq * 4 + i;
      const float tot = psum[0][r] + psum[1][r] + psum[2][r] + psum[3][r];
      const float tq  = psq[0][r]  + psq[1][r]  + psq[2][r]  + psq[3][r];
      const float mean = tot / NW;
      const float rstd = rsqrtf(tq / NW - mean * mean + 1e-5f);
      const int row = bm + r;
#pragma unroll
      for (int n = 0; n < NR; ++n) {
        const int col = wofs + n * 16 + lr;
        const float y = (acc[m][n][i] - mean) * rstd * g[col] + be[col];
        y32[(size_t)row * NW + col] = y;
        y16[(size_t)row * NW + col] = f2b(y);
      }
    }
}

// ---------------- MFMA attention ------------------------------------------
template<int NTOK>
__global__ __launch_bounds__(256) void attn_mfma(
    const u16t* __restrict__ qkv, float* __restrict__ share,
    u16t* __restrict__ outb) {
  __shared__ u16t VT[16][NTOK + 40];
  __shared__ u16t PB[4][16][40];
  const int t = threadIdx.x, lane = t & 63, wv = t >> 6;
  const int lr = lane & 15, lq = lane >> 4;
  const int bpb = NTOK / 64;
  const int bh = blockIdx.x / bpb, rg = blockIdx.x % bpb;
  const int b = bh >> 3, h = bh & 7;
  const u16t* qkvb = qkv + (size_t)b * NTOK * 384;

  for (int tok = t; tok < NTOK; tok += 256) {
    const u16t* vp = qkvb + (size_t)tok * 384 + 256 + h * 16;
    short8 v0 = *(const short8*)vp;
    short8 v1 = *(const short8*)(vp + 8);
#pragma unroll
    for (int d = 0; d < 8; ++d) {
      VT[d][tok]     = (u16t)v0[d];
      VT[d + 8][tok] = (u16t)v1[d];
    }
  }
  __syncthreads();

  const int i0 = rg * 64 + wv * 16;
  short8 qf = {0, 0, 0, 0, 0, 0, 0, 0};
  if (lq < 2)
    qf = *(const short8*)(qkvb + (size_t)(i0 + lr) * 384 + h * 16 + lq * 8);

  f32x4 oacc = {0.f, 0.f, 0.f, 0.f};
  f32x4 sacc = {0.f, 0.f, 0.f, 0.f};
  const f32x4 zero = {0.f, 0.f, 0.f, 0.f};
  float* shb = share + (size_t)bh * NTOK * NTOK;

  for (int t0 = 0; t0 < NTOK; t0 += 32) {
#pragma unroll
    for (int s2 = 0; s2 < 2; ++s2) {
      short8 kf = {0, 0, 0, 0, 0, 0, 0, 0};
      if (lq < 2)
        kf = *(const short8*)(qkvb + (size_t)(t0 + s2 * 16 + lr) * 384 + 128 + h * 16 + lq * 8);
      f32x4 e = __builtin_amdgcn_mfma_f32_16x16x32_bf16(qf, kf, zero, 0, 0, 0);
#pragma unroll
      for (int i = 0; i < 4; ++i) {
        const float ev = e[i] * 0.25f;
        shb[(size_t)(i0 + lq * 4 + i) * NTOK + t0 + s2 * 16 + lr] = ev;
        const float p = __expf(ev);
        sacc[i] += p;
        PB[wv][lq * 4 + i][s2 * 16 + lr] = f2b(p);
      }
    }
    asm volatile("s_waitcnt lgkmcnt(0)" ::: "memory");
    __builtin_amdgcn_sched_barrier(0);
    short8 pa = *(const short8*)&PB[wv][lr][lq * 8];
    short8 vf = *(const short8*)&VT[lr][t0 + lq * 8];
    oacc = __builtin_amdgcn_mfma_f32_16x16x32_bf16(pa, vf, oacc, 0, 0, 0);
    __builtin_amdgcn_sched_barrier(0);
  }
#pragma unroll
  for (int i = 0; i < 4; ++i) {
    float s = sacc[i];
    s += __shfl_xor(s, 1); s += __shfl_xor(s, 2);
    s += __shfl_xor(s, 4); s += __shfl_xor(s, 8);
    sacc[i] = s;
  }
#pragma unroll
  for (int i = 0; i < 4; ++i) {
    const float o = oacc[i] / sacc[i];
    outb[((size_t)(b * NTOK) + i0 + lq * 4 + i) * 128 + h * 16 + lr] = f2b(o);
  }
}

// ---------------- LayerNorm (input pre-summed), float4 vectorized ----------
template<int NT, bool B16>
__global__ __launch_bounds__(NT) void ln_vec(
    const float* __restrict__ xin, const float* __restrict__ g,
    const float* __restrict__ be, float* __restrict__ y32,
    u16t* __restrict__ y16, int D) {
  const int row = blockIdx.x, t = threadIdx.x;
  const int lane = t & 63;
  const float4 x = ((const float4*)xin)[(size_t)row * (D >> 2) + t];
  float s = x.x + x.y + x.z + x.w;
  float s2 = x.x * x.x + x.y * x.y + x.z * x.z + x.w * x.w;
#pragma unroll
  for (int off = 32; off; off >>= 1) {
    s  += __shfl_xor(s, off);
    s2 += __shfl_xor(s2, off);
  }
  if (NT == 128) {
    __shared__ float a1[2], a2[2];
    const int wv = t >> 6;
    if (lane == 0) { a1[wv] = s; a2[wv] = s2; }
    __syncthreads();
    s = a1[0] + a1[1]; s2 = a2[0] + a2[1];
  }
  const float mean = s / D;
  const float var  = s2 / D - mean * mean;
  const float rstd = rsqrtf(var + 1e-5f);
  const float4 gv = ((const float4*)g)[t];
  const float4 bv = ((const float4*)be)[t];
  float4 y;
  y.x = (x.x - mean) * rstd * gv.x + bv.x;
  y.y = (x.y - mean) * rstd * gv.y + bv.y;
  y.z = (x.z - mean) * rstd * gv.z + bv.z;
  y.w = (x.w - mean) * rstd * gv.w + bv.w;
  ((float4*)y32)[(size_t)row * (D >> 2) + t] = y;
  if (B16) {
    bf16x4 p;
    p[0] = (short)f2b(y.x); p[1] = (short)f2b(y.y);
    p[2] = (short)f2b(y.z); p[3] = (short)f2b(y.w);
    *(bf16x4*)&y16[(size_t)row * D + t * 4] = p;
  }
}

// ---------------- batched transpose [B][R][C]->[B][C][R], opt bf16 twin ----
template<bool BF16OUT>
__global__ void transp(const float* __restrict__ in, float* __restrict__ out32,
                       u16t* __restrict__ out16, int R, int C) {
  __shared__ float tile[32][33];
  const int b = blockIdx.z;
  const int r0 = blockIdx.y << 5, c0 = blockIdx.x << 5;
  const float* inb = in + (size_t)b * R * C;
  const int tx = threadIdx.x, ty = threadIdx.y;
#pragma unroll
  for (int dy = 0; dy < 32; dy += 8)
    tile[ty + dy][tx] = inb[(size_t)(r0 + ty + dy) * C + c0 + tx];
  __syncthreads();
#pragma unroll
  for (int dy = 0; dy < 32; dy += 8) {
    const float v = tile[tx][ty + dy];
    const size_t idx = (size_t)b * R * C + (size_t)(c0 + ty + dy) * R + r0 + tx;
    out32[idx] = v;
    if (BF16OUT) out16[idx] = f2b(v);
  }
}

// ---------------- one-shot prep -------------------------------------------
__global__ __launch_bounds__(256) void prep_all(
    const float* __restrict__ x0, u16t* __restrict__ x16,
    const float* __restrict__ wqkv1, u16t* __restrict__ tqkv1,
    const float* __restrict__ wo1,   u16t* __restrict__ two1,
    const float* __restrict__ ff1w1, u16t* __restrict__ tff1a,
    const float* __restrict__ ff1w2, u16t* __restrict__ tff1b,
    const float* __restrict__ wqkv2, u16t* __restrict__ tqkv2,
    const float* __restrict__ wo2,   u16t* __restrict__ two2,
    const float* __restrict__ ff2w1, u16t* __restrict__ tff2a,
    const float* __restrict__ ff2w2, u16t* __restrict__ tff2b,
    const float* __restrict__ ff1b1, float* __restrict__ bp1,
    const float* __restrict__ ff2b1, float* __restrict__ bp2) {
  __shared__ float tile[32][33];
  const int b = blockIdx.x, t = threadIdx.x;
  const int tx = t & 31, ty = t >> 5;
  const float* src; u16t* dst;
  int K, N, bxd, blk, halfN = 0; bool perm = false;
  if (b < 1024) {
    const float* p = x0 + (size_t)(b * 256 + t) * 8;
    short8 v;
#pragma unroll
    for (int j = 0; j < 8; ++j) v[j] = (short)f2b(p[j]);
    *(short8*)(x16 + (size_t)(b * 256 + t) * 8) = v;
    return;
  } else if (b < 1120) { src = wqkv1; dst = tqkv1; K = 256;  N = 384;  bxd = 12;  blk = b - 1024; }
  else if (b < 1152)   { src = wo1;   dst = two1;  K = 128;  N = 256;  bxd = 8;   blk = b - 1120; }
  else if (b < 1664)   { src = ff1w1; dst = tff1a; K = 256;  N = 2048; bxd = 64;  blk = b - 1152; perm = true; halfN = 1024; }
  else if (b < 1920)   { src = ff1w2; dst = tff1b; K = 1024; N = 256;  bxd = 8;   blk = b - 1664; }
  else if (b < 2112)   { src = wqkv2; dst = tqkv2; K = 512;  N = 384;  bxd = 12;  blk = b - 1920; }
  else if (b < 2176)   { src = wo2;   dst = two2;  K = 128;  N = 512;  bxd = 16;  blk = b - 2112; }
  else if (b < 4224)   { src = ff2w1; dst = tff2a; K = 512;  N = 4096; bxd = 128; blk = b - 2176; perm = true; halfN = 2048; }
  else if (b < 5248)   { src = ff2w2; dst = tff2b; K = 2048; N = 512;  bxd = 16;  blk = b - 4224; }
  else if (b < 5256) { const int n = (b - 5248) * 256 + t; bp1[n] = ff1b1[origcol(n, 1024)]; return; }
  else               { const int n = (b - 5256) * 256 + t; bp2[n] = ff2b1[origcol(n, 2048)]; return; }

  const int bx = blk % bxd, by = blk / bxd;
  const int n0 = bx * 32, k0 = by * 32;
  const int nn = n0 + tx;
  const int no = perm ? origcol(nn, halfN) : nn;
#pragma unroll
  for (int dy = 0; dy < 32; dy += 8)
    tile[ty + dy][tx] = src[(size_t)(k0 + ty + dy) * N + no];
  __syncthreads();
#pragma unroll
  for (int dy = 0; dy < 32; dy += 8)
    dst[(size_t)(n0 + ty + dy) * K + k0 + tx] = f2b(tile[tx][ty + dy]);
}

// ---------------------------------------------------------------------------
extern "C" void kernel_launch(void* const* d_in, const int* in_sizes, int n_in,
                              void* d_out, int out_size, void* d_ws, size_t ws_size,
                              hipStream_t stream) {
  (void)in_sizes; (void)n_in; (void)out_size; (void)ws_size;
  const float* x0    = (const float*)d_in[0];
  const float* wqkv1 = (const float*)d_in[1];
  const float* wo1   = (const float*)d_in[2];
  const float* bo1   = (const float*)d_in[3];
  const float* ff1w1 = (const float*)d_in[4];
  const float* ff1b1 = (const float*)d_in[5];
  const float* ff1w2 = (const float*)d_in[6];
  const float* ff1b2 = (const float*)d_in[7];
  const float* wqkv2 = (const float*)d_in[8];
  const float* wo2   = (const float*)d_in[9];
  const float* bo2   = (const float*)d_in[10];
  const float* ff2w1 = (const float*)d_in[11];
  const float* ff2b1 = (const float*)d_in[12];
  const float* ff2w2 = (const float*)d_in[13];
  const float* ff2b2 = (const float*)d_in[14];
  const float* ln1g  = (const float*)d_in[15];
  const float* ln1b  = (const float*)d_in[16];
  const float* ln2g  = (const float*)d_in[17];
  const float* ln2b  = (const float*)d_in[18];
  const float* ln3g  = (const float*)d_in[19];
  const float* ln3b  = (const float*)d_in[20];
  const float* ln4g  = (const float*)d_in[21];
  const float* ln4b  = (const float*)d_in[22];

  float* out_x  = (float*)d_out;
  float* share1 = out_x + (size_t)2097152;
  float* share2 = share1 + (size_t)33554432;

  size_t off = 0;
  auto carve = [&](size_t bytes) -> void* {
    void* p = (char*)d_ws + off;
    off += (bytes + 255) & ~(size_t)255;
    return p;
  };
  u16t*  x16    = (u16t*)carve((size_t)8192 * 256 * 2);
  u16t*  qkv16  = (u16t*)carve((size_t)8192 * 384 * 2);
  u16t*  attn16 = (u16t*)carve((size_t)8192 * 128 * 2);
  float* sumb   = (float*)carve((size_t)8192 * 256 * 4);
  float* xa32   = (float*)carve((size_t)8192 * 256 * 4);
  u16t*  xa16   = (u16t*)carve((size_t)8192 * 256 * 2);
  float* xb32   = (float*)carve((size_t)8192 * 256 * 4);
  float* xt32   = (float*)carve((size_t)8192 * 256 * 4);
  u16t*  xt16   = (u16t*)carve((size_t)8192 * 256 * 2);
  float* xc32   = (float*)carve((size_t)8192 * 256 * 4);
  u16t*  xc16   = (u16t*)carve((size_t)8192 * 256 * 2);
  float* xd32   = (float*)carve((size_t)8192 * 256 * 4);
  u16t*  ubuf   = (u16t*)carve((size_t)8192 * 1024 * 2);
  u16t*  tqkv1  = (u16t*)carve((size_t)384 * 256 * 2);
  u16t*  two1   = (u16t*)carve((size_t)256 * 128 * 2);
  u16t*  tff1a  = (u16t*)carve((size_t)2048 * 256 * 2);
  u16t*  tff1b  = (u16t*)carve((size_t)256 * 1024 * 2);
  u16t*  tqkv2  = (u16t*)carve((size_t)384 * 512 * 2);
  u16t*  two2   = (u16t*)carve((size_t)512 * 128 * 2);
  u16t*  tff2a  = (u16t*)carve((size_t)4096 * 512 * 2);
  u16t*  tff2b  = (u16t*)carve((size_t)512 * 2048 * 2);
  float* bp1    = (float*)carve((size_t)2048 * 4);
  float* bp2    = (float*)carve((size_t)4096 * 4);

  // dynamic-LDS opt-in for the fused wo+LN kernels (72 KB / 136 KB)
  (void)hipFuncSetAttribute(reinterpret_cast<const void*>(&gemmlnF<256>),
                            hipFuncAttributeMaxDynamicSharedMemorySize, 73728);
  (void)hipFuncSetAttribute(reinterpret_cast<const void*>(&gemmlnF<512>),
                            hipFuncAttributeMaxDynamicSharedMemorySize, 139264);

  prep_all<<<5272, 256, 0, stream>>>(x0, x16, wqkv1, tqkv1, wo1, two1,
      ff1w1, tff1a, ff1w2, tff1b, wqkv2, tqkv2, wo2, two2,
      ff2w1, tff2a, ff2w2, tff2b, ff1b1, bp1, ff2b1, bp2);

  // ---- stage 1 (tokens=512, feat=256) ----
  mgemm64<0><<<dim3(6, 128), 256, 0, stream>>>(x16, tqkv1, nullptr, nullptr, qkv16, 8192, 384, 256);
  attn_mfma<512><<<1024, 256, 0, stream>>>(qkv16, share1, attn16);
  gemmlnF<256><<<256, 256, 73728, stream>>>(attn16, two1, bo1, x0, ln1g, ln1b, xa32, xa16);
  mgemm<2><<<dim3(16, 64), 256, 0, stream>>>(xa16, tff1a, bp1, nullptr, ubuf, 8192, 2048, 256);
  mgemm64<1><<<dim3(4, 128), 256, 0, stream>>>(ubuf, tff1b, ff1b2, xa32, sumb, 8192, 256, 1024);
  ln_vec<64, false><<<8192, 64, 0, stream>>>(sumb, ln2g, ln2b, xb32, nullptr, 256);

  // ---- transpose to [B,256,512] ----
  transp<true><<<dim3(8, 16, 16), dim3(32, 8), 0, stream>>>(xb32, xt32, xt16, 512, 256);

  // ---- stage 2 (tokens=256, feat=512) ----
  mgemm64<0><<<dim3(6, 64), 256, 0, stream>>>(xt16, tqkv2, nullptr, nullptr, qkv16, 4096, 384, 512);
  attn_mfma<256><<<512, 256, 0, stream>>>(qkv16, share2, attn16);
  gemmlnF<512><<<128, 256, 139264, stream>>>(attn16, two2, bo2, xt32, ln3g, ln3b, xc32, xc16);
  mgemm<2><<<dim3(32, 32), 256, 0, stream>>>(xc16, tff2a, bp2, nullptr, ubuf, 4096, 4096, 512);
  mgemm64<1><<<dim3(8, 64), 256, 0, stream>>>(ubuf, tff2b, ff2b2, xc32, sumb, 4096, 512, 2048);
  ln_vec<128, false><<<4096, 128, 0, stream>>>(sumb, ln4g, ln4b, xd32, nullptr, 512);

  // ---- transpose back -> out ----
  transp<false><<<dim3(16, 8, 16), dim3(32, 8), 0, stream>>>(xd32, out_x, nullptr, 256, 512);
}

// Round 11
// 201.875 us; speedup vs baseline: 1.1842x; 1.0244x over previous
//
#include <hip/hip_runtime.h>
#include <cstddef>

// ---------------------------------------------------------------------------
// B=16, N=512, D=256, H=8, DH=16, INNER=128, SCALE=0.25
// R10 base (206.8us) + BK=128 in the thin mgemm64 GEMMs (four 32-col LDS
// sub-tiles): same bytes/MFMAs, half the barrier drains again. 16 launches.
// ---------------------------------------------------------------------------

typedef __attribute__((ext_vector_type(8))) short short8;
typedef __attribute__((ext_vector_type(4))) short bf16x4;
typedef __attribute__((ext_vector_type(4))) float f32x4;
typedef unsigned short u16t;

__device__ __forceinline__ u16t f2b(float f) {           // fp32 -> bf16 (RNE)
  union { float f; unsigned u; } x; x.f = f;
  unsigned r = (x.u + 0x7fffu + ((x.u >> 16) & 1u)) >> 16;
  return (u16t)r;
}

__device__ __forceinline__ void gload16(const void* g, void* l) {
  __builtin_amdgcn_global_load_lds(
      (const __attribute__((address_space(1))) void*)g,
      (__attribute__((address_space(3))) void*)l, 16, 0, 0);
}

// exact-GELU via Abramowitz-Stegun 7.1.26 erf (max abs err 1.5e-7)
__device__ __forceinline__ float gelu_f(float g) {
  const float x = g * 0.70710678118654752f;
  const float ax = fabsf(x);
  const float t = 1.f / (1.f + 0.3275911f * ax);
  const float p = t * (0.254829592f + t * (-0.284496736f +
                  t * (1.421413741f + t * (-1.453152027f + t * 1.061405429f))));
  const float er = 1.f - p * __expf(-x * x);
  return 0.5f * g * (1.f + copysignf(er, x));
}

// GEGLU weight-column permutation: n_new -> n_orig.
__device__ __forceinline__ int origcol(int n, int halfN) {
  const int nb = n >> 7, s = (n >> 4) & 7, r = n & 15;
  return ((s & 1) ? halfN : 0) + (nb << 6) + ((s >> 1) << 4) + r;
}

// ---------------- 128x128 MFMA GEMM, BK=64 (EPI 2 = fused GEGLU) -----------
template<int EPI>
__global__ __launch_bounds__(256) void mgemm(
    const u16t* __restrict__ A, const u16t* __restrict__ BT,
    const float* __restrict__ bias, const float* __restrict__ res,
    void* __restrict__ C, int M, int N, int K) {
  __shared__ u16t Al[2][128 * 32];   // two 32-col halves, 8 KB each
  __shared__ u16t Bl[2][128 * 32];
  const int t = threadIdx.x, lane = t & 63, wid = t >> 6;
  const int wr = wid >> 1, wc = wid & 1;
  const int lr = lane & 15, lq = lane >> 4;
  const int bm = blockIdx.y << 7, bn = blockIdx.x << 7;

  const int ao0 = wid * 2048 + lane * 16;
  const int ar0 = ao0 >> 6,          ac0 = (ao0 & 63) >> 1;
  const int ar1 = (ao0 + 1024) >> 6, ac1 = ((ao0 + 1024) & 63) >> 1;

  const u16t* Ab = A + (size_t)bm * K;
  const u16t* Bb = BT + (size_t)bn * K;

  f32x4 acc[4][4];
#pragma unroll
  for (int m = 0; m < 4; ++m)
#pragma unroll
    for (int n = 0; n < 4; ++n) acc[m][n] = (f32x4){0.f, 0.f, 0.f, 0.f};

  for (int k0 = 0; k0 < K; k0 += 64) {
#pragma unroll
    for (int h = 0; h < 2; ++h) {
      const int kh = k0 + h * 32;
      gload16(Ab + (size_t)ar0 * K + kh + ac0, (char*)Al[h] + wid * 2048);
      gload16(Ab + (size_t)ar1 * K + kh + ac1, (char*)Al[h] + wid * 2048 + 1024);
      gload16(Bb + (size_t)ar0 * K + kh + ac0, (char*)Bl[h] + wid * 2048);
      gload16(Bb + (size_t)ar1 * K + kh + ac1, (char*)Bl[h] + wid * 2048 + 1024);
    }
    __syncthreads();
#pragma unroll
    for (int h = 0; h < 2; ++h) {
      short8 af[4], bf[4];
#pragma unroll
      for (int m = 0; m < 4; ++m)
        af[m] = *(const short8*)&Al[h][(wr * 64 + m * 16 + lr) * 32 + lq * 8];
#pragma unroll
      for (int n = 0; n < 4; ++n)
        bf[n] = *(const short8*)&Bl[h][(wc * 64 + n * 16 + lr) * 32 + lq * 8];
#pragma unroll
      for (int m = 0; m < 4; ++m)
#pragma unroll
        for (int n = 0; n < 4; ++n)
          acc[m][n] = __builtin_amdgcn_mfma_f32_16x16x32_bf16(af[m], bf[n], acc[m][n], 0, 0, 0);
    }
    __syncthreads();
  }

  if (EPI == 2) {                    // fused bias + GEGLU (permuted cols)
    const int Nh = N >> 1;
#pragma unroll
    for (int np = 0; np < 2; ++np) {
      const int ca = bn + wc * 64 + np * 32 + lr;
      const float ba = bias[ca], bg = bias[ca + 16];
      const int uc = (bn >> 1) + wc * 32 + np * 16 + lr;
#pragma unroll
      for (int m = 0; m < 4; ++m) {
#pragma unroll
        for (int i = 0; i < 4; ++i) {
          const int row = bm + wr * 64 + m * 16 + lq * 4 + i;
          const float a = acc[m][2 * np][i] + ba;
          const float g = acc[m][2 * np + 1][i] + bg;
          ((u16t*)C)[(size_t)row * Nh + uc] = f2b(a * gelu_f(g));
        }
      }
    }
  } else {
#pragma unroll
    for (int n = 0; n < 4; ++n) {
      const int col = bn + wc * 64 + n * 16 + lr;
      const float bv = bias ? bias[col] : 0.f;
#pragma unroll
      for (int m = 0; m < 4; ++m) {
#pragma unroll
        for (int i = 0; i < 4; ++i) {
          const int row = bm + wr * 64 + m * 16 + lq * 4 + i;
          float v = acc[m][n][i] + bv;
          if (EPI == 1) {
            v += res[(size_t)row * N + col];
            ((float*)C)[(size_t)row * N + col] = v;
          } else {
            ((u16t*)C)[(size_t)row * N + col] = f2b(v);
          }
        }
      }
    }
  }
}

// ---------------- 64x64 MFMA GEMM, BK=128, for thin shapes -----------------
template<int EPI>
__global__ __launch_bounds__(256) void mgemm64(
    const u16t* __restrict__ A, const u16t* __restrict__ BT,
    const float* __restrict__ bias, const float* __restrict__ res,
    void* __restrict__ C, int M, int N, int K) {
  __shared__ u16t Al[4][64 * 32];    // four 32-col quarters, 4 KB each
  __shared__ u16t Bl[4][64 * 32];
  const int t = threadIdx.x, lane = t & 63, wid = t >> 6;
  const int wr = wid >> 1, wc = wid & 1;
  const int lr = lane & 15, lq = lane >> 4;
  const int bm = blockIdx.y << 6, bn = blockIdx.x << 6;
  const int ch = wid * 64 + lane;
  const int crow = ch >> 2, ccol = (ch & 3) << 3;

  const u16t* Ab = A + (size_t)bm * K;
  const u16t* Bb = BT + (size_t)bn * K;

  f32x4 acc[2][2];
#pragma unroll
  for (int m = 0; m < 2; ++m)
#pragma unroll
    for (int n = 0; n < 2; ++n) acc[m][n] = (f32x4){0.f, 0.f, 0.f, 0.f};

  for (int k0 = 0; k0 < K; k0 += 128) {
#pragma unroll
    for (int h = 0; h < 4; ++h) {
      const int kh = k0 + h * 32;
      gload16(Ab + (size_t)crow * K + kh + ccol, (char*)Al[h] + wid * 1024);
      gload16(Bb + (size_t)crow * K + kh + ccol, (char*)Bl[h] + wid * 1024);
    }
    __syncthreads();
#pragma unroll
    for (int h = 0; h < 4; ++h) {
      short8 af[2], bf[2];
#pragma unroll
      for (int m = 0; m < 2; ++m)
        af[m] = *(const short8*)&Al[h][(wr * 32 + m * 16 + lr) * 32 + lq * 8];
#pragma unroll
      for (int n = 0; n < 2; ++n)
        bf[n] = *(const short8*)&Bl[h][(wc * 32 + n * 16 + lr) * 32 + lq * 8];
#pragma unroll
      for (int m = 0; m < 2; ++m)
#pragma unroll
        for (int n = 0; n < 2; ++n)
          acc[m][n] = __builtin_amdgcn_mfma_f32_16x16x32_bf16(af[m], bf[n], acc[m][n], 0, 0, 0);
    }
    __syncthreads();
  }

#pragma unroll
  for (int n = 0; n < 2; ++n) {
    const int col = bn + wc * 32 + n * 16 + lr;
    const float bv = bias ? bias[col] : 0.f;
#pragma unroll
    for (int m = 0; m < 2; ++m) {
#pragma unroll
      for (int i = 0; i < 4; ++i) {
        const int row = bm + wr * 32 + m * 16 + lq * 4 + i;
        float v = acc[m][n][i] + bv;
        if (EPI == 1) {
          v += res[(size_t)row * N + col];
          ((float*)C)[(size_t)row * N + col] = v;
        } else {
          ((u16t*)C)[(size_t)row * N + col] = f2b(v);
        }
      }
    }
  }
}

// ---------------- wo-projection + bias + residual + LayerNorm, fused -------
template<int NW>
__global__ __launch_bounds__(256) void gemmlnF(
    const u16t* __restrict__ A, const u16t* __restrict__ BT,
    const float* __restrict__ bias, const float* __restrict__ res,
    const float* __restrict__ g, const float* __restrict__ be,
    float* __restrict__ y32, u16t* __restrict__ y16) {
  constexpr int NR = NW / 64;        // col frags per wave
  extern __shared__ u16t lds[];
  u16t* Al = lds;                    // [32][128] row-major
  u16t* Bl = lds + 32 * 128;         // [NW][128] row-major
  __shared__ float psum[4][32], psq[4][32];
  const int t = threadIdx.x, lane = t & 63, wid = t >> 6;
  const int lr = lane & 15, lq = lane >> 4;
  const int bm = blockIdx.x << 5;
  const int wofs = wid * (NW / 4);

  const int c0 = wid * 64 + lane;
#pragma unroll
  for (int j = 0; j < 2; ++j) {
    const int c = j * 256 + c0;
    gload16(A + (size_t)(bm + (c >> 4)) * 128 + ((c & 15) << 3),
            (char*)Al + (size_t)(j * 256 + wid * 64) * 16);
  }
#pragma unroll
  for (int j = 0; j < NW / 16; ++j) {
    const int c = j * 256 + c0;
    gload16(BT + (size_t)(c >> 4) * 128 + ((c & 15) << 3),
            (char*)Bl + (size_t)(j * 256 + wid * 64) * 16);
  }
  __syncthreads();

  f32x4 acc[2][NR];
#pragma unroll
  for (int m = 0; m < 2; ++m)
#pragma unroll
    for (int n = 0; n < NR; ++n) acc[m][n] = (f32x4){0.f, 0.f, 0.f, 0.f};

#pragma unroll
  for (int kk = 0; kk < 4; ++kk) {
    short8 af[2], bf[NR];
#pragma unroll
    for (int m = 0; m < 2; ++m)
      af[m] = *(const short8*)&Al[(m * 16 + lr) * 128 + kk * 32 + lq * 8];
#pragma unroll
    for (int n = 0; n < NR; ++n)
      bf[n] = *(const short8*)&Bl[(wofs + n * 16 + lr) * 128 + kk * 32 + lq * 8];
#pragma unroll
    for (int m = 0; m < 2; ++m)
#pragma unroll
      for (int n = 0; n < NR; ++n)
        acc[m][n] = __builtin_amdgcn_mfma_f32_16x16x32_bf16(af[m], bf[n], acc[m][n], 0, 0, 0);
  }

  float ps[2][4], ps2[2][4];
#pragma unroll
  for (int m = 0; m < 2; ++m)
#pragma unroll
    for (int i = 0; i < 4; ++i) { ps[m][i] = 0.f; ps2[m][i] = 0.f; }
#pragma unroll
  for (int m = 0; m < 2; ++m)
#pragma unroll
    for (int n = 0; n < NR; ++n) {
      const int col = wofs + n * 16 + lr;
      const float bv = bias[col];
#pragma unroll
      for (int i = 0; i < 4; ++i) {
        const int row = bm + m * 16 + lq * 4 + i;
        const float v = acc[m][n][i] + bv + res[(size_t)row * NW + col];
        acc[m][n][i] = v;
        ps[m][i] += v; ps2[m][i] += v * v;
      }
    }
#pragma unroll
  for (int m = 0; m < 2; ++m)
#pragma unroll
    for (int i = 0; i < 4; ++i) {
      float s = ps[m][i], s2 = ps2[m][i];
      s  += __shfl_xor(s, 1);  s  += __shfl_xor(s, 2);
      s  += __shfl_xor(s, 4);  s  += __shfl_xor(s, 8);
      s2 += __shfl_xor(s2, 1); s2 += __shfl_xor(s2, 2);
      s2 += __shfl_xor(s2, 4); s2 += __shfl_xor(s2, 8);
      if (lr == 0) {
        psum[wid][m * 16 + lq * 4 + i] = s;
        psq[wid][m * 16 + lq * 4 + i]  = s2;
      }
    }
  __syncthreads();
#pragma unroll
  for (int m = 0; m < 2; ++m)
#pragma unroll
    for (int i = 0; i < 4; ++i) {
      const int r = m * 16 + lq * 4 + i;
      const float tot = psum[0][r] + psum[1][r] + psum[2][r] + psum[3][r];
      const float tq  = psq[0][r]  + psq[1][r]  + psq[2][r]  + psq[3][r];
      const float mean = tot / NW;
      const float rstd = rsqrtf(tq / NW - mean * mean + 1e-5f);
      const int row = bm + r;
#pragma unroll
      for (int n = 0; n < NR; ++n) {
        const int col = wofs + n * 16 + lr;
        const float y = (acc[m][n][i] - mean) * rstd * g[col] + be[col];
        y32[(size_t)row * NW + col] = y;
        y16[(size_t)row * NW + col] = f2b(y);
      }
    }
}

// ---------------- MFMA attention ------------------------------------------
template<int NTOK>
__global__ __launch_bounds__(256) void attn_mfma(
    const u16t* __restrict__ qkv, float* __restrict__ share,
    u16t* __restrict__ outb) {
  __shared__ u16t VT[16][NTOK + 40];
  __shared__ u16t PB[4][16][40];
  const int t = threadIdx.x, lane = t & 63, wv = t >> 6;
  const int lr = lane & 15, lq = lane >> 4;
  const int bpb = NTOK / 64;
  const int bh = blockIdx.x / bpb, rg = blockIdx.x % bpb;
  const int b = bh >> 3, h = bh & 7;
  const u16t* qkvb = qkv + (size_t)b * NTOK * 384;

  for (int tok = t; tok < NTOK; tok += 256) {
    const u16t* vp = qkvb + (size_t)tok * 384 + 256 + h * 16;
    short8 v0 = *(const short8*)vp;
    short8 v1 = *(const short8*)(vp + 8);
#pragma unroll
    for (int d = 0; d < 8; ++d) {
      VT[d][tok]     = (u16t)v0[d];
      VT[d + 8][tok] = (u16t)v1[d];
    }
  }
  __syncthreads();

  const int i0 = rg * 64 + wv * 16;
  short8 qf = {0, 0, 0, 0, 0, 0, 0, 0};
  if (lq < 2)
    qf = *(const short8*)(qkvb + (size_t)(i0 + lr) * 384 + h * 16 + lq * 8);

  f32x4 oacc = {0.f, 0.f, 0.f, 0.f};
  f32x4 sacc = {0.f, 0.f, 0.f, 0.f};
  const f32x4 zero = {0.f, 0.f, 0.f, 0.f};
  float* shb = share + (size_t)bh * NTOK * NTOK;

  for (int t0 = 0; t0 < NTOK; t0 += 32) {
#pragma unroll
    for (int s2 = 0; s2 < 2; ++s2) {
      short8 kf = {0, 0, 0, 0, 0, 0, 0, 0};
      if (lq < 2)
        kf = *(const short8*)(qkvb + (size_t)(t0 + s2 * 16 + lr) * 384 + 128 + h * 16 + lq * 8);
      f32x4 e = __builtin_amdgcn_mfma_f32_16x16x32_bf16(qf, kf, zero, 0, 0, 0);
#pragma unroll
      for (int i = 0; i < 4; ++i) {
        const float ev = e[i] * 0.25f;
        shb[(size_t)(i0 + lq * 4 + i) * NTOK + t0 + s2 * 16 + lr] = ev;
        const float p = __expf(ev);
        sacc[i] += p;
        PB[wv][lq * 4 + i][s2 * 16 + lr] = f2b(p);
      }
    }
    asm volatile("s_waitcnt lgkmcnt(0)" ::: "memory");
    __builtin_amdgcn_sched_barrier(0);
    short8 pa = *(const short8*)&PB[wv][lr][lq * 8];
    short8 vf = *(const short8*)&VT[lr][t0 + lq * 8];
    oacc = __builtin_amdgcn_mfma_f32_16x16x32_bf16(pa, vf, oacc, 0, 0, 0);
    __builtin_amdgcn_sched_barrier(0);
  }
#pragma unroll
  for (int i = 0; i < 4; ++i) {
    float s = sacc[i];
    s += __shfl_xor(s, 1); s += __shfl_xor(s, 2);
    s += __shfl_xor(s, 4); s += __shfl_xor(s, 8);
    sacc[i] = s;
  }
#pragma unroll
  for (int i = 0; i < 4; ++i) {
    const float o = oacc[i] / sacc[i];
    outb[((size_t)(b * NTOK) + i0 + lq * 4 + i) * 128 + h * 16 + lr] = f2b(o);
  }
}

// ---------------- LayerNorm (input pre-summed), float4 vectorized ----------
template<int NT, bool B16>
__global__ __launch_bounds__(NT) void ln_vec(
    const float* __restrict__ xin, const float* __restrict__ g,
    const float* __restrict__ be, float* __restrict__ y32,
    u16t* __restrict__ y16, int D) {
  const int row = blockIdx.x, t = threadIdx.x;
  const int lane = t & 63;
  const float4 x = ((const float4*)xin)[(size_t)row * (D >> 2) + t];
  float s = x.x + x.y + x.z + x.w;
  float s2 = x.x * x.x + x.y * x.y + x.z * x.z + x.w * x.w;
#pragma unroll
  for (int off = 32; off; off >>= 1) {
    s  += __shfl_xor(s, off);
    s2 += __shfl_xor(s2, off);
  }
  if (NT == 128) {
    __shared__ float a1[2], a2[2];
    const int wv = t >> 6;
    if (lane == 0) { a1[wv] = s; a2[wv] = s2; }
    __syncthreads();
    s = a1[0] + a1[1]; s2 = a2[0] + a2[1];
  }
  const float mean = s / D;
  const float var  = s2 / D - mean * mean;
  const float rstd = rsqrtf(var + 1e-5f);
  const float4 gv = ((const float4*)g)[t];
  const float4 bv = ((const float4*)be)[t];
  float4 y;
  y.x = (x.x - mean) * rstd * gv.x + bv.x;
  y.y = (x.y - mean) * rstd * gv.y + bv.y;
  y.z = (x.z - mean) * rstd * gv.z + bv.z;
  y.w = (x.w - mean) * rstd * gv.w + bv.w;
  ((float4*)y32)[(size_t)row * (D >> 2) + t] = y;
  if (B16) {
    bf16x4 p;
    p[0] = (short)f2b(y.x); p[1] = (short)f2b(y.y);
    p[2] = (short)f2b(y.z); p[3] = (short)f2b(y.w);
    *(bf16x4*)&y16[(size_t)row * D + t * 4] = p;
  }
}

// ---------------- batched transpose [B][R][C]->[B][C][R], opt bf16 twin ----
template<bool BF16OUT>
__global__ void transp(const float* __restrict__ in, float* __restrict__ out32,
                       u16t* __restrict__ out16, int R, int C) {
  __shared__ float tile[32][33];
  const int b = blockIdx.z;
  const int r0 = blockIdx.y << 5, c0 = blockIdx.x << 5;
  const float* inb = in + (size_t)b * R * C;
  const int tx = threadIdx.x, ty = threadIdx.y;
#pragma unroll
  for (int dy = 0; dy < 32; dy += 8)
    tile[ty + dy][tx] = inb[(size_t)(r0 + ty + dy) * C + c0 + tx];
  __syncthreads();
#pragma unroll
  for (int dy = 0; dy < 32; dy += 8) {
    const float v = tile[tx][ty + dy];
    const size_t idx = (size_t)b * R * C + (size_t)(c0 + ty + dy) * R + r0 + tx;
    out32[idx] = v;
    if (BF16OUT) out16[idx] = f2b(v);
  }
}

// ---------------- one-shot prep -------------------------------------------
__global__ __launch_bounds__(256) void prep_all(
    const float* __restrict__ x0, u16t* __restrict__ x16,
    const float* __restrict__ wqkv1, u16t* __restrict__ tqkv1,
    const float* __restrict__ wo1,   u16t* __restrict__ two1,
    const float* __restrict__ ff1w1, u16t* __restrict__ tff1a,
    const float* __restrict__ ff1w2, u16t* __restrict__ tff1b,
    const float* __restrict__ wqkv2, u16t* __restrict__ tqkv2,
    const float* __restrict__ wo2,   u16t* __restrict__ two2,
    const float* __restrict__ ff2w1, u16t* __restrict__ tff2a,
    const float* __restrict__ ff2w2, u16t* __restrict__ tff2b,
    const float* __restrict__ ff1b1, float* __restrict__ bp1,
    const float* __restrict__ ff2b1, float* __restrict__ bp2) {
  __shared__ float tile[32][33];
  const int b = blockIdx.x, t = threadIdx.x;
  const int tx = t & 31, ty = t >> 5;
  const float* src; u16t* dst;
  int K, N, bxd, blk, halfN = 0; bool perm = false;
  if (b < 1024) {
    const float* p = x0 + (size_t)(b * 256 + t) * 8;
    short8 v;
#pragma unroll
    for (int j = 0; j < 8; ++j) v[j] = (short)f2b(p[j]);
    *(short8*)(x16 + (size_t)(b * 256 + t) * 8) = v;
    return;
  } else if (b < 1120) { src = wqkv1; dst = tqkv1; K = 256;  N = 384;  bxd = 12;  blk = b - 1024; }
  else if (b < 1152)   { src = wo1;   dst = two1;  K = 128;  N = 256;  bxd = 8;   blk = b - 1120; }
  else if (b < 1664)   { src = ff1w1; dst = tff1a; K = 256;  N = 2048; bxd = 64;  blk = b - 1152; perm = true; halfN = 1024; }
  else if (b < 1920)   { src = ff1w2; dst = tff1b; K = 1024; N = 256;  bxd = 8;   blk = b - 1664; }
  else if (b < 2112)   { src = wqkv2; dst = tqkv2; K = 512;  N = 384;  bxd = 12;  blk = b - 1920; }
  else if (b < 2176)   { src = wo2;   dst = two2;  K = 128;  N = 512;  bxd = 16;  blk = b - 2112; }
  else if (b < 4224)   { src = ff2w1; dst = tff2a; K = 512;  N = 4096; bxd = 128; blk = b - 2176; perm = true; halfN = 2048; }
  else if (b < 5248)   { src = ff2w2; dst = tff2b; K = 2048; N = 512;  bxd = 16;  blk = b - 4224; }
  else if (b < 5256) { const int n = (b - 5248) * 256 + t; bp1[n] = ff1b1[origcol(n, 1024)]; return; }
  else               { const int n = (b - 5256) * 256 + t; bp2[n] = ff2b1[origcol(n, 2048)]; return; }

  const int bx = blk % bxd, by = blk / bxd;
  const int n0 = bx * 32, k0 = by * 32;
  const int nn = n0 + tx;
  const int no = perm ? origcol(nn, halfN) : nn;
#pragma unroll
  for (int dy = 0; dy < 32; dy += 8)
    tile[ty + dy][tx] = src[(size_t)(k0 + ty + dy) * N + no];
  __syncthreads();
#pragma unroll
  for (int dy = 0; dy < 32; dy += 8)
    dst[(size_t)(n0 + ty + dy) * K + k0 + tx] = f2b(tile[tx][ty + dy]);
}

// ---------------------------------------------------------------------------
extern "C" void kernel_launch(void* const* d_in, const int* in_sizes, int n_in,
                              void* d_out, int out_size, void* d_ws, size_t ws_size,
                              hipStream_t stream) {
  (void)in_sizes; (void)n_in; (void)out_size; (void)ws_size;
  const float* x0    = (const float*)d_in[0];
  const float* wqkv1 = (const float*)d_in[1];
  const float* wo1   = (const float*)d_in[2];
  const float* bo1   = (const float*)d_in[3];
  const float* ff1w1 = (const float*)d_in[4];
  const float* ff1b1 = (const float*)d_in[5];
  const float* ff1w2 = (const float*)d_in[6];
  const float* ff1b2 = (const float*)d_in[7];
  const float* wqkv2 = (const float*)d_in[8];
  const float* wo2   = (const float*)d_in[9];
  const float* bo2   = (const float*)d_in[10];
  const float* ff2w1 = (const float*)d_in[11];
  const float* ff2b1 = (const float*)d_in[12];
  const float* ff2w2 = (const float*)d_in[13];
  const float* ff2b2 = (const float*)d_in[14];
  const float* ln1g  = (const float*)d_in[15];
  const float* ln1b  = (const float*)d_in[16];
  const float* ln2g  = (const float*)d_in[17];
  const float* ln2b  = (const float*)d_in[18];
  const float* ln3g  = (const float*)d_in[19];
  const float* ln3b  = (const float*)d_in[20];
  const float* ln4g  = (const float*)d_in[21];
  const float* ln4b  = (const float*)d_in[22];

  float* out_x  = (float*)d_out;
  float* share1 = out_x + (size_t)2097152;
  float* share2 = share1 + (size_t)33554432;

  size_t off = 0;
  auto carve = [&](size_t bytes) -> void* {
    void* p = (char*)d_ws + off;
    off += (bytes + 255) & ~(size_t)255;
    return p;
  };
  u16t*  x16    = (u16t*)carve((size_t)8192 * 256 * 2);
  u16t*  qkv16  = (u16t*)carve((size_t)8192 * 384 * 2);
  u16t*  attn16 = (u16t*)carve((size_t)8192 * 128 * 2);
  float* sumb   = (float*)carve((size_t)8192 * 256 * 4);
  float* xa32   = (float*)carve((size_t)8192 * 256 * 4);
  u16t*  xa16   = (u16t*)carve((size_t)8192 * 256 * 2);
  float* xb32   = (float*)carve((size_t)8192 * 256 * 4);
  float* xt32   = (float*)carve((size_t)8192 * 256 * 4);
  u16t*  xt16   = (u16t*)carve((size_t)8192 * 256 * 2);
  float* xc32   = (float*)carve((size_t)8192 * 256 * 4);
  u16t*  xc16   = (u16t*)carve((size_t)8192 * 256 * 2);
  float* xd32   = (float*)carve((size_t)8192 * 256 * 4);
  u16t*  ubuf   = (u16t*)carve((size_t)8192 * 1024 * 2);
  u16t*  tqkv1  = (u16t*)carve((size_t)384 * 256 * 2);
  u16t*  two1   = (u16t*)carve((size_t)256 * 128 * 2);
  u16t*  tff1a  = (u16t*)carve((size_t)2048 * 256 * 2);
  u16t*  tff1b  = (u16t*)carve((size_t)256 * 1024 * 2);
  u16t*  tqkv2  = (u16t*)carve((size_t)384 * 512 * 2);
  u16t*  two2   = (u16t*)carve((size_t)512 * 128 * 2);
  u16t*  tff2a  = (u16t*)carve((size_t)4096 * 512 * 2);
  u16t*  tff2b  = (u16t*)carve((size_t)512 * 2048 * 2);
  float* bp1    = (float*)carve((size_t)2048 * 4);
  float* bp2    = (float*)carve((size_t)4096 * 4);

  // dynamic-LDS opt-in for the fused wo+LN kernels (72 KB / 136 KB)
  (void)hipFuncSetAttribute(reinterpret_cast<const void*>(&gemmlnF<256>),
                            hipFuncAttributeMaxDynamicSharedMemorySize, 73728);
  (void)hipFuncSetAttribute(reinterpret_cast<const void*>(&gemmlnF<512>),
                            hipFuncAttributeMaxDynamicSharedMemorySize, 139264);

  prep_all<<<5272, 256, 0, stream>>>(x0, x16, wqkv1, tqkv1, wo1, two1,
      ff1w1, tff1a, ff1w2, tff1b, wqkv2, tqkv2, wo2, two2,
      ff2w1, tff2a, ff2w2, tff2b, ff1b1, bp1, ff2b1, bp2);

  // ---- stage 1 (tokens=512, feat=256) ----
  mgemm64<0><<<dim3(6, 128), 256, 0, stream>>>(x16, tqkv1, nullptr, nullptr, qkv16, 8192, 384, 256);
  attn_mfma<512><<<1024, 256, 0, stream>>>(qkv16, share1, attn16);
  gemmlnF<256><<<256, 256, 73728, stream>>>(attn16, two1, bo1, x0, ln1g, ln1b, xa32, xa16);
  mgemm<2><<<dim3(16, 64), 256, 0, stream>>>(xa16, tff1a, bp1, nullptr, ubuf, 8192, 2048, 256);
  mgemm64<1><<<dim3(4, 128), 256, 0, stream>>>(ubuf, tff1b, ff1b2, xa32, sumb, 8192, 256, 1024);
  ln_vec<64, false><<<8192, 64, 0, stream>>>(sumb, ln2g, ln2b, xb32, nullptr, 256);

  // ---- transpose to [B,256,512] ----
  transp<true><<<dim3(8, 16, 16), dim3(32, 8), 0, stream>>>(xb32, xt32, xt16, 512, 256);

  // ---- stage 2 (tokens=256, feat=512) ----
  mgemm64<0><<<dim3(6, 64), 256, 0, stream>>>(xt16, tqkv2, nullptr, nullptr, qkv16, 4096, 384, 512);
  attn_mfma<256><<<512, 256, 0, stream>>>(qkv16, share2, attn16);
  gemmlnF<512><<<128, 256, 139264, stream>>>(attn16, two2, bo2, xt32, ln3g, ln3b, xc32, xc16);
  mgemm<2><<<dim3(32, 32), 256, 0, stream>>>(xc16, tff2a, bp2, nullptr, ubuf, 4096, 4096, 512);
  mgemm64<1><<<dim3(8, 64), 256, 0, stream>>>(ubuf, tff2b, ff2b2, xc32, sumb, 4096, 512, 2048);
  ln_vec<128, false><<<4096, 128, 0, stream>>>(sumb, ln4g, ln4b, xd32, nullptr, 512);

  // ---- transpose back -> out ----
  transp<false><<<dim3(16, 8, 16), dim3(32, 8), 0, stream>>>(xd32, out_x, nullptr, 256, 512);
}

// Round 13
// 198.924 us; speedup vs baseline: 1.2017x; 1.0148x over previous
//
#include <hip/hip_runtime.h>
#include <cstddef>

// ---------------------------------------------------------------------------
// B=16, N=512, D=256, H=8, DH=16, INNER=128, SCALE=0.25
// R11 base (201.9us) + gemmlnF BM parameterized (<512> at BM=16 -> grid 256
// fills all CUs). R12's A-staging loop-bound bug FIXED (j < BM/16; ++j).
// 16 launches.
// ---------------------------------------------------------------------------

typedef __attribute__((ext_vector_type(8))) short short8;
typedef __attribute__((ext_vector_type(4))) short bf16x4;
typedef __attribute__((ext_vector_type(4))) float f32x4;
typedef unsigned short u16t;

__device__ __forceinline__ u16t f2b(float f) {           // fp32 -> bf16 (RNE)
  union { float f; unsigned u; } x; x.f = f;
  unsigned r = (x.u + 0x7fffu + ((x.u >> 16) & 1u)) >> 16;
  return (u16t)r;
}

__device__ __forceinline__ void gload16(const void* g, void* l) {
  __builtin_amdgcn_global_load_lds(
      (const __attribute__((address_space(1))) void*)g,
      (__attribute__((address_space(3))) void*)l, 16, 0, 0);
}

// exact-GELU via Abramowitz-Stegun 7.1.26 erf (max abs err 1.5e-7)
__device__ __forceinline__ float gelu_f(float g) {
  const float x = g * 0.70710678118654752f;
  const float ax = fabsf(x);
  const float t = 1.f / (1.f + 0.3275911f * ax);
  const float p = t * (0.254829592f + t * (-0.284496736f +
                  t * (1.421413741f + t * (-1.453152027f + t * 1.061405429f))));
  const float er = 1.f - p * __expf(-x * x);
  return 0.5f * g * (1.f + copysignf(er, x));
}

// GEGLU weight-column permutation: n_new -> n_orig.
__device__ __forceinline__ int origcol(int n, int halfN) {
  const int nb = n >> 7, s = (n >> 4) & 7, r = n & 15;
  return ((s & 1) ? halfN : 0) + (nb << 6) + ((s >> 1) << 4) + r;
}

// ---------------- 128x128 MFMA GEMM, BK=64 (EPI 2 = fused GEGLU) -----------
template<int EPI>
__global__ __launch_bounds__(256) void mgemm(
    const u16t* __restrict__ A, const u16t* __restrict__ BT,
    const float* __restrict__ bias, const float* __restrict__ res,
    void* __restrict__ C, int M, int N, int K) {
  __shared__ u16t Al[2][128 * 32];   // two 32-col halves, 8 KB each
  __shared__ u16t Bl[2][128 * 32];
  const int t = threadIdx.x, lane = t & 63, wid = t >> 6;
  const int wr = wid >> 1, wc = wid & 1;
  const int lr = lane & 15, lq = lane >> 4;
  const int bm = blockIdx.y << 7, bn = blockIdx.x << 7;

  const int ao0 = wid * 2048 + lane * 16;
  const int ar0 = ao0 >> 6,          ac0 = (ao0 & 63) >> 1;
  const int ar1 = (ao0 + 1024) >> 6, ac1 = ((ao0 + 1024) & 63) >> 1;

  const u16t* Ab = A + (size_t)bm * K;
  const u16t* Bb = BT + (size_t)bn * K;

  f32x4 acc[4][4];
#pragma unroll
  for (int m = 0; m < 4; ++m)
#pragma unroll
    for (int n = 0; n < 4; ++n) acc[m][n] = (f32x4){0.f, 0.f, 0.f, 0.f};

  for (int k0 = 0; k0 < K; k0 += 64) {
#pragma unroll
    for (int h = 0; h < 2; ++h) {
      const int kh = k0 + h * 32;
      gload16(Ab + (size_t)ar0 * K + kh + ac0, (char*)Al[h] + wid * 2048);
      gload16(Ab + (size_t)ar1 * K + kh + ac1, (char*)Al[h] + wid * 2048 + 1024);
      gload16(Bb + (size_t)ar0 * K + kh + ac0, (char*)Bl[h] + wid * 2048);
      gload16(Bb + (size_t)ar1 * K + kh + ac1, (char*)Bl[h] + wid * 2048 + 1024);
    }
    __syncthreads();
#pragma unroll
    for (int h = 0; h < 2; ++h) {
      short8 af[4], bf[4];
#pragma unroll
      for (int m = 0; m < 4; ++m)
        af[m] = *(const short8*)&Al[h][(wr * 64 + m * 16 + lr) * 32 + lq * 8];
#pragma unroll
      for (int n = 0; n < 4; ++n)
        bf[n] = *(const short8*)&Bl[h][(wc * 64 + n * 16 + lr) * 32 + lq * 8];
#pragma unroll
      for (int m = 0; m < 4; ++m)
#pragma unroll
        for (int n = 0; n < 4; ++n)
          acc[m][n] = __builtin_amdgcn_mfma_f32_16x16x32_bf16(af[m], bf[n], acc[m][n], 0, 0, 0);
    }
    __syncthreads();
  }

  if (EPI == 2) {                    // fused bias + GEGLU (permuted cols)
    const int Nh = N >> 1;
#pragma unroll
    for (int np = 0; np < 2; ++np) {
      const int ca = bn + wc * 64 + np * 32 + lr;
      const float ba = bias[ca], bg = bias[ca + 16];
      const int uc = (bn >> 1) + wc * 32 + np * 16 + lr;
#pragma unroll
      for (int m = 0; m < 4; ++m) {
#pragma unroll
        for (int i = 0; i < 4; ++i) {
          const int row = bm + wr * 64 + m * 16 + lq * 4 + i;
          const float a = acc[m][2 * np][i] + ba;
          const float g = acc[m][2 * np + 1][i] + bg;
          ((u16t*)C)[(size_t)row * Nh + uc] = f2b(a * gelu_f(g));
        }
      }
    }
  } else {
#pragma unroll
    for (int n = 0; n < 4; ++n) {
      const int col = bn + wc * 64 + n * 16 + lr;
      const float bv = bias ? bias[col] : 0.f;
#pragma unroll
      for (int m = 0; m < 4; ++m) {
#pragma unroll
        for (int i = 0; i < 4; ++i) {
          const int row = bm + wr * 64 + m * 16 + lq * 4 + i;
          float v = acc[m][n][i] + bv;
          if (EPI == 1) {
            v += res[(size_t)row * N + col];
            ((float*)C)[(size_t)row * N + col] = v;
          } else {
            ((u16t*)C)[(size_t)row * N + col] = f2b(v);
          }
        }
      }
    }
  }
}

// ---------------- 64x64 MFMA GEMM, BK=128, for thin shapes -----------------
template<int EPI>
__global__ __launch_bounds__(256) void mgemm64(
    const u16t* __restrict__ A, const u16t* __restrict__ BT,
    const float* __restrict__ bias, const float* __restrict__ res,
    void* __restrict__ C, int M, int N, int K) {
  __shared__ u16t Al[4][64 * 32];    // four 32-col quarters, 4 KB each
  __shared__ u16t Bl[4][64 * 32];
  const int t = threadIdx.x, lane = t & 63, wid = t >> 6;
  const int wr = wid >> 1, wc = wid & 1;
  const int lr = lane & 15, lq = lane >> 4;
  const int bm = blockIdx.y << 6, bn = blockIdx.x << 6;
  const int ch = wid * 64 + lane;
  const int crow = ch >> 2, ccol = (ch & 3) << 3;

  const u16t* Ab = A + (size_t)bm * K;
  const u16t* Bb = BT + (size_t)bn * K;

  f32x4 acc[2][2];
#pragma unroll
  for (int m = 0; m < 2; ++m)
#pragma unroll
    for (int n = 0; n < 2; ++n) acc[m][n] = (f32x4){0.f, 0.f, 0.f, 0.f};

  for (int k0 = 0; k0 < K; k0 += 128) {
#pragma unroll
    for (int h = 0; h < 4; ++h) {
      const int kh = k0 + h * 32;
      gload16(Ab + (size_t)crow * K + kh + ccol, (char*)Al[h] + wid * 1024);
      gload16(Bb + (size_t)crow * K + kh + ccol, (char*)Bl[h] + wid * 1024);
    }
    __syncthreads();
#pragma unroll
    for (int h = 0; h < 4; ++h) {
      short8 af[2], bf[2];
#pragma unroll
      for (int m = 0; m < 2; ++m)
        af[m] = *(const short8*)&Al[h][(wr * 32 + m * 16 + lr) * 32 + lq * 8];
#pragma unroll
      for (int n = 0; n < 2; ++n)
        bf[n] = *(const short8*)&Bl[h][(wc * 32 + n * 16 + lr) * 32 + lq * 8];
#pragma unroll
      for (int m = 0; m < 2; ++m)
#pragma unroll
        for (int n = 0; n < 2; ++n)
          acc[m][n] = __builtin_amdgcn_mfma_f32_16x16x32_bf16(af[m], bf[n], acc[m][n], 0, 0, 0);
    }
    __syncthreads();
  }

#pragma unroll
  for (int n = 0; n < 2; ++n) {
    const int col = bn + wc * 32 + n * 16 + lr;
    const float bv = bias ? bias[col] : 0.f;
#pragma unroll
    for (int m = 0; m < 2; ++m) {
#pragma unroll
      for (int i = 0; i < 4; ++i) {
        const int row = bm + wr * 32 + m * 16 + lq * 4 + i;
        float v = acc[m][n][i] + bv;
        if (EPI == 1) {
          v += res[(size_t)row * N + col];
          ((float*)C)[(size_t)row * N + col] = v;
        } else {
          ((u16t*)C)[(size_t)row * N + col] = f2b(v);
        }
      }
    }
  }
}

// ---------------- wo-projection + bias + residual + LayerNorm, fused -------
// C = LN(A[M,128] @ BT[NW,128]^T + bias + res). Whole B staged in LDS once.
// BM rows/block (BM=16 for NW=512 so grid fills all 256 CUs).
template<int NW, int BM>
__global__ __launch_bounds__(256) void gemmlnF(
    const u16t* __restrict__ A, const u16t* __restrict__ BT,
    const float* __restrict__ bias, const float* __restrict__ res,
    const float* __restrict__ g, const float* __restrict__ be,
    float* __restrict__ y32, u16t* __restrict__ y16) {
  constexpr int NR = NW / 64;        // col frags per wave
  constexpr int MR = BM / 16;        // row frags
  extern __shared__ u16t lds[];
  u16t* Al = lds;                    // [BM][128] row-major
  u16t* Bl = lds + BM * 128;         // [NW][128] row-major
  __shared__ float psum[4][BM], psq[4][BM];
  const int t = threadIdx.x, lane = t & 63, wid = t >> 6;
  const int lr = lane & 15, lq = lane >> 4;
  const int bm = blockIdx.x * BM;
  const int wofs = wid * (NW / 4);

  // stage A: BM*16 chunks of 16B, 256/iter (verified form from R9,
  // generalized: BM/16 iterations)
  const int c0 = wid * 64 + lane;
#pragma unroll
  for (int j = 0; j < BM / 16; ++j) {
    const int c = j * 256 + c0;
    gload16(A + (size_t)(bm + (c >> 4)) * 128 + ((c & 15) << 3),
            (char*)Al + (size_t)(j * 256 + wid * 64) * 16);
  }
#pragma unroll
  for (int j = 0; j < NW / 16; ++j) {
    const int c = j * 256 + c0;
    gload16(BT + (size_t)(c >> 4) * 128 + ((c & 15) << 3),
            (char*)Bl + (size_t)(j * 256 + wid * 64) * 16);
  }
  __syncthreads();

  f32x4 acc[MR][NR];
#pragma unroll
  for (int m = 0; m < MR; ++m)
#pragma unroll
    for (int n = 0; n < NR; ++n) acc[m][n] = (f32x4){0.f, 0.f, 0.f, 0.f};

#pragma unroll
  for (int kk = 0; kk < 4; ++kk) {
    short8 af[MR], bf[NR];
#pragma unroll
    for (int m = 0; m < MR; ++m)
      af[m] = *(const short8*)&Al[(m * 16 + lr) * 128 + kk * 32 + lq * 8];
#pragma unroll
    for (int n = 0; n < NR; ++n)
      bf[n] = *(const short8*)&Bl[(wofs + n * 16 + lr) * 128 + kk * 32 + lq * 8];
#pragma unroll
    for (int m = 0; m < MR; ++m)
#pragma unroll
      for (int n = 0; n < NR; ++n)
        acc[m][n] = __builtin_amdgcn_mfma_f32_16x16x32_bf16(af[m], bf[n], acc[m][n], 0, 0, 0);
  }

  float ps[MR][4], ps2[MR][4];
#pragma unroll
  for (int m = 0; m < MR; ++m)
#pragma unroll
    for (int i = 0; i < 4; ++i) { ps[m][i] = 0.f; ps2[m][i] = 0.f; }
#pragma unroll
  for (int m = 0; m < MR; ++m)
#pragma unroll
    for (int n = 0; n < NR; ++n) {
      const int col = wofs + n * 16 + lr;
      const float bv = bias[col];
#pragma unroll
      for (int i = 0; i < 4; ++i) {
        const int row = bm + m * 16 + lq * 4 + i;
        const float v = acc[m][n][i] + bv + res[(size_t)row * NW + col];
        acc[m][n][i] = v;
        ps[m][i] += v; ps2[m][i] += v * v;
      }
    }
#pragma unroll
  for (int m = 0; m < MR; ++m)
#pragma unroll
    for (int i = 0; i < 4; ++i) {
      float s = ps[m][i], s2 = ps2[m][i];
      s  += __shfl_xor(s, 1);  s  += __shfl_xor(s, 2);
      s  += __shfl_xor(s, 4);  s  += __shfl_xor(s, 8);
      s2 += __shfl_xor(s2, 1); s2 += __shfl_xor(s2, 2);
      s2 += __shfl_xor(s2, 4); s2 += __shfl_xor(s2, 8);
      if (lr == 0) {
        psum[wid][m * 16 + lq * 4 + i] = s;
        psq[wid][m * 16 + lq * 4 + i]  = s2;
      }
    }
  __syncthreads();
#pragma unroll
  for (int m = 0; m < MR; ++m)
#pragma unroll
    for (int i = 0; i < 4; ++i) {
      const int r = m * 16 + lq * 4 + i;
      const float tot = psum[0][r] + psum[1][r] + psum[2][r] + psum[3][r];
      const float tq  = psq[0][r]  + psq[1][r]  + psq[2][r]  + psq[3][r];
      const float mean = tot / NW;
      const float rstd = rsqrtf(tq / NW - mean * mean + 1e-5f);
      const int row = bm + r;
#pragma unroll
      for (int n = 0; n < NR; ++n) {
        const int col = wofs + n * 16 + lr;
        const float y = (acc[m][n][i] - mean) * rstd * g[col] + be[col];
        y32[(size_t)row * NW + col] = y;
        y16[(size_t)row * NW + col] = f2b(y);
      }
    }
}

// ---------------- MFMA attention ------------------------------------------
template<int NTOK>
__global__ __launch_bounds__(256) void attn_mfma(
    const u16t* __restrict__ qkv, float* __restrict__ share,
    u16t* __restrict__ outb) {
  __shared__ u16t VT[16][NTOK + 40];
  __shared__ u16t PB[4][16][40];
  const int t = threadIdx.x, lane = t & 63, wv = t >> 6;
  const int lr = lane & 15, lq = lane >> 4;
  const int bpb = NTOK / 64;
  const int bh = blockIdx.x / bpb, rg = blockIdx.x % bpb;
  const int b = bh >> 3, h = bh & 7;
  const u16t* qkvb = qkv + (size_t)b * NTOK * 384;

  for (int tok = t; tok < NTOK; tok += 256) {
    const u16t* vp = qkvb + (size_t)tok * 384 + 256 + h * 16;
    short8 v0 = *(const short8*)vp;
    short8 v1 = *(const short8*)(vp + 8);
#pragma unroll
    for (int d = 0; d < 8; ++d) {
      VT[d][tok]     = (u16t)v0[d];
      VT[d + 8][tok] = (u16t)v1[d];
    }
  }
  __syncthreads();

  const int i0 = rg * 64 + wv * 16;
  short8 qf = {0, 0, 0, 0, 0, 0, 0, 0};
  if (lq < 2)
    qf = *(const short8*)(qkvb + (size_t)(i0 + lr) * 384 + h * 16 + lq * 8);

  f32x4 oacc = {0.f, 0.f, 0.f, 0.f};
  f32x4 sacc = {0.f, 0.f, 0.f, 0.f};
  const f32x4 zero = {0.f, 0.f, 0.f, 0.f};
  float* shb = share + (size_t)bh * NTOK * NTOK;

  for (int t0 = 0; t0 < NTOK; t0 += 32) {
#pragma unroll
    for (int s2 = 0; s2 < 2; ++s2) {
      short8 kf = {0, 0, 0, 0, 0, 0, 0, 0};
      if (lq < 2)
        kf = *(const short8*)(qkvb + (size_t)(t0 + s2 * 16 + lr) * 384 + 128 + h * 16 + lq * 8);
      f32x4 e = __builtin_amdgcn_mfma_f32_16x16x32_bf16(qf, kf, zero, 0, 0, 0);
#pragma unroll
      for (int i = 0; i < 4; ++i) {
        const float ev = e[i] * 0.25f;
        shb[(size_t)(i0 + lq * 4 + i) * NTOK + t0 + s2 * 16 + lr] = ev;
        const float p = __expf(ev);
        sacc[i] += p;
        PB[wv][lq * 4 + i][s2 * 16 + lr] = f2b(p);
      }
    }
    asm volatile("s_waitcnt lgkmcnt(0)" ::: "memory");
    __builtin_amdgcn_sched_barrier(0);
    short8 pa = *(const short8*)&PB[wv][lr][lq * 8];
    short8 vf = *(const short8*)&VT[lr][t0 + lq * 8];
    oacc = __builtin_amdgcn_mfma_f32_16x16x32_bf16(pa, vf, oacc, 0, 0, 0);
    __builtin_amdgcn_sched_barrier(0);
  }
#pragma unroll
  for (int i = 0; i < 4; ++i) {
    float s = sacc[i];
    s += __shfl_xor(s, 1); s += __shfl_xor(s, 2);
    s += __shfl_xor(s, 4); s += __shfl_xor(s, 8);
    sacc[i] = s;
  }
#pragma unroll
  for (int i = 0; i < 4; ++i) {
    const float o = oacc[i] / sacc[i];
    outb[((size_t)(b * NTOK) + i0 + lq * 4 + i) * 128 + h * 16 + lr] = f2b(o);
  }
}

// ---------------- LayerNorm (input pre-summed), float4 vectorized ----------
template<int NT, bool B16>
__global__ __launch_bounds__(NT) void ln_vec(
    const float* __restrict__ xin, const float* __restrict__ g,
    const float* __restrict__ be, float* __restrict__ y32,
    u16t* __restrict__ y16, int D) {
  const int row = blockIdx.x, t = threadIdx.x;
  const int lane = t & 63;
  const float4 x = ((const float4*)xin)[(size_t)row * (D >> 2) + t];
  float s = x.x + x.y + x.z + x.w;
  float s2 = x.x * x.x + x.y * x.y + x.z * x.z + x.w * x.w;
#pragma unroll
  for (int off = 32; off; off >>= 1) {
    s  += __shfl_xor(s, off);
    s2 += __shfl_xor(s2, off);
  }
  if (NT == 128) {
    __shared__ float a1[2], a2[2];
    const int wv = t >> 6;
    if (lane == 0) { a1[wv] = s; a2[wv] = s2; }
    __syncthreads();
    s = a1[0] + a1[1]; s2 = a2[0] + a2[1];
  }
  const float mean = s / D;
  const float var  = s2 / D - mean * mean;
  const float rstd = rsqrtf(var + 1e-5f);
  const float4 gv = ((const float4*)g)[t];
  const float4 bv = ((const float4*)be)[t];
  float4 y;
  y.x = (x.x - mean) * rstd * gv.x + bv.x;
  y.y = (x.y - mean) * rstd * gv.y + bv.y;
  y.z = (x.z - mean) * rstd * gv.z + bv.z;
  y.w = (x.w - mean) * rstd * gv.w + bv.w;
  ((float4*)y32)[(size_t)row * (D >> 2) + t] = y;
  if (B16) {
    bf16x4 p;
    p[0] = (short)f2b(y.x); p[1] = (short)f2b(y.y);
    p[2] = (short)f2b(y.z); p[3] = (short)f2b(y.w);
    *(bf16x4*)&y16[(size_t)row * D + t * 4] = p;
  }
}

// ---------------- batched transpose [B][R][C]->[B][C][R], opt bf16 twin ----
template<bool BF16OUT>
__global__ void transp(const float* __restrict__ in, float* __restrict__ out32,
                       u16t* __restrict__ out16, int R, int C) {
  __shared__ float tile[32][33];
  const int b = blockIdx.z;
  const int r0 = blockIdx.y << 5, c0 = blockIdx.x << 5;
  const float* inb = in + (size_t)b * R * C;
  const int tx = threadIdx.x, ty = threadIdx.y;
#pragma unroll
  for (int dy = 0; dy < 32; dy += 8)
    tile[ty + dy][tx] = inb[(size_t)(r0 + ty + dy) * C + c0 + tx];
  __syncthreads();
#pragma unroll
  for (int dy = 0; dy < 32; dy += 8) {
    const float v = tile[tx][ty + dy];
    const size_t idx = (size_t)b * R * C + (size_t)(c0 + ty + dy) * R + r0 + tx;
    out32[idx] = v;
    if (BF16OUT) out16[idx] = f2b(v);
  }
}

// ---------------- one-shot prep -------------------------------------------
__global__ __launch_bounds__(256) void prep_all(
    const float* __restrict__ x0, u16t* __restrict__ x16,
    const float* __restrict__ wqkv1, u16t* __restrict__ tqkv1,
    const float* __restrict__ wo1,   u16t* __restrict__ two1,
    const float* __restrict__ ff1w1, u16t* __restrict__ tff1a,
    const float* __restrict__ ff1w2, u16t* __restrict__ tff1b,
    const float* __restrict__ wqkv2, u16t* __restrict__ tqkv2,
    const float* __restrict__ wo2,   u16t* __restrict__ two2,
    const float* __restrict__ ff2w1, u16t* __restrict__ tff2a,
    const float* __restrict__ ff2w2, u16t* __restrict__ tff2b,
    const float* __restrict__ ff1b1, float* __restrict__ bp1,
    const float* __restrict__ ff2b1, float* __restrict__ bp2) {
  __shared__ float tile[32][33];
  const int b = blockIdx.x, t = threadIdx.x;
  const int tx = t & 31, ty = t >> 5;
  const float* src; u16t* dst;
  int K, N, bxd, blk, halfN = 0; bool perm = false;
  if (b < 1024) {
    const float* p = x0 + (size_t)(b * 256 + t) * 8;
    short8 v;
#pragma unroll
    for (int j = 0; j < 8; ++j) v[j] = (short)f2b(p[j]);
    *(short8*)(x16 + (size_t)(b * 256 + t) * 8) = v;
    return;
  } else if (b < 1120) { src = wqkv1; dst = tqkv1; K = 256;  N = 384;  bxd = 12;  blk = b - 1024; }
  else if (b < 1152)   { src = wo1;   dst = two1;  K = 128;  N = 256;  bxd = 8;   blk = b - 1120; }
  else if (b < 1664)   { src = ff1w1; dst = tff1a; K = 256;  N = 2048; bxd = 64;  blk = b - 1152; perm = true; halfN = 1024; }
  else if (b < 1920)   { src = ff1w2; dst = tff1b; K = 1024; N = 256;  bxd = 8;   blk = b - 1664; }
  else if (b < 2112)   { src = wqkv2; dst = tqkv2; K = 512;  N = 384;  bxd = 12;  blk = b - 1920; }
  else if (b < 2176)   { src = wo2;   dst = two2;  K = 128;  N = 512;  bxd = 16;  blk = b - 2112; }
  else if (b < 4224)   { src = ff2w1; dst = tff2a; K = 512;  N = 4096; bxd = 128; blk = b - 2176; perm = true; halfN = 2048; }
  else if (b < 5248)   { src = ff2w2; dst = tff2b; K = 2048; N = 512;  bxd = 16;  blk = b - 4224; }
  else if (b < 5256) { const int n = (b - 5248) * 256 + t; bp1[n] = ff1b1[origcol(n, 1024)]; return; }
  else               { const int n = (b - 5256) * 256 + t; bp2[n] = ff2b1[origcol(n, 2048)]; return; }

  const int bx = blk % bxd, by = blk / bxd;
  const int n0 = bx * 32, k0 = by * 32;
  const int nn = n0 + tx;
  const int no = perm ? origcol(nn, halfN) : nn;
#pragma unroll
  for (int dy = 0; dy < 32; dy += 8)
    tile[ty + dy][tx] = src[(size_t)(k0 + ty + dy) * N + no];
  __syncthreads();
#pragma unroll
  for (int dy = 0; dy < 32; dy += 8)
    dst[(size_t)(n0 + ty + dy) * K + k0 + tx] = f2b(tile[tx][ty + dy]);
}

// ---------------------------------------------------------------------------
extern "C" void kernel_launch(void* const* d_in, const int* in_sizes, int n_in,
                              void* d_out, int out_size, void* d_ws, size_t ws_size,
                              hipStream_t stream) {
  (void)in_sizes; (void)n_in; (void)out_size; (void)ws_size;
  const float* x0    = (const float*)d_in[0];
  const float* wqkv1 = (const float*)d_in[1];
  const float* wo1   = (const float*)d_in[2];
  const float* bo1   = (const float*)d_in[3];
  const float* ff1w1 = (const float*)d_in[4];
  const float* ff1b1 = (const float*)d_in[5];
  const float* ff1w2 = (const float*)d_in[6];
  const float* ff1b2 = (const float*)d_in[7];
  const float* wqkv2 = (const float*)d_in[8];
  const float* wo2   = (const float*)d_in[9];
  const float* bo2   = (const float*)d_in[10];
  const float* ff2w1 = (const float*)d_in[11];
  const float* ff2b1 = (const float*)d_in[12];
  const float* ff2w2 = (const float*)d_in[13];
  const float* ff2b2 = (const float*)d_in[14];
  const float* ln1g  = (const float*)d_in[15];
  const float* ln1b  = (const float*)d_in[16];
  const float* ln2g  = (const float*)d_in[17];
  const float* ln2b  = (const float*)d_in[18];
  const float* ln3g  = (const float*)d_in[19];
  const float* ln3b  = (const float*)d_in[20];
  const float* ln4g  = (const float*)d_in[21];
  const float* ln4b  = (const float*)d_in[22];

  float* out_x  = (float*)d_out;
  float* share1 = out_x + (size_t)2097152;
  float* share2 = share1 + (size_t)33554432;

  size_t off = 0;
  auto carve = [&](size_t bytes) -> void* {
    void* p = (char*)d_ws + off;
    off += (bytes + 255) & ~(size_t)255;
    return p;
  };
  u16t*  x16    = (u16t*)carve((size_t)8192 * 256 * 2);
  u16t*  qkv16  = (u16t*)carve((size_t)8192 * 384 * 2);
  u16t*  attn16 = (u16t*)carve((size_t)8192 * 128 * 2);
  float* sumb   = (float*)carve((size_t)8192 * 256 * 4);
  float* xa32   = (float*)carve((size_t)8192 * 256 * 4);
  u16t*  xa16   = (u16t*)carve((size_t)8192 * 256 * 2);
  float* xb32   = (float*)carve((size_t)8192 * 256 * 4);
  float* xt32   = (float*)carve((size_t)8192 * 256 * 4);
  u16t*  xt16   = (u16t*)carve((size_t)8192 * 256 * 2);
  float* xc32   = (float*)carve((size_t)8192 * 256 * 4);
  u16t*  xc16   = (u16t*)carve((size_t)8192 * 256 * 2);
  float* xd32   = (float*)carve((size_t)8192 * 256 * 4);
  u16t*  ubuf   = (u16t*)carve((size_t)8192 * 1024 * 2);
  u16t*  tqkv1  = (u16t*)carve((size_t)384 * 256 * 2);
  u16t*  two1   = (u16t*)carve((size_t)256 * 128 * 2);
  u16t*  tff1a  = (u16t*)carve((size_t)2048 * 256 * 2);
  u16t*  tff1b  = (u16t*)carve((size_t)256 * 1024 * 2);
  u16t*  tqkv2  = (u16t*)carve((size_t)384 * 512 * 2);
  u16t*  two2   = (u16t*)carve((size_t)512 * 128 * 2);
  u16t*  tff2a  = (u16t*)carve((size_t)4096 * 512 * 2);
  u16t*  tff2b  = (u16t*)carve((size_t)512 * 2048 * 2);
  float* bp1    = (float*)carve((size_t)2048 * 4);
  float* bp2    = (float*)carve((size_t)4096 * 4);

  // dynamic-LDS opt-in for the fused wo+LN kernels (72 KB / 132 KB)
  (void)hipFuncSetAttribute(reinterpret_cast<const void*>(&gemmlnF<256, 32>),
                            hipFuncAttributeMaxDynamicSharedMemorySize, 73728);
  (void)hipFuncSetAttribute(reinterpret_cast<const void*>(&gemmlnF<512, 16>),
                            hipFuncAttributeMaxDynamicSharedMemorySize, 135168);

  prep_all<<<5272, 256, 0, stream>>>(x0, x16, wqkv1, tqkv1, wo1, two1,
      ff1w1, tff1a, ff1w2, tff1b, wqkv2, tqkv2, wo2, two2,
      ff2w1, tff2a, ff2w2, tff2b, ff1b1, bp1, ff2b1, bp2);

  // ---- stage 1 (tokens=512, feat=256) ----
  mgemm64<0><<<dim3(6, 128), 256, 0, stream>>>(x16, tqkv1, nullptr, nullptr, qkv16, 8192, 384, 256);
  attn_mfma<512><<<1024, 256, 0, stream>>>(qkv16, share1, attn16);
  gemmlnF<256, 32><<<256, 256, 73728, stream>>>(attn16, two1, bo1, x0, ln1g, ln1b, xa32, xa16);
  mgemm<2><<<dim3(16, 64), 256, 0, stream>>>(xa16, tff1a, bp1, nullptr, ubuf, 8192, 2048, 256);
  mgemm64<1><<<dim3(4, 128), 256, 0, stream>>>(ubuf, tff1b, ff1b2, xa32, sumb, 8192, 256, 1024);
  ln_vec<64, false><<<8192, 64, 0, stream>>>(sumb, ln2g, ln2b, xb32, nullptr, 256);

  // ---- transpose to [B,256,512] ----
  transp<true><<<dim3(8, 16, 16), dim3(32, 8), 0, stream>>>(xb32, xt32, xt16, 512, 256);

  // ---- stage 2 (tokens=256, feat=512) ----
  mgemm64<0><<<dim3(6, 64), 256, 0, stream>>>(xt16, tqkv2, nullptr, nullptr, qkv16, 4096, 384, 512);
  attn_mfma<256><<<512, 256, 0, stream>>>(qkv16, share2, attn16);
  gemmlnF<512, 16><<<256, 256, 135168, stream>>>(attn16, two2, bo2, xt32, ln3g, ln3b, xc32, xc16);
  mgemm<2><<<dim3(32, 32), 256, 0, stream>>>(xc16, tff2a, bp2, nullptr, ubuf, 4096, 4096, 512);
  mgemm64<1><<<dim3(8, 64), 256, 0, stream>>>(ubuf, tff2b, ff2b2, xc32, sumb, 4096, 512, 2048);
  ln_vec<128, false><<<4096, 128, 0, stream>>>(sumb, ln4g, ln4b, xd32, nullptr, 512);

  // ---- transpose back -> out ----
  transp<false><<<dim3(16, 8, 16), dim3(32, 8), 0, stream>>>(xd32, out_x, nullptr, 256, 512);
}

// Round 14
// 194.830 us; speedup vs baseline: 1.2270x; 1.0210x over previous
//
#include <hip/hip_runtime.h>
#include <cstddef>

// ---------------------------------------------------------------------------
// B=16, N=512, D=256, H=8, DH=16, INNER=128, SCALE=0.25
// R13 base (198.9us) + LN2/LN4 fused into transposes (ln_stats pre-pass) +
// gemmlnF<256> at BM=16 (grid 512 = 2 blocks/CU). 16 launches.
// ---------------------------------------------------------------------------

typedef __attribute__((ext_vector_type(8))) short short8;
typedef __attribute__((ext_vector_type(4))) short bf16x4;
typedef __attribute__((ext_vector_type(4))) float f32x4;
typedef unsigned short u16t;

__device__ __forceinline__ u16t f2b(float f) {           // fp32 -> bf16 (RNE)
  union { float f; unsigned u; } x; x.f = f;
  unsigned r = (x.u + 0x7fffu + ((x.u >> 16) & 1u)) >> 16;
  return (u16t)r;
}

__device__ __forceinline__ void gload16(const void* g, void* l) {
  __builtin_amdgcn_global_load_lds(
      (const __attribute__((address_space(1))) void*)g,
      (__attribute__((address_space(3))) void*)l, 16, 0, 0);
}

// exact-GELU via Abramowitz-Stegun 7.1.26 erf (max abs err 1.5e-7)
__device__ __forceinline__ float gelu_f(float g) {
  const float x = g * 0.70710678118654752f;
  const float ax = fabsf(x);
  const float t = 1.f / (1.f + 0.3275911f * ax);
  const float p = t * (0.254829592f + t * (-0.284496736f +
                  t * (1.421413741f + t * (-1.453152027f + t * 1.061405429f))));
  const float er = 1.f - p * __expf(-x * x);
  return 0.5f * g * (1.f + copysignf(er, x));
}

// GEGLU weight-column permutation: n_new -> n_orig.
__device__ __forceinline__ int origcol(int n, int halfN) {
  const int nb = n >> 7, s = (n >> 4) & 7, r = n & 15;
  return ((s & 1) ? halfN : 0) + (nb << 6) + ((s >> 1) << 4) + r;
}

// ---------------- 128x128 MFMA GEMM, BK=64 (EPI 2 = fused GEGLU) -----------
template<int EPI>
__global__ __launch_bounds__(256) void mgemm(
    const u16t* __restrict__ A, const u16t* __restrict__ BT,
    const float* __restrict__ bias, const float* __restrict__ res,
    void* __restrict__ C, int M, int N, int K) {
  __shared__ u16t Al[2][128 * 32];   // two 32-col halves, 8 KB each
  __shared__ u16t Bl[2][128 * 32];
  const int t = threadIdx.x, lane = t & 63, wid = t >> 6;
  const int wr = wid >> 1, wc = wid & 1;
  const int lr = lane & 15, lq = lane >> 4;
  const int bm = blockIdx.y << 7, bn = blockIdx.x << 7;

  const int ao0 = wid * 2048 + lane * 16;
  const int ar0 = ao0 >> 6,          ac0 = (ao0 & 63) >> 1;
  const int ar1 = (ao0 + 1024) >> 6, ac1 = ((ao0 + 1024) & 63) >> 1;

  const u16t* Ab = A + (size_t)bm * K;
  const u16t* Bb = BT + (size_t)bn * K;

  f32x4 acc[4][4];
#pragma unroll
  for (int m = 0; m < 4; ++m)
#pragma unroll
    for (int n = 0; n < 4; ++n) acc[m][n] = (f32x4){0.f, 0.f, 0.f, 0.f};

  for (int k0 = 0; k0 < K; k0 += 64) {
#pragma unroll
    for (int h = 0; h < 2; ++h) {
      const int kh = k0 + h * 32;
      gload16(Ab + (size_t)ar0 * K + kh + ac0, (char*)Al[h] + wid * 2048);
      gload16(Ab + (size_t)ar1 * K + kh + ac1, (char*)Al[h] + wid * 2048 + 1024);
      gload16(Bb + (size_t)ar0 * K + kh + ac0, (char*)Bl[h] + wid * 2048);
      gload16(Bb + (size_t)ar1 * K + kh + ac1, (char*)Bl[h] + wid * 2048 + 1024);
    }
    __syncthreads();
#pragma unroll
    for (int h = 0; h < 2; ++h) {
      short8 af[4], bf[4];
#pragma unroll
      for (int m = 0; m < 4; ++m)
        af[m] = *(const short8*)&Al[h][(wr * 64 + m * 16 + lr) * 32 + lq * 8];
#pragma unroll
      for (int n = 0; n < 4; ++n)
        bf[n] = *(const short8*)&Bl[h][(wc * 64 + n * 16 + lr) * 32 + lq * 8];
#pragma unroll
      for (int m = 0; m < 4; ++m)
#pragma unroll
        for (int n = 0; n < 4; ++n)
          acc[m][n] = __builtin_amdgcn_mfma_f32_16x16x32_bf16(af[m], bf[n], acc[m][n], 0, 0, 0);
    }
    __syncthreads();
  }

  if (EPI == 2) {                    // fused bias + GEGLU (permuted cols)
    const int Nh = N >> 1;
#pragma unroll
    for (int np = 0; np < 2; ++np) {
      const int ca = bn + wc * 64 + np * 32 + lr;
      const float ba = bias[ca], bg = bias[ca + 16];
      const int uc = (bn >> 1) + wc * 32 + np * 16 + lr;
#pragma unroll
      for (int m = 0; m < 4; ++m) {
#pragma unroll
        for (int i = 0; i < 4; ++i) {
          const int row = bm + wr * 64 + m * 16 + lq * 4 + i;
          const float a = acc[m][2 * np][i] + ba;
          const float g = acc[m][2 * np + 1][i] + bg;
          ((u16t*)C)[(size_t)row * Nh + uc] = f2b(a * gelu_f(g));
        }
      }
    }
  } else {
#pragma unroll
    for (int n = 0; n < 4; ++n) {
      const int col = bn + wc * 64 + n * 16 + lr;
      const float bv = bias ? bias[col] : 0.f;
#pragma unroll
      for (int m = 0; m < 4; ++m) {
#pragma unroll
        for (int i = 0; i < 4; ++i) {
          const int row = bm + wr * 64 + m * 16 + lq * 4 + i;
          float v = acc[m][n][i] + bv;
          if (EPI == 1) {
            v += res[(size_t)row * N + col];
            ((float*)C)[(size_t)row * N + col] = v;
          } else {
            ((u16t*)C)[(size_t)row * N + col] = f2b(v);
          }
        }
      }
    }
  }
}

// ---------------- 64x64 MFMA GEMM, BK=128, for thin shapes -----------------
template<int EPI>
__global__ __launch_bounds__(256) void mgemm64(
    const u16t* __restrict__ A, const u16t* __restrict__ BT,
    const float* __restrict__ bias, const float* __restrict__ res,
    void* __restrict__ C, int M, int N, int K) {
  __shared__ u16t Al[4][64 * 32];    // four 32-col quarters, 4 KB each
  __shared__ u16t Bl[4][64 * 32];
  const int t = threadIdx.x, lane = t & 63, wid = t >> 6;
  const int wr = wid >> 1, wc = wid & 1;
  const int lr = lane & 15, lq = lane >> 4;
  const int bm = blockIdx.y << 6, bn = blockIdx.x << 6;
  const int ch = wid * 64 + lane;
  const int crow = ch >> 2, ccol = (ch & 3) << 3;

  const u16t* Ab = A + (size_t)bm * K;
  const u16t* Bb = BT + (size_t)bn * K;

  f32x4 acc[2][2];
#pragma unroll
  for (int m = 0; m < 2; ++m)
#pragma unroll
    for (int n = 0; n < 2; ++n) acc[m][n] = (f32x4){0.f, 0.f, 0.f, 0.f};

  for (int k0 = 0; k0 < K; k0 += 128) {
#pragma unroll
    for (int h = 0; h < 4; ++h) {
      const int kh = k0 + h * 32;
      gload16(Ab + (size_t)crow * K + kh + ccol, (char*)Al[h] + wid * 1024);
      gload16(Bb + (size_t)crow * K + kh + ccol, (char*)Bl[h] + wid * 1024);
    }
    __syncthreads();
#pragma unroll
    for (int h = 0; h < 4; ++h) {
      short8 af[2], bf[2];
#pragma unroll
      for (int m = 0; m < 2; ++m)
        af[m] = *(const short8*)&Al[h][(wr * 32 + m * 16 + lr) * 32 + lq * 8];
#pragma unroll
      for (int n = 0; n < 2; ++n)
        bf[n] = *(const short8*)&Bl[h][(wc * 32 + n * 16 + lr) * 32 + lq * 8];
#pragma unroll
      for (int m = 0; m < 2; ++m)
#pragma unroll
        for (int n = 0; n < 2; ++n)
          acc[m][n] = __builtin_amdgcn_mfma_f32_16x16x32_bf16(af[m], bf[n], acc[m][n], 0, 0, 0);
    }
    __syncthreads();
  }

#pragma unroll
  for (int n = 0; n < 2; ++n) {
    const int col = bn + wc * 32 + n * 16 + lr;
    const float bv = bias ? bias[col] : 0.f;
#pragma unroll
    for (int m = 0; m < 2; ++m) {
#pragma unroll
      for (int i = 0; i < 4; ++i) {
        const int row = bm + wr * 32 + m * 16 + lq * 4 + i;
        float v = acc[m][n][i] + bv;
        if (EPI == 1) {
          v += res[(size_t)row * N + col];
          ((float*)C)[(size_t)row * N + col] = v;
        } else {
          ((u16t*)C)[(size_t)row * N + col] = f2b(v);
        }
      }
    }
  }
}

// ---------------- wo-projection + bias + residual + LayerNorm, fused -------
// C = LN(A[M,128] @ BT[NW,128]^T + bias + res). Whole B staged in LDS once.
template<int NW, int BM>
__global__ __launch_bounds__(256) void gemmlnF(
    const u16t* __restrict__ A, const u16t* __restrict__ BT,
    const float* __restrict__ bias, const float* __restrict__ res,
    const float* __restrict__ g, const float* __restrict__ be,
    float* __restrict__ y32, u16t* __restrict__ y16) {
  constexpr int NR = NW / 64;        // col frags per wave
  constexpr int MR = BM / 16;        // row frags
  extern __shared__ u16t lds[];
  u16t* Al = lds;                    // [BM][128] row-major
  u16t* Bl = lds + BM * 128;         // [NW][128] row-major
  __shared__ float psum[4][BM], psq[4][BM];
  const int t = threadIdx.x, lane = t & 63, wid = t >> 6;
  const int lr = lane & 15, lq = lane >> 4;
  const int bm = blockIdx.x * BM;
  const int wofs = wid * (NW / 4);

  // stage A: BM*16 chunks of 16B, 256/iter (R9-verified form, BM/16 iters)
  const int c0 = wid * 64 + lane;
#pragma unroll
  for (int j = 0; j < BM / 16; ++j) {
    const int c = j * 256 + c0;
    gload16(A + (size_t)(bm + (c >> 4)) * 128 + ((c & 15) << 3),
            (char*)Al + (size_t)(j * 256 + wid * 64) * 16);
  }
#pragma unroll
  for (int j = 0; j < NW / 16; ++j) {
    const int c = j * 256 + c0;
    gload16(BT + (size_t)(c >> 4) * 128 + ((c & 15) << 3),
            (char*)Bl + (size_t)(j * 256 + wid * 64) * 16);
  }
  __syncthreads();

  f32x4 acc[MR][NR];
#pragma unroll
  for (int m = 0; m < MR; ++m)
#pragma unroll
    for (int n = 0; n < NR; ++n) acc[m][n] = (f32x4){0.f, 0.f, 0.f, 0.f};

#pragma unroll
  for (int kk = 0; kk < 4; ++kk) {
    short8 af[MR], bf[NR];
#pragma unroll
    for (int m = 0; m < MR; ++m)
      af[m] = *(const short8*)&Al[(m * 16 + lr) * 128 + kk * 32 + lq * 8];
#pragma unroll
    for (int n = 0; n < NR; ++n)
      bf[n] = *(const short8*)&Bl[(wofs + n * 16 + lr) * 128 + kk * 32 + lq * 8];
#pragma unroll
    for (int m = 0; m < MR; ++m)
#pragma unroll
      for (int n = 0; n < NR; ++n)
        acc[m][n] = __builtin_amdgcn_mfma_f32_16x16x32_bf16(af[m], bf[n], acc[m][n], 0, 0, 0);
  }

  float ps[MR][4], ps2[MR][4];
#pragma unroll
  for (int m = 0; m < MR; ++m)
#pragma unroll
    for (int i = 0; i < 4; ++i) { ps[m][i] = 0.f; ps2[m][i] = 0.f; }
#pragma unroll
  for (int m = 0; m < MR; ++m)
#pragma unroll
    for (int n = 0; n < NR; ++n) {
      const int col = wofs + n * 16 + lr;
      const float bv = bias[col];
#pragma unroll
      for (int i = 0; i < 4; ++i) {
        const int row = bm + m * 16 + lq * 4 + i;
        const float v = acc[m][n][i] + bv + res[(size_t)row * NW + col];
        acc[m][n][i] = v;
        ps[m][i] += v; ps2[m][i] += v * v;
      }
    }
#pragma unroll
  for (int m = 0; m < MR; ++m)
#pragma unroll
    for (int i = 0; i < 4; ++i) {
      float s = ps[m][i], s2 = ps2[m][i];
      s  += __shfl_xor(s, 1);  s  += __shfl_xor(s, 2);
      s  += __shfl_xor(s, 4);  s  += __shfl_xor(s, 8);
      s2 += __shfl_xor(s2, 1); s2 += __shfl_xor(s2, 2);
      s2 += __shfl_xor(s2, 4); s2 += __shfl_xor(s2, 8);
      if (lr == 0) {
        psum[wid][m * 16 + lq * 4 + i] = s;
        psq[wid][m * 16 + lq * 4 + i]  = s2;
      }
    }
  __syncthreads();
#pragma unroll
  for (int m = 0; m < MR; ++m)
#pragma unroll
    for (int i = 0; i < 4; ++i) {
      const int r = m * 16 + lq * 4 + i;
      const float tot = psum[0][r] + psum[1][r] + psum[2][r] + psum[3][r];
      const float tq  = psq[0][r]  + psq[1][r]  + psq[2][r]  + psq[3][r];
      const float mean = tot / NW;
      const float rstd = rsqrtf(tq / NW - mean * mean + 1e-5f);
      const int row = bm + r;
#pragma unroll
      for (int n = 0; n < NR; ++n) {
        const int col = wofs + n * 16 + lr;
        const float y = (acc[m][n][i] - mean) * rstd * g[col] + be[col];
        y32[(size_t)row * NW + col] = y;
        y16[(size_t)row * NW + col] = f2b(y);
      }
    }
}

// ---------------- MFMA attention ------------------------------------------
template<int NTOK>
__global__ __launch_bounds__(256) void attn_mfma(
    const u16t* __restrict__ qkv, float* __restrict__ share,
    u16t* __restrict__ outb) {
  __shared__ u16t VT[16][NTOK + 40];
  __shared__ u16t PB[4][16][40];
  const int t = threadIdx.x, lane = t & 63, wv = t >> 6;
  const int lr = lane & 15, lq = lane >> 4;
  const int bpb = NTOK / 64;
  const int bh = blockIdx.x / bpb, rg = blockIdx.x % bpb;
  const int b = bh >> 3, h = bh & 7;
  const u16t* qkvb = qkv + (size_t)b * NTOK * 384;

  for (int tok = t; tok < NTOK; tok += 256) {
    const u16t* vp = qkvb + (size_t)tok * 384 + 256 + h * 16;
    short8 v0 = *(const short8*)vp;
    short8 v1 = *(const short8*)(vp + 8);
#pragma unroll
    for (int d = 0; d < 8; ++d) {
      VT[d][tok]     = (u16t)v0[d];
      VT[d + 8][tok] = (u16t)v1[d];
    }
  }
  __syncthreads();

  const int i0 = rg * 64 + wv * 16;
  short8 qf = {0, 0, 0, 0, 0, 0, 0, 0};
  if (lq < 2)
    qf = *(const short8*)(qkvb + (size_t)(i0 + lr) * 384 + h * 16 + lq * 8);

  f32x4 oacc = {0.f, 0.f, 0.f, 0.f};
  f32x4 sacc = {0.f, 0.f, 0.f, 0.f};
  const f32x4 zero = {0.f, 0.f, 0.f, 0.f};
  float* shb = share + (size_t)bh * NTOK * NTOK;

  for (int t0 = 0; t0 < NTOK; t0 += 32) {
#pragma unroll
    for (int s2 = 0; s2 < 2; ++s2) {
      short8 kf = {0, 0, 0, 0, 0, 0, 0, 0};
      if (lq < 2)
        kf = *(const short8*)(qkvb + (size_t)(t0 + s2 * 16 + lr) * 384 + 128 + h * 16 + lq * 8);
      f32x4 e = __builtin_amdgcn_mfma_f32_16x16x32_bf16(qf, kf, zero, 0, 0, 0);
#pragma unroll
      for (int i = 0; i < 4; ++i) {
        const float ev = e[i] * 0.25f;
        shb[(size_t)(i0 + lq * 4 + i) * NTOK + t0 + s2 * 16 + lr] = ev;
        const float p = __expf(ev);
        sacc[i] += p;
        PB[wv][lq * 4 + i][s2 * 16 + lr] = f2b(p);
      }
    }
    asm volatile("s_waitcnt lgkmcnt(0)" ::: "memory");
    __builtin_amdgcn_sched_barrier(0);
    short8 pa = *(const short8*)&PB[wv][lr][lq * 8];
    short8 vf = *(const short8*)&VT[lr][t0 + lq * 8];
    oacc = __builtin_amdgcn_mfma_f32_16x16x32_bf16(pa, vf, oacc, 0, 0, 0);
    __builtin_amdgcn_sched_barrier(0);
  }
#pragma unroll
  for (int i = 0; i < 4; ++i) {
    float s = sacc[i];
    s += __shfl_xor(s, 1); s += __shfl_xor(s, 2);
    s += __shfl_xor(s, 4); s += __shfl_xor(s, 8);
    sacc[i] = s;
  }
#pragma unroll
  for (int i = 0; i < 4; ++i) {
    const float o = oacc[i] / sacc[i];
    outb[((size_t)(b * NTOK) + i0 + lq * 4 + i) * 128 + h * 16 + lr] = f2b(o);
  }
}

// ---------------- LN row-stats: mean/rstd per row -> stats[row*2+{0,1}] ----
template<int D>
__global__ __launch_bounds__(256) void ln_stats(
    const float* __restrict__ xin, float* __restrict__ stats) {
  const int wv = threadIdx.x >> 6, lane = threadIdx.x & 63;
  const int row = blockIdx.x * 4 + wv;
  const float* p = xin + (size_t)row * D;
  float s = 0.f, s2 = 0.f;
#pragma unroll
  for (int k = 0; k < D / 256; ++k) {
    const float4 x = ((const float4*)p)[lane + k * 64];
    s  += x.x + x.y + x.z + x.w;
    s2 += x.x * x.x + x.y * x.y + x.z * x.z + x.w * x.w;
  }
#pragma unroll
  for (int off = 32; off; off >>= 1) {
    s += __shfl_xor(s, off); s2 += __shfl_xor(s2, off);
  }
  if (lane == 0) {
    const float mean = s / D;
    stats[row * 2]     = mean;
    stats[row * 2 + 1] = rsqrtf(s2 / D - mean * mean + 1e-5f);
  }
}

// ---------------- batched transpose + optional fused LN -------------------
// in[B][R][C] -> out[b][c][r]; if LN: y = (v-mean[row])*rstd[row]*g[c]+be[c]
// with row = global row b*R + r.
template<bool BF16OUT, bool LN>
__global__ void transp(const float* __restrict__ in,
                       const float* __restrict__ stats,
                       const float* __restrict__ g, const float* __restrict__ be,
                       float* __restrict__ out32, u16t* __restrict__ out16,
                       int R, int C) {
  __shared__ float tile[32][33];
  const int b = blockIdx.z;
  const int r0 = blockIdx.y << 5, c0 = blockIdx.x << 5;
  const float* inb = in + (size_t)b * R * C;
  const int tx = threadIdx.x, ty = threadIdx.y;
#pragma unroll
  for (int dy = 0; dy < 32; dy += 8)
    tile[ty + dy][tx] = inb[(size_t)(r0 + ty + dy) * C + c0 + tx];
  __syncthreads();
  float mean = 0.f, rstd = 1.f;
  if (LN) {
    const size_t grow = (size_t)b * R + r0 + tx;
    mean = stats[grow * 2];
    rstd = stats[grow * 2 + 1];
  }
#pragma unroll
  for (int dy = 0; dy < 32; dy += 8) {
    float v = tile[tx][ty + dy];
    if (LN) {
      const int c = c0 + ty + dy;
      v = (v - mean) * rstd * g[c] + be[c];
    }
    const size_t idx = (size_t)b * R * C + (size_t)(c0 + ty + dy) * R + r0 + tx;
    out32[idx] = v;
    if (BF16OUT) out16[idx] = f2b(v);
  }
}

// ---------------- one-shot prep -------------------------------------------
__global__ __launch_bounds__(256) void prep_all(
    const float* __restrict__ x0, u16t* __restrict__ x16,
    const float* __restrict__ wqkv1, u16t* __restrict__ tqkv1,
    const float* __restrict__ wo1,   u16t* __restrict__ two1,
    const float* __restrict__ ff1w1, u16t* __restrict__ tff1a,
    const float* __restrict__ ff1w2, u16t* __restrict__ tff1b,
    const float* __restrict__ wqkv2, u16t* __restrict__ tqkv2,
    const float* __restrict__ wo2,   u16t* __restrict__ two2,
    const float* __restrict__ ff2w1, u16t* __restrict__ tff2a,
    const float* __restrict__ ff2w2, u16t* __restrict__ tff2b,
    const float* __restrict__ ff1b1, float* __restrict__ bp1,
    const float* __restrict__ ff2b1, float* __restrict__ bp2) {
  __shared__ float tile[32][33];
  const int b = blockIdx.x, t = threadIdx.x;
  const int tx = t & 31, ty = t >> 5;
  const float* src; u16t* dst;
  int K, N, bxd, blk, halfN = 0; bool perm = false;
  if (b < 1024) {
    const float* p = x0 + (size_t)(b * 256 + t) * 8;
    short8 v;
#pragma unroll
    for (int j = 0; j < 8; ++j) v[j] = (short)f2b(p[j]);
    *(short8*)(x16 + (size_t)(b * 256 + t) * 8) = v;
    return;
  } else if (b < 1120) { src = wqkv1; dst = tqkv1; K = 256;  N = 384;  bxd = 12;  blk = b - 1024; }
  else if (b < 1152)   { src = wo1;   dst = two1;  K = 128;  N = 256;  bxd = 8;   blk = b - 1120; }
  else if (b < 1664)   { src = ff1w1; dst = tff1a; K = 256;  N = 2048; bxd = 64;  blk = b - 1152; perm = true; halfN = 1024; }
  else if (b < 1920)   { src = ff1w2; dst = tff1b; K = 1024; N = 256;  bxd = 8;   blk = b - 1664; }
  else if (b < 2112)   { src = wqkv2; dst = tqkv2; K = 512;  N = 384;  bxd = 12;  blk = b - 1920; }
  else if (b < 2176)   { src = wo2;   dst = two2;  K = 128;  N = 512;  bxd = 16;  blk = b - 2112; }
  else if (b < 4224)   { src = ff2w1; dst = tff2a; K = 512;  N = 4096; bxd = 128; blk = b - 2176; perm = true; halfN = 2048; }
  else if (b < 5248)   { src = ff2w2; dst = tff2b; K = 2048; N = 512;  bxd = 16;  blk = b - 4224; }
  else if (b < 5256) { const int n = (b - 5248) * 256 + t; bp1[n] = ff1b1[origcol(n, 1024)]; return; }
  else               { const int n = (b - 5256) * 256 + t; bp2[n] = ff2b1[origcol(n, 2048)]; return; }

  const int bx = blk % bxd, by = blk / bxd;
  const int n0 = bx * 32, k0 = by * 32;
  const int nn = n0 + tx;
  const int no = perm ? origcol(nn, halfN) : nn;
#pragma unroll
  for (int dy = 0; dy < 32; dy += 8)
    tile[ty + dy][tx] = src[(size_t)(k0 + ty + dy) * N + no];
  __syncthreads();
#pragma unroll
  for (int dy = 0; dy < 32; dy += 8)
    dst[(size_t)(n0 + ty + dy) * K + k0 + tx] = f2b(tile[tx][ty + dy]);
}

// ---------------------------------------------------------------------------
extern "C" void kernel_launch(void* const* d_in, const int* in_sizes, int n_in,
                              void* d_out, int out_size, void* d_ws, size_t ws_size,
                              hipStream_t stream) {
  (void)in_sizes; (void)n_in; (void)out_size; (void)ws_size;
  const float* x0    = (const float*)d_in[0];
  const float* wqkv1 = (const float*)d_in[1];
  const float* wo1   = (const float*)d_in[2];
  const float* bo1   = (const float*)d_in[3];
  const float* ff1w1 = (const float*)d_in[4];
  const float* ff1b1 = (const float*)d_in[5];
  const float* ff1w2 = (const float*)d_in[6];
  const float* ff1b2 = (const float*)d_in[7];
  const float* wqkv2 = (const float*)d_in[8];
  const float* wo2   = (const float*)d_in[9];
  const float* bo2   = (const float*)d_in[10];
  const float* ff2w1 = (const float*)d_in[11];
  const float* ff2b1 = (const float*)d_in[12];
  const float* ff2w2 = (const float*)d_in[13];
  const float* ff2b2 = (const float*)d_in[14];
  const float* ln1g  = (const float*)d_in[15];
  const float* ln1b  = (const float*)d_in[16];
  const float* ln2g  = (const float*)d_in[17];
  const float* ln2b  = (const float*)d_in[18];
  const float* ln3g  = (const float*)d_in[19];
  const float* ln3b  = (const float*)d_in[20];
  const float* ln4g  = (const float*)d_in[21];
  const float* ln4b  = (const float*)d_in[22];

  float* out_x  = (float*)d_out;
  float* share1 = out_x + (size_t)2097152;
  float* share2 = share1 + (size_t)33554432;

  size_t off = 0;
  auto carve = [&](size_t bytes) -> void* {
    void* p = (char*)d_ws + off;
    off += (bytes + 255) & ~(size_t)255;
    return p;
  };
  u16t*  x16    = (u16t*)carve((size_t)8192 * 256 * 2);
  u16t*  qkv16  = (u16t*)carve((size_t)8192 * 384 * 2);
  u16t*  attn16 = (u16t*)carve((size_t)8192 * 128 * 2);
  float* sumb   = (float*)carve((size_t)8192 * 256 * 4);
  float* xa32   = (float*)carve((size_t)8192 * 256 * 4);
  u16t*  xa16   = (u16t*)carve((size_t)8192 * 256 * 2);
  float* xt32   = (float*)carve((size_t)8192 * 256 * 4);
  u16t*  xt16   = (u16t*)carve((size_t)8192 * 256 * 2);
  float* xc32   = (float*)carve((size_t)8192 * 256 * 4);
  u16t*  xc16   = (u16t*)carve((size_t)8192 * 256 * 2);
  u16t*  ubuf   = (u16t*)carve((size_t)8192 * 1024 * 2);
  float* stats1 = (float*)carve((size_t)8192 * 2 * 4);
  float* stats2 = (float*)carve((size_t)4096 * 2 * 4);
  u16t*  tqkv1  = (u16t*)carve((size_t)384 * 256 * 2);
  u16t*  two1   = (u16t*)carve((size_t)256 * 128 * 2);
  u16t*  tff1a  = (u16t*)carve((size_t)2048 * 256 * 2);
  u16t*  tff1b  = (u16t*)carve((size_t)256 * 1024 * 2);
  u16t*  tqkv2  = (u16t*)carve((size_t)384 * 512 * 2);
  u16t*  two2   = (u16t*)carve((size_t)512 * 128 * 2);
  u16t*  tff2a  = (u16t*)carve((size_t)4096 * 512 * 2);
  u16t*  tff2b  = (u16t*)carve((size_t)512 * 2048 * 2);
  float* bp1    = (float*)carve((size_t)2048 * 4);
  float* bp2    = (float*)carve((size_t)4096 * 4);

  // dynamic-LDS opt-in for the fused wo+LN kernels (68 KB / 132 KB)
  (void)hipFuncSetAttribute(reinterpret_cast<const void*>(&gemmlnF<256, 16>),
                            hipFuncAttributeMaxDynamicSharedMemorySize, 69632);
  (void)hipFuncSetAttribute(reinterpret_cast<const void*>(&gemmlnF<512, 16>),
                            hipFuncAttributeMaxDynamicSharedMemorySize, 135168);

  prep_all<<<5272, 256, 0, stream>>>(x0, x16, wqkv1, tqkv1, wo1, two1,
      ff1w1, tff1a, ff1w2, tff1b, wqkv2, tqkv2, wo2, two2,
      ff2w1, tff2a, ff2w2, tff2b, ff1b1, bp1, ff2b1, bp2);

  // ---- stage 1 (tokens=512, feat=256) ----
  mgemm64<0><<<dim3(6, 128), 256, 0, stream>>>(x16, tqkv1, nullptr, nullptr, qkv16, 8192, 384, 256);
  attn_mfma<512><<<1024, 256, 0, stream>>>(qkv16, share1, attn16);
  gemmlnF<256, 16><<<512, 256, 69632, stream>>>(attn16, two1, bo1, x0, ln1g, ln1b, xa32, xa16);
  mgemm<2><<<dim3(16, 64), 256, 0, stream>>>(xa16, tff1a, bp1, nullptr, ubuf, 8192, 2048, 256);
  mgemm64<1><<<dim3(4, 128), 256, 0, stream>>>(ubuf, tff1b, ff1b2, xa32, sumb, 8192, 256, 1024);
  // LN2 stats + fused LN-in-transpose -> xt32, xt16
  ln_stats<256><<<2048, 256, 0, stream>>>(sumb, stats1);
  transp<true, true><<<dim3(8, 16, 16), dim3(32, 8), 0, stream>>>(
      sumb, stats1, ln2g, ln2b, xt32, xt16, 512, 256);

  // ---- stage 2 (tokens=256, feat=512) ----
  mgemm64<0><<<dim3(6, 64), 256, 0, stream>>>(xt16, tqkv2, nullptr, nullptr, qkv16, 4096, 384, 512);
  attn_mfma<256><<<512, 256, 0, stream>>>(qkv16, share2, attn16);
  gemmlnF<512, 16><<<256, 256, 135168, stream>>>(attn16, two2, bo2, xt32, ln3g, ln3b, xc32, xc16);
  mgemm<2><<<dim3(32, 32), 256, 0, stream>>>(xc16, tff2a, bp2, nullptr, ubuf, 4096, 4096, 512);
  mgemm64<1><<<dim3(8, 64), 256, 0, stream>>>(ubuf, tff2b, ff2b2, xc32, sumb, 4096, 512, 2048);
  // LN4 stats + fused LN-in-transpose -> out_x
  ln_stats<512><<<1024, 256, 0, stream>>>(sumb, stats2);
  transp<false, true><<<dim3(16, 8, 16), dim3(32, 8), 0, stream>>>(
      sumb, stats2, ln4g, ln4b, out_x, nullptr, 256, 512);
}